// Round 6
// baseline (87.989 us; speedup 1.0000x reference)
//
#include <hip/hip_runtime.h>
#include <math.h>

// LAPACK >= 3.10 slartg convention (c >= 0). Flip to 0 to emulate <= 3.9.
#define NEW_SLARTG 1

typedef __attribute__((ext_vector_type(8))) short bf16x8;
typedef __attribute__((ext_vector_type(4))) float f32x4;

// =============================================================================
// LAPACK sgesdd emulation for 3x3 (f32), faithful sign conventions.
// Leaf routines NOINLINE to shrink finalize's code footprint (i-fetch).
// =============================================================================

__device__ __attribute__((noinline)) void slartg_f(float f, float g, float& c, float& s, float& r) {
#if NEW_SLARTG
  if (g == 0.0f) { c = 1.0f; s = 0.0f; r = f; }
  else if (f == 0.0f) { c = 0.0f; s = copysignf(1.0f, g); r = fabsf(g); }
  else {
    float d = sqrtf(f*f + g*g);
    c = fabsf(f) / d;
    r = copysignf(d, f);
    s = g / r;
  }
#else
  if (g == 0.0f) { c = 1.0f; s = 0.0f; r = f; }
  else if (f == 0.0f) { c = 0.0f; s = 1.0f; r = g; }
  else {
    float d = sqrtf(f*f + g*g);
    c = f / d; s = g / d; r = d;
    if (fabsf(f) > fabsf(g) && c < 0.0f) { c = -c; s = -s; r = -r; }
  }
#endif
}

__device__ __attribute__((noinline)) void slas2_f(float f, float g, float h, float& ssmin, float& ssmax) {
  float fa = fabsf(f), ga = fabsf(g), ha = fabsf(h);
  float fhmn = fminf(fa, ha), fhmx = fmaxf(fa, ha);
  if (fhmn == 0.0f) {
    ssmin = 0.0f;
    if (fhmx == 0.0f) ssmax = ga;
    else {
      float mn = fminf(fhmx, ga), mx = fmaxf(fhmx, ga);
      float qq = mn / mx;
      ssmax = mx * sqrtf(1.0f + qq*qq);
    }
  } else {
    if (ga < fhmx) {
      float as_ = 1.0f + fhmn/fhmx;
      float at_ = (fhmx - fhmn)/fhmx;
      float au_ = ga/fhmx; au_ = au_*au_;
      float c = 2.0f/(sqrtf(as_*as_ + au_) + sqrtf(at_*at_ + au_));
      ssmin = fhmn*c;
      ssmax = fhmx/c;
    } else {
      float au_ = fhmx/ga;
      if (au_ == 0.0f) {
        ssmin = (fhmn*fhmx)/ga;
        ssmax = ga;
      } else {
        float as_ = 1.0f + fhmn/fhmx;
        float at_ = (fhmx - fhmn)/fhmx;
        float t1 = as_*au_, t2 = at_*au_;
        float c = 1.0f/(sqrtf(1.0f + t1*t1) + sqrtf(1.0f + t2*t2));
        ssmin = (fhmn*c)*au_;
        ssmin = ssmin + ssmin;
        ssmax = ga/(c + c);
      }
    }
  }
}

__device__ __attribute__((noinline)) void slasv2_f(float f, float g, float h,
                         float& ssmin, float& ssmax,
                         float& snr, float& csr, float& snl, float& csl) {
  const float eps = 5.9604645e-08f;
  float ft = f, fa = fabsf(f), ht = h, ha = fabsf(h);
  int pmax = 1;
  bool swap_ = (ha > fa);
  if (swap_) {
    pmax = 3;
    float tq = ft; ft = ht; ht = tq;
    tq = fa; fa = ha; ha = tq;
  }
  float gt = g, ga = fabsf(g);
  float clt = 0.f, crt = 0.f, slt = 0.f, srt = 0.f;
  if (ga == 0.0f) {
    ssmin = ha; ssmax = fa;
    clt = 1.0f; crt = 1.0f; slt = 0.0f; srt = 0.0f;
  } else {
    bool gasmal = true;
    if (ga > fa) {
      pmax = 2;
      if ((fa/ga) < eps) {
        gasmal = false;
        ssmax = ga;
        ssmin = (ha > 1.0f) ? (fa/(ga/ha)) : ((fa/ga)*ha);
        clt = 1.0f; slt = ht/gt; srt = 1.0f; crt = ft/gt;
      }
    }
    if (gasmal) {
      float dd = fa - ha;
      float l = (dd == fa) ? 1.0f : (dd/fa);
      float mr = gt/ft;
      float t = 2.0f - l;
      float mm2 = mr*mr, tt = t*t;
      float s_ = sqrtf(tt + mm2);
      float r_ = (l == 0.0f) ? fabsf(mr) : sqrtf(l*l + mm2);
      float a_ = 0.5f*(s_ + r_);
      ssmin = ha/a_;
      ssmax = fa*a_;
      if (mm2 == 0.0f) {
        if (l == 0.0f) t = copysignf(2.0f, ft)*copysignf(1.0f, gt);
        else t = gt/copysignf(dd, ft) + mr/t;
      } else {
        t = (mr/(s_ + t) + mr/(r_ + l))*(1.0f + a_);
      }
      float l2 = sqrtf(t*t + 4.0f);
      crt = 2.0f/l2;
      srt = t/l2;
      clt = (crt + srt*mr)/a_;
      slt = (ht/ft)*srt/a_;
    }
  }
  if (swap_) { csl = srt; snl = crt; csr = slt; snr = clt; }
  else       { csl = clt; snl = slt; csr = crt; snr = srt; }
  float tsign = 0.f;
  if (pmax == 1) tsign = copysignf(1.0f, csr)*copysignf(1.0f, csl)*copysignf(1.0f, f);
  if (pmax == 2) tsign = copysignf(1.0f, snr)*copysignf(1.0f, csl)*copysignf(1.0f, g);
  if (pmax == 3) tsign = copysignf(1.0f, snr)*copysignf(1.0f, snl)*copysignf(1.0f, h);
  ssmax = copysignf(ssmax, tsign);
  ssmin = copysignf(ssmin, tsign*copysignf(1.0f, f)*copysignf(1.0f, h));
}

__device__ __forceinline__ void rot_rows3(float mt[3][3], int r1, int r2, float c, float s) {
#pragma unroll
  for (int k = 0; k < 3; ++k) {
    float x = mt[r1][k], y = mt[r2][k];
    mt[r1][k] = c*x + s*y;
    mt[r2][k] = c*y - s*x;
  }
}
__device__ __forceinline__ void rot_cols3(float mt[3][3], int c1_, int c2_, float c, float s) {
#pragma unroll
  for (int k = 0; k < 3; ++k) {
    float x = mt[k][c1_], y = mt[k][c2_];
    mt[k][c1_] = c*x + s*y;
    mt[k][c2_] = c*y - s*x;
  }
}

#define D_(i) d[(i)-1]
#define E_(i) e[(i)-1]

__device__ void sbdsqr3(float* d, float* e, float u[3][3], float vt[3][3]) {
  const float eps  = 5.9604645e-08f;
  const float unfl = 1.17549435e-38f;
  const float tol  = 10.0f*eps;

  float sminoa = fabsf(d[0]);
  if (sminoa != 0.0f) {
    float mu = sminoa;
    mu = fabsf(d[1])*(mu/(mu + fabsf(e[0])));
    sminoa = fminf(sminoa, mu);
    if (sminoa != 0.0f) {
      mu = fabsf(d[2])*(mu/(mu + fabsf(e[1])));
      sminoa = fminf(sminoa, mu);
    }
  }
  sminoa = sminoa / sqrtf(3.0f);
  float thresh = fmaxf(tol*sminoa, 54.0f*unfl);

  int m = 3, oldll = -1, oldm = -1, idir = 0;
  int guard = 0;
  while (m > 1 && ++guard < 200) {
    float smax = fabsf(D_(m));
    int ll = 1; bool split = false;
    for (int lll = 1; lll <= m-1; ++lll) {
      int l2 = m - lll;
      float abss = fabsf(D_(l2)), abse = fabsf(E_(l2));
      if (abse <= thresh) { ll = l2; split = true; break; }
      smax = fmaxf(smax, fmaxf(abss, abse));
    }
    if (split) {
      E_(ll) = 0.0f;
      if (ll == m-1) { m = m - 1; continue; }
      ll = ll + 1;
    } else ll = 1;

    if (ll == m-1) {
      float sigmn, sigmx, sinr, cosr, sinl, cosl;
      slasv2_f(D_(m-1), E_(m-1), D_(m), sigmn, sigmx, sinr, cosr, sinl, cosl);
      D_(m-1) = sigmx; D_(m) = sigmn; E_(m-1) = 0.0f;
      rot_rows3(vt, m-2, m-1, cosr, sinr);
      rot_cols3(u,  m-2, m-1, cosl, sinl);
      m -= 2; continue;
    }

    if (ll > oldm || m < oldll)
      idir = (fabsf(D_(ll)) >= fabsf(D_(m))) ? 1 : 2;

    float sminl = 0.0f;
    bool deflated = false;
    if (idir == 1) {
      if (fabsf(E_(m-1)) <= tol*fabsf(D_(m))) { E_(m-1) = 0.0f; continue; }
      float mu = fabsf(D_(ll)); sminl = mu;
      for (int lll = ll; lll <= m-1; ++lll) {
        if (fabsf(E_(lll)) <= tol*mu) { E_(lll) = 0.0f; deflated = true; break; }
        mu = fabsf(D_(lll+1))*(mu/(mu + fabsf(E_(lll))));
        sminl = fminf(sminl, mu);
      }
    } else {
      if (fabsf(E_(ll)) <= tol*fabsf(D_(ll))) { E_(ll) = 0.0f; continue; }
      float mu = fabsf(D_(m)); sminl = mu;
      for (int lll = m-1; lll >= ll; --lll) {
        if (fabsf(E_(lll)) <= tol*mu) { E_(lll) = 0.0f; deflated = true; break; }
        mu = fabsf(D_(lll))*(mu/(mu + fabsf(E_(lll))));
        sminl = fminf(sminl, mu);
      }
    }
    if (deflated) continue;
    oldll = ll; oldm = m;

    float shift = 0.0f, rdum;
    if (!(3.0f*tol*(sminl/smax) <= fmaxf(eps, 0.01f*tol))) {
      float sll;
      if (idir == 1) { sll = fabsf(D_(ll)); slas2_f(D_(m-1), E_(m-1), D_(m), shift, rdum); }
      else           { sll = fabsf(D_(m));  slas2_f(D_(ll), E_(ll), D_(ll+1), shift, rdum); }
      if (sll > 0.0f) { float qq = shift/sll; if (qq*qq < eps) shift = 0.0f; }
    }

    if (shift == 0.0f) {
      if (idir == 1) {
        float cs = 1.0f, oldcs = 1.0f, sn = 0.0f, oldsn = 0.0f, r;
        float c1[2], s1[2], c2[2], s2[2];
        int k = 0;
        for (int i = ll; i <= m-1; ++i, ++k) {
          float fin = D_(i)*cs;
          slartg_f(fin, E_(i), cs, sn, r);
          if (i > ll) E_(i-1) = oldsn*r;
          float f2 = oldcs*r, g2 = D_(i+1)*sn;
          slartg_f(f2, g2, oldcs, oldsn, D_(i));
          c1[k] = cs; s1[k] = sn; c2[k] = oldcs; s2[k] = oldsn;
        }
        float h = D_(m)*cs;
        D_(m) = h*oldcs;
        E_(m-1) = h*oldsn;
        k = 0;
        for (int i = ll; i <= m-1; ++i, ++k) rot_rows3(vt, i-1, i, c1[k], s1[k]);
        k = 0;
        for (int i = ll; i <= m-1; ++i, ++k) rot_cols3(u, i-1, i, c2[k], s2[k]);
        if (fabsf(E_(m-1)) <= thresh) E_(m-1) = 0.0f;
      } else {
        float cs = 1.0f, oldcs = 1.0f, sn = 0.0f, oldsn = 0.0f, r;
        float c1[2], s1[2], c2[2], s2[2];
        for (int i = m; i >= ll+1; --i) {
          float fin = D_(i)*cs;
          slartg_f(fin, E_(i-1), cs, sn, r);
          if (i < m) E_(i) = oldsn*r;
          float f2 = oldcs*r, g2 = D_(i-1)*sn;
          slartg_f(f2, g2, oldcs, oldsn, D_(i));
          int slot = i - ll;
          c1[slot-1] = cs; s1[slot-1] = -sn; c2[slot-1] = oldcs; s2[slot-1] = -oldsn;
        }
        float h = D_(ll)*cs;
        D_(ll) = h*oldcs;
        E_(ll) = h*oldsn;
        for (int j = m-ll; j >= 1; --j) rot_rows3(vt, ll+j-2, ll+j-1, c2[j-1], s2[j-1]);
        for (int j = m-ll; j >= 1; --j) rot_cols3(u,  ll+j-2, ll+j-1, c1[j-1], s1[j-1]);
        if (fabsf(E_(ll)) <= thresh) E_(ll) = 0.0f;
      }
    } else {
      if (idir == 1) {
        float f = (fabsf(D_(ll)) - shift)*(copysignf(1.0f, D_(ll)) + shift/D_(ll));
        float g = E_(ll);
        float cr, sr, cl, sl, r;
        float c1[2], s1[2], c2[2], s2[2];
        int k = 0;
        for (int i = ll; i <= m-1; ++i, ++k) {
          slartg_f(f, g, cr, sr, r);
          if (i > ll) E_(i-1) = r;
          f = cr*D_(i) + sr*E_(i);
          E_(i) = cr*E_(i) - sr*D_(i);
          g = sr*D_(i+1);
          D_(i+1) = cr*D_(i+1);
          slartg_f(f, g, cl, sl, r);
          D_(i) = r;
          f = cl*E_(i) + sl*D_(i+1);
          D_(i+1) = cl*D_(i+1) - sl*E_(i);
          if (i < m-1) { g = sl*E_(i+1); E_(i+1) = cl*E_(i+1); }
          c1[k] = cr; s1[k] = sr; c2[k] = cl; s2[k] = sl;
        }
        E_(m-1) = f;
        k = 0;
        for (int i = ll; i <= m-1; ++i, ++k) rot_rows3(vt, i-1, i, c1[k], s1[k]);
        k = 0;
        for (int i = ll; i <= m-1; ++i, ++k) rot_cols3(u, i-1, i, c2[k], s2[k]);
        if (fabsf(E_(m-1)) <= thresh) E_(m-1) = 0.0f;
      } else {
        float f = (fabsf(D_(m)) - shift)*(copysignf(1.0f, D_(m)) + shift/D_(m));
        float g = E_(m-1);
        float cr, sr, cl, sl, r;
        float c1[2], s1[2], c2[2], s2[2];
        for (int i = m; i >= ll+1; --i) {
          slartg_f(f, g, cr, sr, r);
          if (i < m) E_(i) = r;
          f = cr*D_(i) + sr*E_(i-1);
          E_(i-1) = cr*E_(i-1) - sr*D_(i);
          g = sr*D_(i-1);
          D_(i-1) = cr*D_(i-1);
          slartg_f(f, g, cl, sl, r);
          D_(i) = r;
          f = cl*E_(i-1) + sl*D_(i-1);
          D_(i-1) = cl*D_(i-1) - sl*E_(i-1);
          if (i > ll+1) { g = sl*E_(i-2); E_(i-2) = cl*E_(i-2); }
          int slot = i - ll;
          c1[slot-1] = cr; s1[slot-1] = -sr; c2[slot-1] = cl; s2[slot-1] = -sl;
        }
        E_(ll) = f;
        if (fabsf(E_(ll)) <= thresh) E_(ll) = 0.0f;
        for (int j = m-ll; j >= 1; --j) rot_rows3(vt, ll+j-2, ll+j-1, c2[j-1], s2[j-1]);
        for (int j = m-ll; j >= 1; --j) rot_cols3(u,  ll+j-2, ll+j-1, c1[j-1], s1[j-1]);
      }
    }
  }

  for (int i = 1; i <= 3; ++i) {
    if (D_(i) < 0.0f) {
      D_(i) = -D_(i);
#pragma unroll
      for (int k = 0; k < 3; ++k) vt[i-1][k] = -vt[i-1][k];
    }
  }
  for (int i = 1; i <= 2; ++i) {
    int isub = 1; float smn = D_(1);
    for (int j = 2; j <= 4-i; ++j) {
      if (D_(j) <= smn) { isub = j; smn = D_(j); }
    }
    if (isub != 4-i) {
      D_(isub) = D_(4-i); D_(4-i) = smn;
#pragma unroll
      for (int k = 0; k < 3; ++k) { float tq = vt[isub-1][k]; vt[isub-1][k] = vt[4-i-1][k]; vt[4-i-1][k] = tq; }
#pragma unroll
      for (int k = 0; k < 3; ++k) { float tq = u[k][isub-1]; u[k][isub-1] = u[k][4-i-1]; u[k][4-i-1] = tq; }
    }
  }
}

__device__ void svd3_gesdd(const float Ain[3][3], float u[3][3], float vt[3][3]) {
  float a[3][3];
#pragma unroll
  for (int i = 0; i < 3; ++i)
#pragma unroll
    for (int j = 0; j < 3; ++j) a[i][j] = Ain[i][j];

  float d[3], e[2];
  float tq0 = 0.f, tq1 = 0.f, tp0 = 0.f;
  float v0a = 0.f, v0b = 0.f, v1a = 0.f, p0a = 0.f;

  {
    float alpha = a[0][0];
    float xn = sqrtf(a[1][0]*a[1][0] + a[2][0]*a[2][0]);
    if (xn == 0.0f) { tq0 = 0.0f; d[0] = alpha; }
    else {
      float beta = -copysignf(sqrtf(alpha*alpha + xn*xn), alpha);
      tq0 = (beta - alpha)/beta;
      float sc = 1.0f/(alpha - beta);
      v0a = a[1][0]*sc; v0b = a[2][0]*sc;
      d[0] = beta;
    }
#pragma unroll
    for (int j = 1; j < 3; ++j) {
      float w = (a[0][j] + v0a*a[1][j] + v0b*a[2][j])*tq0;
      a[0][j] -= w; a[1][j] -= w*v0a; a[2][j] -= w*v0b;
    }
  }
  {
    float alpha = a[0][1];
    float xn = fabsf(a[0][2]);
    if (xn == 0.0f) { tp0 = 0.0f; e[0] = alpha; }
    else {
      float beta = -copysignf(sqrtf(alpha*alpha + xn*xn), alpha);
      tp0 = (beta - alpha)/beta;
      p0a = a[0][2]/(alpha - beta);
      e[0] = beta;
    }
#pragma unroll
    for (int i = 1; i < 3; ++i) {
      float w = (a[i][1] + p0a*a[i][2])*tp0;
      a[i][1] -= w; a[i][2] -= w*p0a;
    }
  }
  {
    float alpha = a[1][1];
    float xn = fabsf(a[2][1]);
    if (xn == 0.0f) { tq1 = 0.0f; d[1] = alpha; }
    else {
      float beta = -copysignf(sqrtf(alpha*alpha + xn*xn), alpha);
      tq1 = (beta - alpha)/beta;
      v1a = a[2][1]/(alpha - beta);
      d[1] = beta;
    }
    float w = (a[1][2] + v1a*a[2][2])*tq1;
    a[1][2] -= w; a[2][2] -= w*v1a;
  }
  e[1] = a[1][2];
  d[2] = a[2][2];

  float ub[3][3] = {{1,0,0},{0,1,0},{0,0,1}};
  float vb[3][3] = {{1,0,0},{0,1,0},{0,0,1}};
  sbdsqr3(d, e, ub, vb);

#pragma unroll
  for (int j = 0; j < 3; ++j) {
    float w = (ub[1][j] + v1a*ub[2][j])*tq1;
    ub[1][j] -= w; ub[2][j] -= w*v1a;
  }
#pragma unroll
  for (int j = 0; j < 3; ++j) {
    float w = (ub[0][j] + v0a*ub[1][j] + v0b*ub[2][j])*tq0;
    ub[0][j] -= w; ub[1][j] -= w*v0a; ub[2][j] -= w*v0b;
  }
#pragma unroll
  for (int i = 0; i < 3; ++i) {
    float w = (vb[i][1] + p0a*vb[i][2])*tp0;
    vb[i][1] -= w; vb[i][2] -= w*p0a;
  }
#pragma unroll
  for (int i = 0; i < 3; ++i)
#pragma unroll
    for (int j = 0; j < 3; ++j) { u[i][j] = ub[i][j]; vt[i][j] = vb[i][j]; }
}

// =============================================================================
// bf16 helpers (RNE, manual)
// =============================================================================
__device__ __forceinline__ unsigned short f2bf(float x) {
  unsigned int u = __float_as_uint(x);
  unsigned int r = (u + 0x7FFFu + ((u >> 16) & 1u)) >> 16;
  return (unsigned short)r;
}
__device__ __forceinline__ float bf2f(unsigned short h) {
  return __uint_as_float(((unsigned int)h) << 16);
}

// =============================================================================
// Kernel 0: pack.  Qp row: [qh(16)|ql(16)] (pre-scaled 0.25*log2e); Kp row:
// [kh(16)|kl(16)]; Vp row: float4. 256 blocks x 128 thr = 1 thread per (b,n).
// =============================================================================
__global__ __launch_bounds__(128)
void pack_kernel(const float* __restrict__ srcE, const float* __restrict__ tgtE,
                 const float* __restrict__ tgt,
                 unsigned short* __restrict__ Qp, unsigned short* __restrict__ Kp,
                 float4* __restrict__ Vp) {
  const int g = blockIdx.x*128 + threadIdx.x;   // 32768 = 16*2048
  const int b = g >> 11, n = g & 2047;
  const float* qs = srcE + (size_t)b*16*2048 + n;
  const float* ks = tgtE + (size_t)b*16*2048 + n;
  const float QSCALE = 0.25f * 1.44269504088896340736f;  // fold 1/4 and 1/ln2

  unsigned short qrow[32], krow[32];
#pragma unroll
  for (int dd = 0; dd < 16; ++dd) {
    float q = qs[dd*2048] * QSCALE;
    unsigned short qh = f2bf(q);
    qrow[dd] = qh; qrow[16+dd] = f2bf(q - bf2f(qh));
    float k = ks[dd*2048];
    unsigned short kh = f2bf(k);
    krow[dd] = kh; krow[16+dd] = f2bf(k - bf2f(kh));
  }
  uint4* qdst = (uint4*)(Qp + (size_t)g*32);
  uint4* kdst = (uint4*)(Kp + (size_t)g*32);
#pragma unroll
  for (int i = 0; i < 4; ++i) { qdst[i] = ((uint4*)qrow)[i]; kdst[i] = ((uint4*)krow)[i]; }

  const float* vp = tgt + (size_t)b*3*2048 + n;
  Vp[g] = make_float4(vp[0], vp[2048], vp[4096], 0.f);
}

// =============================================================================
// Kernel 1: MFMA flash attention + per-(b,ntile16) partial stats.
// grid = 2048: bid = nt*16 + b (bid%8==b%8 -> one XCD's L2 holds 2 batches).
// block = 256 (4 waves), ONE 16-n tile, all 2048 m; wave w: m-tiles w,w+4,...
// Lean registers (target <=85 VGPR -> 6+ waves/SIMD). A2 operand of the
// split-bf16 second MFMA equals A1 (its B upper half is zero), so no selects.
// =============================================================================
__global__ __launch_bounds__(256, 6)
void corr_kernel(const unsigned short* __restrict__ Qp, const unsigned short* __restrict__ Kp,
                 const float4* __restrict__ Vp, const float* __restrict__ src,
                 float* __restrict__ ws) {
  const int bid = blockIdx.x;
  const int b   = bid & 15;
  const int nt  = bid >> 4;          // 0..127, 16 n each
  const int tid = threadIdx.x;
  const int w   = tid >> 6;          // 0..3
  const int L   = tid & 63;
  const int lg  = L >> 4;
  const int ll  = L & 15;

  __shared__ __align__(16) float4 partial[4][16];   // 1 KB

  const unsigned short* Qb = Qp + (size_t)b*2048*32;
  const unsigned short* Kb = Kp + (size_t)b*2048*32;
  const float4* Vb = Vp + (size_t)b*2048;

  // ---- Q-fragments for this block's n-tile (registers) ----
  const bf16x8 zero8 = {0,0,0,0,0,0,0,0};
  const unsigned short* qr = Qb + (size_t)(nt*16 + ll)*32;
  bf16x8 bq1 = *(const bf16x8*)(qr + (lg & 1)*8);            // [qh|qh]
  bf16x8 bq2 = (lg < 2) ? *(const bf16x8*)(qr + 16 + (lg & 1)*8) : zero8;  // [ql|0]

  f32x4 acc = (f32x4){0.f, 0.f, 0.f, 0.f};

  for (int mt = w; mt < 128; mt += 4) {
    const unsigned short* ar = Kb + (size_t)(mt*16 + ll)*32;
    bf16x8 a1 = *(const bf16x8*)(ar + lg*8);                 // [kh|kl]
    const int vr = mt*16 + lg*4;
    float4 v0 = Vb[vr + 0];
    float4 v1 = Vb[vr + 1];
    float4 v2 = Vb[vr + 2];
    float4 v3 = Vb[vr + 3];
    f32x4 c = (f32x4){0.f, 0.f, 0.f, 0.f};
    c = __builtin_amdgcn_mfma_f32_16x16x32_bf16(a1, bq1, c, 0, 0, 0);
    c = __builtin_amdgcn_mfma_f32_16x16x32_bf16(a1, bq2, c, 0, 0, 0);  // bq2 hi=0
    // C/D: col n = ll, row m = mt*16 + lg*4 + r
    float e0 = __builtin_amdgcn_exp2f(c.x);
    float e1 = __builtin_amdgcn_exp2f(c.y);
    float e2 = __builtin_amdgcn_exp2f(c.z);
    float e3 = __builtin_amdgcn_exp2f(c.w);
    acc.x += (e0 + e1) + (e2 + e3);
    acc.y += e0*v0.x + e1*v1.x + e2*v2.x + e3*v3.x;
    acc.z += e0*v0.y + e1*v1.y + e2*v2.y + e3*v3.y;
    acc.w += e0*v0.z + e1*v1.z + e2*v2.z + e3*v3.z;
  }

  // ---- reduce across the 4 lane-groups ----
  {
    float x = acc.x, y = acc.y, z = acc.z, ww = acc.w;
    x += __shfl_xor(x, 16); x += __shfl_xor(x, 32);
    y += __shfl_xor(y, 16); y += __shfl_xor(y, 32);
    z += __shfl_xor(z, 16); z += __shfl_xor(z, 32);
    ww += __shfl_xor(ww, 16); ww += __shfl_xor(ww, 32);
    if (lg == 0) partial[w][ll] = make_float4(x, y, z, ww);
  }
  __syncthreads();

  // ---- per-n finish + 15-value single-wave reduction (wave 0 only) ----
  if (tid < 64) {
    float vals[15];
#pragma unroll
    for (int k = 0; k < 15; ++k) vals[k] = 0.f;
    if (tid < 16) {
      float4 s4 = make_float4(0.f, 0.f, 0.f, 0.f);
#pragma unroll
      for (int w2 = 0; w2 < 4; ++w2) {
        float4 p = partial[w2][tid];
        s4.x += p.x; s4.y += p.y; s4.z += p.z; s4.w += p.w;
      }
      float inv = 1.0f / s4.x;
      float c0 = s4.y*inv, c1 = s4.z*inv, c2 = s4.w*inv;
      const int n = nt*16 + tid;
      const float* sp = src + (size_t)b*3*2048;
      float s0v = sp[n], s1v = sp[2048+n], s2v = sp[4096+n];
      vals[0]=c0; vals[1]=c1; vals[2]=c2; vals[3]=s0v; vals[4]=s1v; vals[5]=s2v;
      vals[6]=s0v*c0; vals[7]=s0v*c1; vals[8]=s0v*c2;
      vals[9]=s1v*c0; vals[10]=s1v*c1; vals[11]=s1v*c2;
      vals[12]=s2v*c0; vals[13]=s2v*c1; vals[14]=s2v*c2;
    }
#pragma unroll
    for (int k = 0; k < 15; ++k) {
      float v = vals[k];
      v += __shfl_xor(v, 1);  v += __shfl_xor(v, 2);  v += __shfl_xor(v, 4);
      v += __shfl_xor(v, 8);  v += __shfl_xor(v, 16); v += __shfl_xor(v, 32);
      vals[k] = v;
    }
    if (tid == 0) {
#pragma unroll
      for (int k = 0; k < 15; ++k) ws[bid*16 + k] = vals[k];
    }
  }
}

// =============================================================================
// Kernel 2: ONE block, 16 waves; wave w = batch w; lane 0 runs the SVD.
// =============================================================================
__global__ __launch_bounds__(1024)
void finalize_kernel(const float* __restrict__ ws, float* __restrict__ out) {
  const int b = threadIdx.x >> 6;
  const int L = threadIdx.x & 63;

  float a = 0.0f;
  if (L < 15) {
    for (int ntile = 0; ntile < 128; ++ntile)
      a += ws[(ntile*16 + b)*16 + L];
  }
  float acc[15];
#pragma unroll
  for (int k = 0; k < 15; ++k) acc[k] = __shfl(a, k);

  if (L == 0) {
    const float invN = 1.0f/2048.0f;
    float Sc[3] = {acc[0], acc[1], acc[2]};
    float Ss[3] = {acc[3], acc[4], acc[5]};
    float cm[3] = {Sc[0]*invN, Sc[1]*invN, Sc[2]*invN};
    float sm[3] = {Ss[0]*invN, Ss[1]*invN, Ss[2]*invN};

    float A[3][3];
#pragma unroll
    for (int i = 0; i < 3; ++i)
#pragma unroll
      for (int j = 0; j < 3; ++j)
        A[i][j] = acc[6 + i*3 + j] - Ss[i]*cm[j];

    float u[3][3], vt[3][3];
    svd3_gesdd(A, u, vt);

    float R[3][3];
#pragma unroll
    for (int i = 0; i < 3; ++i)
#pragma unroll
      for (int k = 0; k < 3; ++k)
        R[i][k] = vt[i][0]*u[k][0] + vt[i][1]*u[k][1] + vt[i][2]*u[k][2];

    float det = R[0][0]*(R[1][1]*R[2][2] - R[1][2]*R[2][1])
              - R[0][1]*(R[1][0]*R[2][2] - R[1][2]*R[2][0])
              + R[0][2]*(R[1][0]*R[2][1] - R[1][1]*R[2][0]);

    if (det < 0.0f) {
#pragma unroll
      for (int i = 0; i < 3; ++i)
#pragma unroll
        for (int k = 0; k < 3; ++k)
          R[i][k] -= 2.0f*vt[i][2]*u[k][2];
    }

    float tv[3];
#pragma unroll
    for (int i = 0; i < 3; ++i)
      tv[i] = -(R[i][0]*sm[0] + R[i][1]*sm[1] + R[i][2]*sm[2]) + cm[i];

#pragma unroll
    for (int i = 0; i < 3; ++i)
#pragma unroll
      for (int j = 0; j < 3; ++j)
        out[b*9 + i*3 + j] = R[i][j];
#pragma unroll
    for (int i = 0; i < 3; ++i)
      out[144 + b*3 + i] = tv[i];
  }
}

extern "C" void kernel_launch(void* const* d_in, const int* in_sizes, int n_in,
                              void* d_out, int out_size, void* d_ws, size_t ws_size,
                              hipStream_t stream) {
  const float* srcE = (const float*)d_in[0];
  const float* tgtE = (const float*)d_in[1];
  const float* src  = (const float*)d_in[2];
  const float* tgt  = (const float*)d_in[3];
  float* out = (float*)d_out;

  // ws layout: [0,128KB) partials (2048*16 f32) | Qp 2MB | Kp 2MB | Vp 512KB
  float* part = (float*)d_ws;
  unsigned short* Qp = (unsigned short*)((char*)d_ws + 131072);
  unsigned short* Kp = (unsigned short*)((char*)d_ws + 131072 + (size_t)16*2048*32*2);
  float4* Vp = (float4*)((char*)d_ws + 131072 + (size_t)2*16*2048*32*2);

  hipLaunchKernelGGL(pack_kernel, dim3(256), dim3(128), 0, stream, srcE, tgtE, tgt, Qp, Kp, Vp);
  hipLaunchKernelGGL(corr_kernel, dim3(2048), dim3(256), 0, stream, Qp, Kp, Vp, src, part);
  hipLaunchKernelGGL(finalize_kernel, dim3(1), dim3(1024), 0, stream, part, out);
}

// Round 8
// 61.348 us; speedup vs baseline: 1.4343x; 1.4343x over previous
//
#include <hip/hip_runtime.h>
#include <math.h>

// LAPACK >= 3.10 slartg convention (c >= 0). Flip to 0 to emulate <= 3.9.
#define NEW_SLARTG 1

typedef __attribute__((ext_vector_type(8))) short bf16x8;
typedef __attribute__((ext_vector_type(4))) float f32x4;

// =============================================================================
// LAPACK sgesdd emulation for 3x3 (f32), faithful sign conventions. (UNCHANGED)
// =============================================================================

__device__ __attribute__((noinline)) void slartg_f(float f, float g, float& c, float& s, float& r) {
#if NEW_SLARTG
  if (g == 0.0f) { c = 1.0f; s = 0.0f; r = f; }
  else if (f == 0.0f) { c = 0.0f; s = copysignf(1.0f, g); r = fabsf(g); }
  else {
    float d = sqrtf(f*f + g*g);
    c = fabsf(f) / d;
    r = copysignf(d, f);
    s = g / r;
  }
#else
  if (g == 0.0f) { c = 1.0f; s = 0.0f; r = f; }
  else if (f == 0.0f) { c = 0.0f; s = 1.0f; r = g; }
  else {
    float d = sqrtf(f*f + g*g);
    c = f / d; s = g / d; r = d;
    if (fabsf(f) > fabsf(g) && c < 0.0f) { c = -c; s = -s; r = -r; }
  }
#endif
}

__device__ __attribute__((noinline)) void slas2_f(float f, float g, float h, float& ssmin, float& ssmax) {
  float fa = fabsf(f), ga = fabsf(g), ha = fabsf(h);
  float fhmn = fminf(fa, ha), fhmx = fmaxf(fa, ha);
  if (fhmn == 0.0f) {
    ssmin = 0.0f;
    if (fhmx == 0.0f) ssmax = ga;
    else {
      float mn = fminf(fhmx, ga), mx = fmaxf(fhmx, ga);
      float qq = mn / mx;
      ssmax = mx * sqrtf(1.0f + qq*qq);
    }
  } else {
    if (ga < fhmx) {
      float as_ = 1.0f + fhmn/fhmx;
      float at_ = (fhmx - fhmn)/fhmx;
      float au_ = ga/fhmx; au_ = au_*au_;
      float c = 2.0f/(sqrtf(as_*as_ + au_) + sqrtf(at_*at_ + au_));
      ssmin = fhmn*c;
      ssmax = fhmx/c;
    } else {
      float au_ = fhmx/ga;
      if (au_ == 0.0f) {
        ssmin = (fhmn*fhmx)/ga;
        ssmax = ga;
      } else {
        float as_ = 1.0f + fhmn/fhmx;
        float at_ = (fhmx - fhmn)/fhmx;
        float t1 = as_*au_, t2 = at_*au_;
        float c = 1.0f/(sqrtf(1.0f + t1*t1) + sqrtf(1.0f + t2*t2));
        ssmin = (fhmn*c)*au_;
        ssmin = ssmin + ssmin;
        ssmax = ga/(c + c);
      }
    }
  }
}

__device__ __attribute__((noinline)) void slasv2_f(float f, float g, float h,
                         float& ssmin, float& ssmax,
                         float& snr, float& csr, float& snl, float& csl) {
  const float eps = 5.9604645e-08f;
  float ft = f, fa = fabsf(f), ht = h, ha = fabsf(h);
  int pmax = 1;
  bool swap_ = (ha > fa);
  if (swap_) {
    pmax = 3;
    float tq = ft; ft = ht; ht = tq;
    tq = fa; fa = ha; ha = tq;
  }
  float gt = g, ga = fabsf(g);
  float clt = 0.f, crt = 0.f, slt = 0.f, srt = 0.f;
  if (ga == 0.0f) {
    ssmin = ha; ssmax = fa;
    clt = 1.0f; crt = 1.0f; slt = 0.0f; srt = 0.0f;
  } else {
    bool gasmal = true;
    if (ga > fa) {
      pmax = 2;
      if ((fa/ga) < eps) {
        gasmal = false;
        ssmax = ga;
        ssmin = (ha > 1.0f) ? (fa/(ga/ha)) : ((fa/ga)*ha);
        clt = 1.0f; slt = ht/gt; srt = 1.0f; crt = ft/gt;
      }
    }
    if (gasmal) {
      float dd = fa - ha;
      float l = (dd == fa) ? 1.0f : (dd/fa);
      float mr = gt/ft;
      float t = 2.0f - l;
      float mm2 = mr*mr, tt = t*t;
      float s_ = sqrtf(tt + mm2);
      float r_ = (l == 0.0f) ? fabsf(mr) : sqrtf(l*l + mm2);
      float a_ = 0.5f*(s_ + r_);
      ssmin = ha/a_;
      ssmax = fa*a_;
      if (mm2 == 0.0f) {
        if (l == 0.0f) t = copysignf(2.0f, ft)*copysignf(1.0f, gt);
        else t = gt/copysignf(dd, ft) + mr/t;
      } else {
        t = (mr/(s_ + t) + mr/(r_ + l))*(1.0f + a_);
      }
      float l2 = sqrtf(t*t + 4.0f);
      crt = 2.0f/l2;
      srt = t/l2;
      clt = (crt + srt*mr)/a_;
      slt = (ht/ft)*srt/a_;
    }
  }
  if (swap_) { csl = srt; snl = crt; csr = slt; snr = clt; }
  else       { csl = clt; snl = slt; csr = crt; snr = srt; }
  float tsign = 0.f;
  if (pmax == 1) tsign = copysignf(1.0f, csr)*copysignf(1.0f, csl)*copysignf(1.0f, f);
  if (pmax == 2) tsign = copysignf(1.0f, snr)*copysignf(1.0f, csl)*copysignf(1.0f, g);
  if (pmax == 3) tsign = copysignf(1.0f, snr)*copysignf(1.0f, snl)*copysignf(1.0f, h);
  ssmax = copysignf(ssmax, tsign);
  ssmin = copysignf(ssmin, tsign*copysignf(1.0f, f)*copysignf(1.0f, h));
}

__device__ __forceinline__ void rot_rows3(float mt[3][3], int r1, int r2, float c, float s) {
#pragma unroll
  for (int k = 0; k < 3; ++k) {
    float x = mt[r1][k], y = mt[r2][k];
    mt[r1][k] = c*x + s*y;
    mt[r2][k] = c*y - s*x;
  }
}
__device__ __forceinline__ void rot_cols3(float mt[3][3], int c1_, int c2_, float c, float s) {
#pragma unroll
  for (int k = 0; k < 3; ++k) {
    float x = mt[k][c1_], y = mt[k][c2_];
    mt[k][c1_] = c*x + s*y;
    mt[k][c2_] = c*y - s*x;
  }
}

#define D_(i) d[(i)-1]
#define E_(i) e[(i)-1]

__device__ void sbdsqr3(float* d, float* e, float u[3][3], float vt[3][3]) {
  const float eps  = 5.9604645e-08f;
  const float unfl = 1.17549435e-38f;
  const float tol  = 10.0f*eps;

  float sminoa = fabsf(d[0]);
  if (sminoa != 0.0f) {
    float mu = sminoa;
    mu = fabsf(d[1])*(mu/(mu + fabsf(e[0])));
    sminoa = fminf(sminoa, mu);
    if (sminoa != 0.0f) {
      mu = fabsf(d[2])*(mu/(mu + fabsf(e[1])));
      sminoa = fminf(sminoa, mu);
    }
  }
  sminoa = sminoa / sqrtf(3.0f);
  float thresh = fmaxf(tol*sminoa, 54.0f*unfl);

  int m = 3, oldll = -1, oldm = -1, idir = 0;
  int guard = 0;
  while (m > 1 && ++guard < 200) {
    float smax = fabsf(D_(m));
    int ll = 1; bool split = false;
    for (int lll = 1; lll <= m-1; ++lll) {
      int l2 = m - lll;
      float abss = fabsf(D_(l2)), abse = fabsf(E_(l2));
      if (abse <= thresh) { ll = l2; split = true; break; }
      smax = fmaxf(smax, fmaxf(abss, abse));
    }
    if (split) {
      E_(ll) = 0.0f;
      if (ll == m-1) { m = m - 1; continue; }
      ll = ll + 1;
    } else ll = 1;

    if (ll == m-1) {
      float sigmn, sigmx, sinr, cosr, sinl, cosl;
      slasv2_f(D_(m-1), E_(m-1), D_(m), sigmn, sigmx, sinr, cosr, sinl, cosl);
      D_(m-1) = sigmx; D_(m) = sigmn; E_(m-1) = 0.0f;
      rot_rows3(vt, m-2, m-1, cosr, sinr);
      rot_cols3(u,  m-2, m-1, cosl, sinl);
      m -= 2; continue;
    }

    if (ll > oldm || m < oldll)
      idir = (fabsf(D_(ll)) >= fabsf(D_(m))) ? 1 : 2;

    float sminl = 0.0f;
    bool deflated = false;
    if (idir == 1) {
      if (fabsf(E_(m-1)) <= tol*fabsf(D_(m))) { E_(m-1) = 0.0f; continue; }
      float mu = fabsf(D_(ll)); sminl = mu;
      for (int lll = ll; lll <= m-1; ++lll) {
        if (fabsf(E_(lll)) <= tol*mu) { E_(lll) = 0.0f; deflated = true; break; }
        mu = fabsf(D_(lll+1))*(mu/(mu + fabsf(E_(lll))));
        sminl = fminf(sminl, mu);
      }
    } else {
      if (fabsf(E_(ll)) <= tol*fabsf(D_(ll))) { E_(ll) = 0.0f; continue; }
      float mu = fabsf(D_(m)); sminl = mu;
      for (int lll = m-1; lll >= ll; --lll) {
        if (fabsf(E_(lll)) <= tol*mu) { E_(lll) = 0.0f; deflated = true; break; }
        mu = fabsf(D_(lll))*(mu/(mu + fabsf(E_(lll))));
        sminl = fminf(sminl, mu);
      }
    }
    if (deflated) continue;
    oldll = ll; oldm = m;

    float shift = 0.0f, rdum;
    if (!(3.0f*tol*(sminl/smax) <= fmaxf(eps, 0.01f*tol))) {
      float sll;
      if (idir == 1) { sll = fabsf(D_(ll)); slas2_f(D_(m-1), E_(m-1), D_(m), shift, rdum); }
      else           { sll = fabsf(D_(m));  slas2_f(D_(ll), E_(ll), D_(ll+1), shift, rdum); }
      if (sll > 0.0f) { float qq = shift/sll; if (qq*qq < eps) shift = 0.0f; }
    }

    if (shift == 0.0f) {
      if (idir == 1) {
        float cs = 1.0f, oldcs = 1.0f, sn = 0.0f, oldsn = 0.0f, r;
        float c1[2], s1[2], c2[2], s2[2];
        int k = 0;
        for (int i = ll; i <= m-1; ++i, ++k) {
          float fin = D_(i)*cs;
          slartg_f(fin, E_(i), cs, sn, r);
          if (i > ll) E_(i-1) = oldsn*r;
          float f2 = oldcs*r, g2 = D_(i+1)*sn;
          slartg_f(f2, g2, oldcs, oldsn, D_(i));
          c1[k] = cs; s1[k] = sn; c2[k] = oldcs; s2[k] = oldsn;
        }
        float h = D_(m)*cs;
        D_(m) = h*oldcs;
        E_(m-1) = h*oldsn;
        k = 0;
        for (int i = ll; i <= m-1; ++i, ++k) rot_rows3(vt, i-1, i, c1[k], s1[k]);
        k = 0;
        for (int i = ll; i <= m-1; ++i, ++k) rot_cols3(u, i-1, i, c2[k], s2[k]);
        if (fabsf(E_(m-1)) <= thresh) E_(m-1) = 0.0f;
      } else {
        float cs = 1.0f, oldcs = 1.0f, sn = 0.0f, oldsn = 0.0f, r;
        float c1[2], s1[2], c2[2], s2[2];
        for (int i = m; i >= ll+1; --i) {
          float fin = D_(i)*cs;
          slartg_f(fin, E_(i-1), cs, sn, r);
          if (i < m) E_(i) = oldsn*r;
          float f2 = oldcs*r, g2 = D_(i-1)*sn;
          slartg_f(f2, g2, oldcs, oldsn, D_(i));
          int slot = i - ll;
          c1[slot-1] = cs; s1[slot-1] = -sn; c2[slot-1] = oldcs; s2[slot-1] = -oldsn;
        }
        float h = D_(ll)*cs;
        D_(ll) = h*oldcs;
        E_(ll) = h*oldsn;
        for (int j = m-ll; j >= 1; --j) rot_rows3(vt, ll+j-2, ll+j-1, c2[j-1], s2[j-1]);
        for (int j = m-ll; j >= 1; --j) rot_cols3(u,  ll+j-2, ll+j-1, c1[j-1], s1[j-1]);
        if (fabsf(E_(ll)) <= thresh) E_(ll) = 0.0f;
      }
    } else {
      if (idir == 1) {
        float f = (fabsf(D_(ll)) - shift)*(copysignf(1.0f, D_(ll)) + shift/D_(ll));
        float g = E_(ll);
        float cr, sr, cl, sl, r;
        float c1[2], s1[2], c2[2], s2[2];
        int k = 0;
        for (int i = ll; i <= m-1; ++i, ++k) {
          slartg_f(f, g, cr, sr, r);
          if (i > ll) E_(i-1) = r;
          f = cr*D_(i) + sr*E_(i);
          E_(i) = cr*E_(i) - sr*D_(i);
          g = sr*D_(i+1);
          D_(i+1) = cr*D_(i+1);
          slartg_f(f, g, cl, sl, r);
          D_(i) = r;
          f = cl*E_(i) + sl*D_(i+1);
          D_(i+1) = cl*D_(i+1) - sl*E_(i);
          if (i < m-1) { g = sl*E_(i+1); E_(i+1) = cl*E_(i+1); }
          c1[k] = cr; s1[k] = sr; c2[k] = cl; s2[k] = sl;
        }
        E_(m-1) = f;
        k = 0;
        for (int i = ll; i <= m-1; ++i, ++k) rot_rows3(vt, i-1, i, c1[k], s1[k]);
        k = 0;
        for (int i = ll; i <= m-1; ++i, ++k) rot_cols3(u, i-1, i, c2[k], s2[k]);
        if (fabsf(E_(m-1)) <= thresh) E_(m-1) = 0.0f;
      } else {
        float f = (fabsf(D_(m)) - shift)*(copysignf(1.0f, D_(m)) + shift/D_(m));
        float g = E_(m-1);
        float cr, sr, cl, sl, r;
        float c1[2], s1[2], c2[2], s2[2];
        for (int i = m; i >= ll+1; --i) {
          slartg_f(f, g, cr, sr, r);
          if (i < m) E_(i) = r;
          f = cr*D_(i) + sr*E_(i-1);
          E_(i-1) = cr*E_(i-1) - sr*D_(i);
          g = sr*D_(i-1);
          D_(i-1) = cr*D_(i-1);
          slartg_f(f, g, cl, sl, r);
          D_(i) = r;
          f = cl*E_(i-1) + sl*D_(i-1);
          D_(i-1) = cl*D_(i-1) - sl*E_(i-1);
          if (i > ll+1) { g = sl*E_(i-2); E_(i-2) = cl*E_(i-2); }
          int slot = i - ll;
          c1[slot-1] = cr; s1[slot-1] = -sr; c2[slot-1] = cl; s2[slot-1] = -sl;
        }
        E_(ll) = f;
        if (fabsf(E_(ll)) <= thresh) E_(ll) = 0.0f;
        for (int j = m-ll; j >= 1; --j) rot_rows3(vt, ll+j-2, ll+j-1, c2[j-1], s2[j-1]);
        for (int j = m-ll; j >= 1; --j) rot_cols3(u,  ll+j-2, ll+j-1, c1[j-1], s1[j-1]);
      }
    }
  }

  for (int i = 1; i <= 3; ++i) {
    if (D_(i) < 0.0f) {
      D_(i) = -D_(i);
#pragma unroll
      for (int k = 0; k < 3; ++k) vt[i-1][k] = -vt[i-1][k];
    }
  }
  for (int i = 1; i <= 2; ++i) {
    int isub = 1; float smn = D_(1);
    for (int j = 2; j <= 4-i; ++j) {
      if (D_(j) <= smn) { isub = j; smn = D_(j); }
    }
    if (isub != 4-i) {
      D_(isub) = D_(4-i); D_(4-i) = smn;
#pragma unroll
      for (int k = 0; k < 3; ++k) { float tq = vt[isub-1][k]; vt[isub-1][k] = vt[4-i-1][k]; vt[4-i-1][k] = tq; }
#pragma unroll
      for (int k = 0; k < 3; ++k) { float tq = u[k][isub-1]; u[k][isub-1] = u[k][4-i-1]; u[k][4-i-1] = tq; }
    }
  }
}

__device__ void svd3_gesdd(const float Ain[3][3], float u[3][3], float vt[3][3]) {
  float a[3][3];
#pragma unroll
  for (int i = 0; i < 3; ++i)
#pragma unroll
    for (int j = 0; j < 3; ++j) a[i][j] = Ain[i][j];

  float d[3], e[2];
  float tq0 = 0.f, tq1 = 0.f, tp0 = 0.f;
  float v0a = 0.f, v0b = 0.f, v1a = 0.f, p0a = 0.f;

  {
    float alpha = a[0][0];
    float xn = sqrtf(a[1][0]*a[1][0] + a[2][0]*a[2][0]);
    if (xn == 0.0f) { tq0 = 0.0f; d[0] = alpha; }
    else {
      float beta = -copysignf(sqrtf(alpha*alpha + xn*xn), alpha);
      tq0 = (beta - alpha)/beta;
      float sc = 1.0f/(alpha - beta);
      v0a = a[1][0]*sc; v0b = a[2][0]*sc;
      d[0] = beta;
    }
#pragma unroll
    for (int j = 1; j < 3; ++j) {
      float w = (a[0][j] + v0a*a[1][j] + v0b*a[2][j])*tq0;
      a[0][j] -= w; a[1][j] -= w*v0a; a[2][j] -= w*v0b;
    }
  }
  {
    float alpha = a[0][1];
    float xn = fabsf(a[0][2]);
    if (xn == 0.0f) { tp0 = 0.0f; e[0] = alpha; }
    else {
      float beta = -copysignf(sqrtf(alpha*alpha + xn*xn), alpha);
      tp0 = (beta - alpha)/beta;
      p0a = a[0][2]/(alpha - beta);
      e[0] = beta;
    }
#pragma unroll
    for (int i = 1; i < 3; ++i) {
      float w = (a[i][1] + p0a*a[i][2])*tp0;
      a[i][1] -= w; a[i][2] -= w*p0a;
    }
  }
  {
    float alpha = a[1][1];
    float xn = fabsf(a[2][1]);
    if (xn == 0.0f) { tq1 = 0.0f; d[1] = alpha; }
    else {
      float beta = -copysignf(sqrtf(alpha*alpha + xn*xn), alpha);
      tq1 = (beta - alpha)/beta;
      v1a = a[2][1]/(alpha - beta);
      d[1] = beta;
    }
    float w = (a[1][2] + v1a*a[2][2])*tq1;
    a[1][2] -= w; a[2][2] -= w*v1a;
  }
  e[1] = a[1][2];
  d[2] = a[2][2];

  float ub[3][3] = {{1,0,0},{0,1,0},{0,0,1}};
  float vb[3][3] = {{1,0,0},{0,1,0},{0,0,1}};
  sbdsqr3(d, e, ub, vb);

#pragma unroll
  for (int j = 0; j < 3; ++j) {
    float w = (ub[1][j] + v1a*ub[2][j])*tq1;
    ub[1][j] -= w; ub[2][j] -= w*v1a;
  }
#pragma unroll
  for (int j = 0; j < 3; ++j) {
    float w = (ub[0][j] + v0a*ub[1][j] + v0b*ub[2][j])*tq0;
    ub[0][j] -= w; ub[1][j] -= w*v0a; ub[2][j] -= w*v0b;
  }
#pragma unroll
  for (int i = 0; i < 3; ++i) {
    float w = (vb[i][1] + p0a*vb[i][2])*tp0;
    vb[i][1] -= w; vb[i][2] -= w*p0a;
  }
#pragma unroll
  for (int i = 0; i < 3; ++i)
#pragma unroll
    for (int j = 0; j < 3; ++j) { u[i][j] = ub[i][j]; vt[i][j] = vb[i][j]; }
}

// =============================================================================
// bf16 helpers (RNE, manual — verified since round 1)
// =============================================================================
__device__ __forceinline__ unsigned int f2bf(float x) {
  unsigned int u = __float_as_uint(x);
  return (u + 0x7FFFu + ((u >> 16) & 1u)) >> 16;
}
__device__ __forceinline__ float bf2f(unsigned int h) {
  return __uint_as_float(h << 16);
}

// =============================================================================
// Kernel 0: pack.
//   Qp row (64B): [qh(16)|ql(16)]  (pre-scaled by 0.25*log2e)
//   Kp row (64B): [kh(16)|kl(16)]
//   W table (bf16): Vt4[b][4][2048]: row 0 = 1.0, rows 1..3 = tgt components.
// =============================================================================
__global__ __launch_bounds__(128)
void pack_kernel(const float* __restrict__ srcE, const float* __restrict__ tgtE,
                 const float* __restrict__ tgt,
                 unsigned short* __restrict__ Qp, unsigned short* __restrict__ Kp,
                 unsigned short* __restrict__ Vt4) {
  const int g = blockIdx.x*128 + threadIdx.x;   // 32768 = 16*2048
  const int b = g >> 11, n = g & 2047;
  const float* qs = srcE + (size_t)b*16*2048 + n;
  const float* ks = tgtE + (size_t)b*16*2048 + n;
  const float QSCALE = 0.25f * 1.44269504088896340736f;

  unsigned short qrow[32], krow[32];
#pragma unroll
  for (int dd = 0; dd < 16; ++dd) {
    float q = qs[dd*2048] * QSCALE;
    unsigned int qh = f2bf(q);
    qrow[dd] = (unsigned short)qh; qrow[16+dd] = (unsigned short)f2bf(q - bf2f(qh));
    float k = ks[dd*2048];
    unsigned int kh = f2bf(k);
    krow[dd] = (unsigned short)kh; krow[16+dd] = (unsigned short)f2bf(k - bf2f(kh));
  }
  uint4* qdst = (uint4*)(Qp + (size_t)g*32);
  uint4* kdst = (uint4*)(Kp + (size_t)g*32);
#pragma unroll
  for (int i = 0; i < 4; ++i) { qdst[i] = ((uint4*)qrow)[i]; kdst[i] = ((uint4*)krow)[i]; }

  const float* vp = tgt + (size_t)b*3*2048 + n;
  unsigned short* wb = Vt4 + (size_t)b*4*2048;
  wb[n]          = 0x3F80;             // ones column (j=0)
  wb[2048 + n]   = (unsigned short)f2bf(vp[0]);
  wb[2*2048 + n] = (unsigned short)f2bf(vp[2048]);
  wb[3*2048 + n] = (unsigned short)f2bf(vp[4096]);
}

// =============================================================================
// Kernel 1: MFMA flash attention; PV + softmax-sum ALSO via MFMA.
// grid = 512: bid = nt*16 + b. block = 512 (8 waves), 64 n per block.
// Wave w handles m-tile PAIRS p = w, w+8, ... (8 pairs = 16 m-tiles = 512 m).
// Per (pair, n-tile): 4 QK MFMAs (split-bf16) -> 8 exp2 -> f2bf pack ->
// wave-private LDS A'-staging (write P^T rows, read A'-frag b128) ->
// 1 PV MFMA vs W=[1|v0|v1|v2] (bf16, cols>=4 zero).
//   A' staging layout: A'[n][k] bf16 at byte n*64 + k*2 (k = tile*16 + m_loc).
//   write: lane(ll,lg) has P[m_loc=lg*4+r][n=ll]: uint2 at ll*64 + tile*32 + lg*8
//   read : lane(ll,lg) A'-frag = b128 at ll*64 + lg*16  (row=ll, k=lg*8+i)
// =============================================================================
__global__ __launch_bounds__(512, 4)
void corr_kernel(const unsigned short* __restrict__ Qp, const unsigned short* __restrict__ Kp,
                 const unsigned short* __restrict__ Vt4, const float* __restrict__ src,
                 float* __restrict__ ws) {
  const int bid = blockIdx.x;
  const int b   = bid & 15;
  const int nt  = bid >> 4;          // 0..31, 64 n each
  const int tid = threadIdx.x;
  const int w   = tid >> 6;
  const int L   = tid & 63;
  const int lg  = L >> 4;
  const int ll  = L & 15;

  __shared__ __align__(16) char  stage[8*1024];       // 8 KB: per-wave A' staging
  __shared__ __align__(16) float partial[8][64][4];   // 8 KB

  const unsigned short* Qb = Qp + (size_t)b*2048*32;
  const unsigned short* Kb = Kp + (size_t)b*2048*32;
  const unsigned short* Wb = Vt4 + (size_t)b*4*2048;

  const bf16x8 zero8 = {0,0,0,0,0,0,0,0};
  char* my = stage + w*1024;
  char* wr0 = my + ll*64 + lg*8;        // tile0 write slot
  char* wr1 = wr0 + 32;                 // tile1 write slot
  const char* rd = my + ll*64 + lg*16;  // A'-frag read slot

  // ---- Q-fragments for this block's 4 n-tiles ----
  bf16x8 bq1[4], bq2[4];
#pragma unroll
  for (int t2 = 0; t2 < 4; ++t2) {
    const unsigned short* qr = Qb + (size_t)(nt*64 + t2*16 + ll)*32;
    bq1[t2] = *(const bf16x8*)(qr + (lg & 1)*8);
    bf16x8 lo = *(const bf16x8*)(qr + 16 + (lg & 1)*8);
    bq2[t2] = (lg < 2) ? lo : zero8;
  }

  f32x4 accp[4];
#pragma unroll
  for (int t2 = 0; t2 < 4; ++t2) accp[t2] = (f32x4){0.f, 0.f, 0.f, 0.f};

  for (int p = w; p < 64; p += 8) {
    const unsigned short* ar = Kb + (size_t)(p*32 + ll)*32;
    bf16x8 a0 = *(const bf16x8*)(ar + lg*8);            // m-tile 2p
    bf16x8 a1 = *(const bf16x8*)(ar + 16*32 + lg*8);    // m-tile 2p+1
    bf16x8 wv = zero8;                                  // W B-frag (cols>=4 zero)
    if (ll < 4) wv = *(const bf16x8*)(Wb + (size_t)ll*2048 + p*32 + lg*8);

#pragma unroll
    for (int t2 = 0; t2 < 4; ++t2) {
      f32x4 c0 = (f32x4){0.f,0.f,0.f,0.f};
      f32x4 c1 = (f32x4){0.f,0.f,0.f,0.f};
      c0 = __builtin_amdgcn_mfma_f32_16x16x32_bf16(a0, bq1[t2], c0, 0, 0, 0);
      c0 = __builtin_amdgcn_mfma_f32_16x16x32_bf16(a0, bq2[t2], c0, 0, 0, 0);
      c1 = __builtin_amdgcn_mfma_f32_16x16x32_bf16(a1, bq1[t2], c1, 0, 0, 0);
      c1 = __builtin_amdgcn_mfma_f32_16x16x32_bf16(a1, bq2[t2], c1, 0, 0, 0);
      // P = exp2(scores); C-frag: row m_loc = lg*4+r, col n = ll
      float e0 = __builtin_amdgcn_exp2f(c0.x), e1 = __builtin_amdgcn_exp2f(c0.y);
      float e2 = __builtin_amdgcn_exp2f(c0.z), e3 = __builtin_amdgcn_exp2f(c0.w);
      float f0 = __builtin_amdgcn_exp2f(c1.x), f1 = __builtin_amdgcn_exp2f(c1.y);
      float f2 = __builtin_amdgcn_exp2f(c1.z), f3 = __builtin_amdgcn_exp2f(c1.w);
      // pack to bf16 pairs (lo = even r) and stage into A' layout
      *(uint2*)wr0 = make_uint2(f2bf(e0) | (f2bf(e1) << 16),
                                f2bf(e2) | (f2bf(e3) << 16));
      *(uint2*)wr1 = make_uint2(f2bf(f0) | (f2bf(f1) << 16),
                                f2bf(f2) | (f2bf(f3) << 16));
      bf16x8 pa = *(const bf16x8*)rd;   // A'[row=ll][k=lg*8..+7]
      // PV: X[n][j] += P^T x W   (j: 0=sumE, 1..3 = sum e*v)
      accp[t2] = __builtin_amdgcn_mfma_f32_16x16x32_bf16(pa, wv, accp[t2], 0, 0, 0);
    }
  }

  // ---- write per-wave partials: X[j=ll][n] for ll<4 ----
  if (ll < 4) {
#pragma unroll
    for (int t2 = 0; t2 < 4; ++t2) {
      int nb = t2*16 + lg*4;
      partial[w][nb+0][ll] = accp[t2].x;
      partial[w][nb+1][ll] = accp[t2].y;
      partial[w][nb+2][ll] = accp[t2].z;
      partial[w][nb+3][ll] = accp[t2].w;
    }
  }
  __syncthreads();

  // ---- per-n finish + 15-value single-wave reduction (wave 0 only) ----
  if (tid < 64) {
    float4 s4 = make_float4(0.f, 0.f, 0.f, 0.f);
#pragma unroll
    for (int w2 = 0; w2 < 8; ++w2) {
      float4 pq = *(const float4*)&partial[w2][tid][0];
      s4.x += pq.x; s4.y += pq.y; s4.z += pq.z; s4.w += pq.w;
    }
    float inv = 1.0f / s4.x;
    float c0 = s4.y*inv, c1 = s4.z*inv, c2 = s4.w*inv;
    const int n = nt*64 + tid;
    const float* sp = src + (size_t)b*3*2048;
    float s0v = sp[n], s1v = sp[2048+n], s2v = sp[4096+n];
    float vals[15] = { c0, c1, c2, s0v, s1v, s2v,
                       s0v*c0, s0v*c1, s0v*c2,
                       s1v*c0, s1v*c1, s1v*c2,
                       s2v*c0, s2v*c1, s2v*c2 };
#pragma unroll
    for (int k = 0; k < 15; ++k) {
      float v = vals[k];
      v += __shfl_xor(v, 1);  v += __shfl_xor(v, 2);  v += __shfl_xor(v, 4);
      v += __shfl_xor(v, 8);  v += __shfl_xor(v, 16); v += __shfl_xor(v, 32);
      vals[k] = v;
    }
    if (tid == 0) {
#pragma unroll
      for (int k = 0; k < 15; ++k) ws[bid*16 + k] = vals[k];
    }
  }
}

// =============================================================================
// Kernel 2: ONE block, 16 waves; wave w = batch w; lane 0 runs the SVD.
// =============================================================================
__global__ __launch_bounds__(1024)
void finalize_kernel(const float* __restrict__ ws, float* __restrict__ out) {
  const int b = threadIdx.x >> 6;
  const int L = threadIdx.x & 63;

  float a = 0.0f;
  if (L < 15) {
#pragma unroll
    for (int ntile = 0; ntile < 32; ++ntile)
      a += ws[(ntile*16 + b)*16 + L];
  }
  float acc[15];
#pragma unroll
  for (int k = 0; k < 15; ++k) acc[k] = __shfl(a, k);

  if (L == 0) {
    const float invN = 1.0f/2048.0f;
    float Sc[3] = {acc[0], acc[1], acc[2]};
    float Ss[3] = {acc[3], acc[4], acc[5]};
    float cm[3] = {Sc[0]*invN, Sc[1]*invN, Sc[2]*invN};
    float sm[3] = {Ss[0]*invN, Ss[1]*invN, Ss[2]*invN};

    float A[3][3];
#pragma unroll
    for (int i = 0; i < 3; ++i)
#pragma unroll
      for (int j = 0; j < 3; ++j)
        A[i][j] = acc[6 + i*3 + j] - Ss[i]*cm[j];

    float u[3][3], vt[3][3];
    svd3_gesdd(A, u, vt);

    float R[3][3];
#pragma unroll
    for (int i = 0; i < 3; ++i)
#pragma unroll
      for (int k = 0; k < 3; ++k)
        R[i][k] = vt[i][0]*u[k][0] + vt[i][1]*u[k][1] + vt[i][2]*u[k][2];

    float det = R[0][0]*(R[1][1]*R[2][2] - R[1][2]*R[2][1])
              - R[0][1]*(R[1][0]*R[2][2] - R[1][2]*R[2][0])
              + R[0][2]*(R[1][0]*R[2][1] - R[1][1]*R[2][0]);

    if (det < 0.0f) {
#pragma unroll
      for (int i = 0; i < 3; ++i)
#pragma unroll
        for (int k = 0; k < 3; ++k)
          R[i][k] -= 2.0f*vt[i][2]*u[k][2];
    }

    float tv[3];
#pragma unroll
    for (int i = 0; i < 3; ++i)
      tv[i] = -(R[i][0]*sm[0] + R[i][1]*sm[1] + R[i][2]*sm[2]) + cm[i];

#pragma unroll
    for (int i = 0; i < 3; ++i)
#pragma unroll
      for (int j = 0; j < 3; ++j)
        out[b*9 + i*3 + j] = R[i][j];
#pragma unroll
    for (int i = 0; i < 3; ++i)
      out[144 + b*3 + i] = tv[i];
  }
}

extern "C" void kernel_launch(void* const* d_in, const int* in_sizes, int n_in,
                              void* d_out, int out_size, void* d_ws, size_t ws_size,
                              hipStream_t stream) {
  const float* srcE = (const float*)d_in[0];
  const float* tgtE = (const float*)d_in[1];
  const float* src  = (const float*)d_in[2];
  const float* tgt  = (const float*)d_in[3];
  float* out = (float*)d_out;

  // ws layout: [0,32KB) partials | Qp 2MB | Kp 2MB | Vt4 256KB
  float* part = (float*)d_ws;
  unsigned short* Qp  = (unsigned short*)((char*)d_ws + 32768);
  unsigned short* Kp  = (unsigned short*)((char*)d_ws + 32768 + (size_t)16*2048*32*2);
  unsigned short* Vt4 = (unsigned short*)((char*)d_ws + 32768 + (size_t)2*16*2048*32*2);

  hipLaunchKernelGGL(pack_kernel, dim3(256), dim3(128), 0, stream, srcE, tgtE, tgt, Qp, Kp, Vt4);
  hipLaunchKernelGGL(corr_kernel, dim3(512), dim3(512), 0, stream, Qp, Kp, Vt4, src, part);
  hipLaunchKernelGGL(finalize_kernel, dim3(1), dim3(1024), 0, stream, part, out);
}

// Round 9
// 56.188 us; speedup vs baseline: 1.5660x; 1.0918x over previous
//
#include <hip/hip_runtime.h>
#include <math.h>

// LAPACK >= 3.10 slartg convention (c >= 0). Flip to 0 to emulate <= 3.9.
#define NEW_SLARTG 1

typedef __attribute__((ext_vector_type(8))) short bf16x8;
typedef __attribute__((ext_vector_type(4))) float f32x4;

// =============================================================================
// LAPACK sgesdd emulation for 3x3 (f32), faithful sign conventions.
// Leaf routines FORCEINLINE: by-ref out-params + noinline caused scratch
// round-trips per call (finalize 40us replayed, round 8). Inlined: reg-only.
// =============================================================================

__device__ __forceinline__ void slartg_f(float f, float g, float& c, float& s, float& r) {
#if NEW_SLARTG
  if (g == 0.0f) { c = 1.0f; s = 0.0f; r = f; }
  else if (f == 0.0f) { c = 0.0f; s = copysignf(1.0f, g); r = fabsf(g); }
  else {
    float d = sqrtf(f*f + g*g);
    c = fabsf(f) / d;
    r = copysignf(d, f);
    s = g / r;
  }
#else
  if (g == 0.0f) { c = 1.0f; s = 0.0f; r = f; }
  else if (f == 0.0f) { c = 0.0f; s = 1.0f; r = g; }
  else {
    float d = sqrtf(f*f + g*g);
    c = f / d; s = g / d; r = d;
    if (fabsf(f) > fabsf(g) && c < 0.0f) { c = -c; s = -s; r = -r; }
  }
#endif
}

__device__ __forceinline__ void slas2_f(float f, float g, float h, float& ssmin, float& ssmax) {
  float fa = fabsf(f), ga = fabsf(g), ha = fabsf(h);
  float fhmn = fminf(fa, ha), fhmx = fmaxf(fa, ha);
  if (fhmn == 0.0f) {
    ssmin = 0.0f;
    if (fhmx == 0.0f) ssmax = ga;
    else {
      float mn = fminf(fhmx, ga), mx = fmaxf(fhmx, ga);
      float qq = mn / mx;
      ssmax = mx * sqrtf(1.0f + qq*qq);
    }
  } else {
    if (ga < fhmx) {
      float as_ = 1.0f + fhmn/fhmx;
      float at_ = (fhmx - fhmn)/fhmx;
      float au_ = ga/fhmx; au_ = au_*au_;
      float c = 2.0f/(sqrtf(as_*as_ + au_) + sqrtf(at_*at_ + au_));
      ssmin = fhmn*c;
      ssmax = fhmx/c;
    } else {
      float au_ = fhmx/ga;
      if (au_ == 0.0f) {
        ssmin = (fhmn*fhmx)/ga;
        ssmax = ga;
      } else {
        float as_ = 1.0f + fhmn/fhmx;
        float at_ = (fhmx - fhmn)/fhmx;
        float t1 = as_*au_, t2 = at_*au_;
        float c = 1.0f/(sqrtf(1.0f + t1*t1) + sqrtf(1.0f + t2*t2));
        ssmin = (fhmn*c)*au_;
        ssmin = ssmin + ssmin;
        ssmax = ga/(c + c);
      }
    }
  }
}

__device__ __forceinline__ void slasv2_f(float f, float g, float h,
                         float& ssmin, float& ssmax,
                         float& snr, float& csr, float& snl, float& csl) {
  const float eps = 5.9604645e-08f;
  float ft = f, fa = fabsf(f), ht = h, ha = fabsf(h);
  int pmax = 1;
  bool swap_ = (ha > fa);
  if (swap_) {
    pmax = 3;
    float tq = ft; ft = ht; ht = tq;
    tq = fa; fa = ha; ha = tq;
  }
  float gt = g, ga = fabsf(g);
  float clt = 0.f, crt = 0.f, slt = 0.f, srt = 0.f;
  if (ga == 0.0f) {
    ssmin = ha; ssmax = fa;
    clt = 1.0f; crt = 1.0f; slt = 0.0f; srt = 0.0f;
  } else {
    bool gasmal = true;
    if (ga > fa) {
      pmax = 2;
      if ((fa/ga) < eps) {
        gasmal = false;
        ssmax = ga;
        ssmin = (ha > 1.0f) ? (fa/(ga/ha)) : ((fa/ga)*ha);
        clt = 1.0f; slt = ht/gt; srt = 1.0f; crt = ft/gt;
      }
    }
    if (gasmal) {
      float dd = fa - ha;
      float l = (dd == fa) ? 1.0f : (dd/fa);
      float mr = gt/ft;
      float t = 2.0f - l;
      float mm2 = mr*mr, tt = t*t;
      float s_ = sqrtf(tt + mm2);
      float r_ = (l == 0.0f) ? fabsf(mr) : sqrtf(l*l + mm2);
      float a_ = 0.5f*(s_ + r_);
      ssmin = ha/a_;
      ssmax = fa*a_;
      if (mm2 == 0.0f) {
        if (l == 0.0f) t = copysignf(2.0f, ft)*copysignf(1.0f, gt);
        else t = gt/copysignf(dd, ft) + mr/t;
      } else {
        t = (mr/(s_ + t) + mr/(r_ + l))*(1.0f + a_);
      }
      float l2 = sqrtf(t*t + 4.0f);
      crt = 2.0f/l2;
      srt = t/l2;
      clt = (crt + srt*mr)/a_;
      slt = (ht/ft)*srt/a_;
    }
  }
  if (swap_) { csl = srt; snl = crt; csr = slt; snr = clt; }
  else       { csl = clt; snl = slt; csr = crt; snr = srt; }
  float tsign = 0.f;
  if (pmax == 1) tsign = copysignf(1.0f, csr)*copysignf(1.0f, csl)*copysignf(1.0f, f);
  if (pmax == 2) tsign = copysignf(1.0f, snr)*copysignf(1.0f, csl)*copysignf(1.0f, g);
  if (pmax == 3) tsign = copysignf(1.0f, snr)*copysignf(1.0f, snl)*copysignf(1.0f, h);
  ssmax = copysignf(ssmax, tsign);
  ssmin = copysignf(ssmin, tsign*copysignf(1.0f, f)*copysignf(1.0f, h));
}

__device__ __forceinline__ void rot_rows3(float mt[3][3], int r1, int r2, float c, float s) {
#pragma unroll
  for (int k = 0; k < 3; ++k) {
    float x = mt[r1][k], y = mt[r2][k];
    mt[r1][k] = c*x + s*y;
    mt[r2][k] = c*y - s*x;
  }
}
__device__ __forceinline__ void rot_cols3(float mt[3][3], int c1_, int c2_, float c, float s) {
#pragma unroll
  for (int k = 0; k < 3; ++k) {
    float x = mt[k][c1_], y = mt[k][c2_];
    mt[k][c1_] = c*x + s*y;
    mt[k][c2_] = c*y - s*x;
  }
}

#define D_(i) d[(i)-1]
#define E_(i) e[(i)-1]

__device__ void sbdsqr3(float* d, float* e, float u[3][3], float vt[3][3]) {
  const float eps  = 5.9604645e-08f;
  const float unfl = 1.17549435e-38f;
  const float tol  = 10.0f*eps;

  float sminoa = fabsf(d[0]);
  if (sminoa != 0.0f) {
    float mu = sminoa;
    mu = fabsf(d[1])*(mu/(mu + fabsf(e[0])));
    sminoa = fminf(sminoa, mu);
    if (sminoa != 0.0f) {
      mu = fabsf(d[2])*(mu/(mu + fabsf(e[1])));
      sminoa = fminf(sminoa, mu);
    }
  }
  sminoa = sminoa / sqrtf(3.0f);
  float thresh = fmaxf(tol*sminoa, 54.0f*unfl);

  int m = 3, oldll = -1, oldm = -1, idir = 0;
  int guard = 0;
  while (m > 1 && ++guard < 200) {
    float smax = fabsf(D_(m));
    int ll = 1; bool split = false;
    for (int lll = 1; lll <= m-1; ++lll) {
      int l2 = m - lll;
      float abss = fabsf(D_(l2)), abse = fabsf(E_(l2));
      if (abse <= thresh) { ll = l2; split = true; break; }
      smax = fmaxf(smax, fmaxf(abss, abse));
    }
    if (split) {
      E_(ll) = 0.0f;
      if (ll == m-1) { m = m - 1; continue; }
      ll = ll + 1;
    } else ll = 1;

    if (ll == m-1) {
      float sigmn, sigmx, sinr, cosr, sinl, cosl;
      slasv2_f(D_(m-1), E_(m-1), D_(m), sigmn, sigmx, sinr, cosr, sinl, cosl);
      D_(m-1) = sigmx; D_(m) = sigmn; E_(m-1) = 0.0f;
      rot_rows3(vt, m-2, m-1, cosr, sinr);
      rot_cols3(u,  m-2, m-1, cosl, sinl);
      m -= 2; continue;
    }

    if (ll > oldm || m < oldll)
      idir = (fabsf(D_(ll)) >= fabsf(D_(m))) ? 1 : 2;

    float sminl = 0.0f;
    bool deflated = false;
    if (idir == 1) {
      if (fabsf(E_(m-1)) <= tol*fabsf(D_(m))) { E_(m-1) = 0.0f; continue; }
      float mu = fabsf(D_(ll)); sminl = mu;
      for (int lll = ll; lll <= m-1; ++lll) {
        if (fabsf(E_(lll)) <= tol*mu) { E_(lll) = 0.0f; deflated = true; break; }
        mu = fabsf(D_(lll+1))*(mu/(mu + fabsf(E_(lll))));
        sminl = fminf(sminl, mu);
      }
    } else {
      if (fabsf(E_(ll)) <= tol*fabsf(D_(ll))) { E_(ll) = 0.0f; continue; }
      float mu = fabsf(D_(m)); sminl = mu;
      for (int lll = m-1; lll >= ll; --lll) {
        if (fabsf(E_(lll)) <= tol*mu) { E_(lll) = 0.0f; deflated = true; break; }
        mu = fabsf(D_(lll))*(mu/(mu + fabsf(E_(lll))));
        sminl = fminf(sminl, mu);
      }
    }
    if (deflated) continue;
    oldll = ll; oldm = m;

    float shift = 0.0f, rdum;
    if (!(3.0f*tol*(sminl/smax) <= fmaxf(eps, 0.01f*tol))) {
      float sll;
      if (idir == 1) { sll = fabsf(D_(ll)); slas2_f(D_(m-1), E_(m-1), D_(m), shift, rdum); }
      else           { sll = fabsf(D_(m));  slas2_f(D_(ll), E_(ll), D_(ll+1), shift, rdum); }
      if (sll > 0.0f) { float qq = shift/sll; if (qq*qq < eps) shift = 0.0f; }
    }

    if (shift == 0.0f) {
      if (idir == 1) {
        float cs = 1.0f, oldcs = 1.0f, sn = 0.0f, oldsn = 0.0f, r;
        float c1[2], s1[2], c2[2], s2[2];
        int k = 0;
        for (int i = ll; i <= m-1; ++i, ++k) {
          float fin = D_(i)*cs;
          slartg_f(fin, E_(i), cs, sn, r);
          if (i > ll) E_(i-1) = oldsn*r;
          float f2 = oldcs*r, g2 = D_(i+1)*sn;
          slartg_f(f2, g2, oldcs, oldsn, D_(i));
          c1[k] = cs; s1[k] = sn; c2[k] = oldcs; s2[k] = oldsn;
        }
        float h = D_(m)*cs;
        D_(m) = h*oldcs;
        E_(m-1) = h*oldsn;
        k = 0;
        for (int i = ll; i <= m-1; ++i, ++k) rot_rows3(vt, i-1, i, c1[k], s1[k]);
        k = 0;
        for (int i = ll; i <= m-1; ++i, ++k) rot_cols3(u, i-1, i, c2[k], s2[k]);
        if (fabsf(E_(m-1)) <= thresh) E_(m-1) = 0.0f;
      } else {
        float cs = 1.0f, oldcs = 1.0f, sn = 0.0f, oldsn = 0.0f, r;
        float c1[2], s1[2], c2[2], s2[2];
        for (int i = m; i >= ll+1; --i) {
          float fin = D_(i)*cs;
          slartg_f(fin, E_(i-1), cs, sn, r);
          if (i < m) E_(i) = oldsn*r;
          float f2 = oldcs*r, g2 = D_(i-1)*sn;
          slartg_f(f2, g2, oldcs, oldsn, D_(i));
          int slot = i - ll;
          c1[slot-1] = cs; s1[slot-1] = -sn; c2[slot-1] = oldcs; s2[slot-1] = -oldsn;
        }
        float h = D_(ll)*cs;
        D_(ll) = h*oldcs;
        E_(ll) = h*oldsn;
        for (int j = m-ll; j >= 1; --j) rot_rows3(vt, ll+j-2, ll+j-1, c2[j-1], s2[j-1]);
        for (int j = m-ll; j >= 1; --j) rot_cols3(u,  ll+j-2, ll+j-1, c1[j-1], s1[j-1]);
        if (fabsf(E_(ll)) <= thresh) E_(ll) = 0.0f;
      }
    } else {
      if (idir == 1) {
        float f = (fabsf(D_(ll)) - shift)*(copysignf(1.0f, D_(ll)) + shift/D_(ll));
        float g = E_(ll);
        float cr, sr, cl, sl, r;
        float c1[2], s1[2], c2[2], s2[2];
        int k = 0;
        for (int i = ll; i <= m-1; ++i, ++k) {
          slartg_f(f, g, cr, sr, r);
          if (i > ll) E_(i-1) = r;
          f = cr*D_(i) + sr*E_(i);
          E_(i) = cr*E_(i) - sr*D_(i);
          g = sr*D_(i+1);
          D_(i+1) = cr*D_(i+1);
          slartg_f(f, g, cl, sl, r);
          D_(i) = r;
          f = cl*E_(i) + sl*D_(i+1);
          D_(i+1) = cl*D_(i+1) - sl*E_(i);
          if (i < m-1) { g = sl*E_(i+1); E_(i+1) = cl*E_(i+1); }
          c1[k] = cr; s1[k] = sr; c2[k] = cl; s2[k] = sl;
        }
        E_(m-1) = f;
        k = 0;
        for (int i = ll; i <= m-1; ++i, ++k) rot_rows3(vt, i-1, i, c1[k], s1[k]);
        k = 0;
        for (int i = ll; i <= m-1; ++i, ++k) rot_cols3(u, i-1, i, c2[k], s2[k]);
        if (fabsf(E_(m-1)) <= thresh) E_(m-1) = 0.0f;
      } else {
        float f = (fabsf(D_(m)) - shift)*(copysignf(1.0f, D_(m)) + shift/D_(m));
        float g = E_(m-1);
        float cr, sr, cl, sl, r;
        float c1[2], s1[2], c2[2], s2[2];
        for (int i = m; i >= ll+1; --i) {
          slartg_f(f, g, cr, sr, r);
          if (i < m) E_(i) = r;
          f = cr*D_(i) + sr*E_(i-1);
          E_(i-1) = cr*E_(i-1) - sr*D_(i);
          g = sr*D_(i-1);
          D_(i-1) = cr*D_(i-1);
          slartg_f(f, g, cl, sl, r);
          D_(i) = r;
          f = cl*E_(i-1) + sl*D_(i-1);
          D_(i-1) = cl*D_(i-1) - sl*E_(i-1);
          if (i > ll+1) { g = sl*E_(i-2); E_(i-2) = cl*E_(i-2); }
          int slot = i - ll;
          c1[slot-1] = cr; s1[slot-1] = -sr; c2[slot-1] = cl; s2[slot-1] = -sl;
        }
        E_(ll) = f;
        if (fabsf(E_(ll)) <= thresh) E_(ll) = 0.0f;
        for (int j = m-ll; j >= 1; --j) rot_rows3(vt, ll+j-2, ll+j-1, c2[j-1], s2[j-1]);
        for (int j = m-ll; j >= 1; --j) rot_cols3(u,  ll+j-2, ll+j-1, c1[j-1], s1[j-1]);
      }
    }
  }

  for (int i = 1; i <= 3; ++i) {
    if (D_(i) < 0.0f) {
      D_(i) = -D_(i);
#pragma unroll
      for (int k = 0; k < 3; ++k) vt[i-1][k] = -vt[i-1][k];
    }
  }
  for (int i = 1; i <= 2; ++i) {
    int isub = 1; float smn = D_(1);
    for (int j = 2; j <= 4-i; ++j) {
      if (D_(j) <= smn) { isub = j; smn = D_(j); }
    }
    if (isub != 4-i) {
      D_(isub) = D_(4-i); D_(4-i) = smn;
#pragma unroll
      for (int k = 0; k < 3; ++k) { float tq = vt[isub-1][k]; vt[isub-1][k] = vt[4-i-1][k]; vt[4-i-1][k] = tq; }
#pragma unroll
      for (int k = 0; k < 3; ++k) { float tq = u[k][isub-1]; u[k][isub-1] = u[k][4-i-1]; u[k][4-i-1] = tq; }
    }
  }
}

__device__ void svd3_gesdd(const float Ain[3][3], float u[3][3], float vt[3][3]) {
  float a[3][3];
#pragma unroll
  for (int i = 0; i < 3; ++i)
#pragma unroll
    for (int j = 0; j < 3; ++j) a[i][j] = Ain[i][j];

  float d[3], e[2];
  float tq0 = 0.f, tq1 = 0.f, tp0 = 0.f;
  float v0a = 0.f, v0b = 0.f, v1a = 0.f, p0a = 0.f;

  {
    float alpha = a[0][0];
    float xn = sqrtf(a[1][0]*a[1][0] + a[2][0]*a[2][0]);
    if (xn == 0.0f) { tq0 = 0.0f; d[0] = alpha; }
    else {
      float beta = -copysignf(sqrtf(alpha*alpha + xn*xn), alpha);
      tq0 = (beta - alpha)/beta;
      float sc = 1.0f/(alpha - beta);
      v0a = a[1][0]*sc; v0b = a[2][0]*sc;
      d[0] = beta;
    }
#pragma unroll
    for (int j = 1; j < 3; ++j) {
      float w = (a[0][j] + v0a*a[1][j] + v0b*a[2][j])*tq0;
      a[0][j] -= w; a[1][j] -= w*v0a; a[2][j] -= w*v0b;
    }
  }
  {
    float alpha = a[0][1];
    float xn = fabsf(a[0][2]);
    if (xn == 0.0f) { tp0 = 0.0f; e[0] = alpha; }
    else {
      float beta = -copysignf(sqrtf(alpha*alpha + xn*xn), alpha);
      tp0 = (beta - alpha)/beta;
      p0a = a[0][2]/(alpha - beta);
      e[0] = beta;
    }
#pragma unroll
    for (int i = 1; i < 3; ++i) {
      float w = (a[i][1] + p0a*a[i][2])*tp0;
      a[i][1] -= w; a[i][2] -= w*p0a;
    }
  }
  {
    float alpha = a[1][1];
    float xn = fabsf(a[2][1]);
    if (xn == 0.0f) { tq1 = 0.0f; d[1] = alpha; }
    else {
      float beta = -copysignf(sqrtf(alpha*alpha + xn*xn), alpha);
      tq1 = (beta - alpha)/beta;
      v1a = a[2][1]/(alpha - beta);
      d[1] = beta;
    }
    float w = (a[1][2] + v1a*a[2][2])*tq1;
    a[1][2] -= w; a[2][2] -= w*v1a;
  }
  e[1] = a[1][2];
  d[2] = a[2][2];

  float ub[3][3] = {{1,0,0},{0,1,0},{0,0,1}};
  float vb[3][3] = {{1,0,0},{0,1,0},{0,0,1}};
  sbdsqr3(d, e, ub, vb);

#pragma unroll
  for (int j = 0; j < 3; ++j) {
    float w = (ub[1][j] + v1a*ub[2][j])*tq1;
    ub[1][j] -= w; ub[2][j] -= w*v1a;
  }
#pragma unroll
  for (int j = 0; j < 3; ++j) {
    float w = (ub[0][j] + v0a*ub[1][j] + v0b*ub[2][j])*tq0;
    ub[0][j] -= w; ub[1][j] -= w*v0a; ub[2][j] -= w*v0b;
  }
#pragma unroll
  for (int i = 0; i < 3; ++i) {
    float w = (vb[i][1] + p0a*vb[i][2])*tp0;
    vb[i][1] -= w; vb[i][2] -= w*p0a;
  }
#pragma unroll
  for (int i = 0; i < 3; ++i)
#pragma unroll
    for (int j = 0; j < 3; ++j) { u[i][j] = ub[i][j]; vt[i][j] = vb[i][j]; }
}

// =============================================================================
// bf16 helpers (RNE, manual — verified since round 1)
// =============================================================================
__device__ __forceinline__ unsigned int f2bf(float x) {
  unsigned int u = __float_as_uint(x);
  return (u + 0x7FFFu + ((u >> 16) & 1u)) >> 16;
}
__device__ __forceinline__ float bf2f(unsigned int h) {
  return __uint_as_float(h << 16);
}

// =============================================================================
// Kernel 0: pack.
//   Qp row (64B): [qh(16)|ql(16)]  (pre-scaled by 0.25*log2e)
//   Kp row (64B): [kh(16)|kl(16)]
//   W table (bf16): Vt4[b][4][2048]: row 0 = 1.0, rows 1..3 = tgt components.
// =============================================================================
__global__ __launch_bounds__(128)
void pack_kernel(const float* __restrict__ srcE, const float* __restrict__ tgtE,
                 const float* __restrict__ tgt,
                 unsigned short* __restrict__ Qp, unsigned short* __restrict__ Kp,
                 unsigned short* __restrict__ Vt4) {
  const int g = blockIdx.x*128 + threadIdx.x;   // 32768 = 16*2048
  const int b = g >> 11, n = g & 2047;
  const float* qs = srcE + (size_t)b*16*2048 + n;
  const float* ks = tgtE + (size_t)b*16*2048 + n;
  const float QSCALE = 0.25f * 1.44269504088896340736f;

  unsigned short qrow[32], krow[32];
#pragma unroll
  for (int dd = 0; dd < 16; ++dd) {
    float q = qs[dd*2048] * QSCALE;
    unsigned int qh = f2bf(q);
    qrow[dd] = (unsigned short)qh; qrow[16+dd] = (unsigned short)f2bf(q - bf2f(qh));
    float k = ks[dd*2048];
    unsigned int kh = f2bf(k);
    krow[dd] = (unsigned short)kh; krow[16+dd] = (unsigned short)f2bf(k - bf2f(kh));
  }
  uint4* qdst = (uint4*)(Qp + (size_t)g*32);
  uint4* kdst = (uint4*)(Kp + (size_t)g*32);
#pragma unroll
  for (int i = 0; i < 4; ++i) { qdst[i] = ((uint4*)qrow)[i]; kdst[i] = ((uint4*)krow)[i]; }

  const float* vp = tgt + (size_t)b*3*2048 + n;
  unsigned short* wb = Vt4 + (size_t)b*4*2048;
  wb[n]          = 0x3F80;             // ones column (j=0)
  wb[2048 + n]   = (unsigned short)f2bf(vp[0]);
  wb[2*2048 + n] = (unsigned short)f2bf(vp[2048]);
  wb[3*2048 + n] = (unsigned short)f2bf(vp[4096]);
}

// =============================================================================
// Kernel 1: MFMA flash attention; PV + softmax-sum ALSO via MFMA. (round 8,
// passed, corr ~15us) — unchanged.
// =============================================================================
__global__ __launch_bounds__(512, 4)
void corr_kernel(const unsigned short* __restrict__ Qp, const unsigned short* __restrict__ Kp,
                 const unsigned short* __restrict__ Vt4, const float* __restrict__ src,
                 float* __restrict__ ws) {
  const int bid = blockIdx.x;
  const int b   = bid & 15;
  const int nt  = bid >> 4;          // 0..31, 64 n each
  const int tid = threadIdx.x;
  const int w   = tid >> 6;
  const int L   = tid & 63;
  const int lg  = L >> 4;
  const int ll  = L & 15;

  __shared__ __align__(16) char  stage[8*1024];       // 8 KB: per-wave A' staging
  __shared__ __align__(16) float partial[8][64][4];   // 8 KB

  const unsigned short* Qb = Qp + (size_t)b*2048*32;
  const unsigned short* Kb = Kp + (size_t)b*2048*32;
  const unsigned short* Wb = Vt4 + (size_t)b*4*2048;

  const bf16x8 zero8 = {0,0,0,0,0,0,0,0};
  char* my = stage + w*1024;
  char* wr0 = my + ll*64 + lg*8;        // tile0 write slot
  char* wr1 = wr0 + 32;                 // tile1 write slot
  const char* rd = my + ll*64 + lg*16;  // A'-frag read slot

  // ---- Q-fragments for this block's 4 n-tiles ----
  bf16x8 bq1[4], bq2[4];
#pragma unroll
  for (int t2 = 0; t2 < 4; ++t2) {
    const unsigned short* qr = Qb + (size_t)(nt*64 + t2*16 + ll)*32;
    bq1[t2] = *(const bf16x8*)(qr + (lg & 1)*8);
    bf16x8 lo = *(const bf16x8*)(qr + 16 + (lg & 1)*8);
    bq2[t2] = (lg < 2) ? lo : zero8;
  }

  f32x4 accp[4];
#pragma unroll
  for (int t2 = 0; t2 < 4; ++t2) accp[t2] = (f32x4){0.f, 0.f, 0.f, 0.f};

  for (int p = w; p < 64; p += 8) {
    const unsigned short* ar = Kb + (size_t)(p*32 + ll)*32;
    bf16x8 a0 = *(const bf16x8*)(ar + lg*8);            // m-tile 2p
    bf16x8 a1 = *(const bf16x8*)(ar + 16*32 + lg*8);    // m-tile 2p+1
    bf16x8 wv = zero8;                                  // W B-frag (cols>=4 zero)
    if (ll < 4) wv = *(const bf16x8*)(Wb + (size_t)ll*2048 + p*32 + lg*8);

#pragma unroll
    for (int t2 = 0; t2 < 4; ++t2) {
      f32x4 c0 = (f32x4){0.f,0.f,0.f,0.f};
      f32x4 c1 = (f32x4){0.f,0.f,0.f,0.f};
      c0 = __builtin_amdgcn_mfma_f32_16x16x32_bf16(a0, bq1[t2], c0, 0, 0, 0);
      c0 = __builtin_amdgcn_mfma_f32_16x16x32_bf16(a0, bq2[t2], c0, 0, 0, 0);
      c1 = __builtin_amdgcn_mfma_f32_16x16x32_bf16(a1, bq1[t2], c1, 0, 0, 0);
      c1 = __builtin_amdgcn_mfma_f32_16x16x32_bf16(a1, bq2[t2], c1, 0, 0, 0);
      // P = exp2(scores); C-frag: row m_loc = lg*4+r, col n = ll
      float e0 = __builtin_amdgcn_exp2f(c0.x), e1 = __builtin_amdgcn_exp2f(c0.y);
      float e2 = __builtin_amdgcn_exp2f(c0.z), e3 = __builtin_amdgcn_exp2f(c0.w);
      float f0 = __builtin_amdgcn_exp2f(c1.x), f1 = __builtin_amdgcn_exp2f(c1.y);
      float f2 = __builtin_amdgcn_exp2f(c1.z), f3 = __builtin_amdgcn_exp2f(c1.w);
      // pack to bf16 pairs (lo = even r) and stage into A' layout
      *(uint2*)wr0 = make_uint2(f2bf(e0) | (f2bf(e1) << 16),
                                f2bf(e2) | (f2bf(e3) << 16));
      *(uint2*)wr1 = make_uint2(f2bf(f0) | (f2bf(f1) << 16),
                                f2bf(f2) | (f2bf(f3) << 16));
      bf16x8 pa = *(const bf16x8*)rd;   // A'[row=ll][k=lg*8..+7]
      // PV: X[n][j] += P^T x W   (j: 0=sumE, 1..3 = sum e*v)
      accp[t2] = __builtin_amdgcn_mfma_f32_16x16x32_bf16(pa, wv, accp[t2], 0, 0, 0);
    }
  }

  // ---- write per-wave partials: X[j=ll][n] for ll<4 ----
  if (ll < 4) {
#pragma unroll
    for (int t2 = 0; t2 < 4; ++t2) {
      int nb = t2*16 + lg*4;
      partial[w][nb+0][ll] = accp[t2].x;
      partial[w][nb+1][ll] = accp[t2].y;
      partial[w][nb+2][ll] = accp[t2].z;
      partial[w][nb+3][ll] = accp[t2].w;
    }
  }
  __syncthreads();

  // ---- per-n finish + 15-value single-wave reduction (wave 0 only) ----
  if (tid < 64) {
    float4 s4 = make_float4(0.f, 0.f, 0.f, 0.f);
#pragma unroll
    for (int w2 = 0; w2 < 8; ++w2) {
      float4 pq = *(const float4*)&partial[w2][tid][0];
      s4.x += pq.x; s4.y += pq.y; s4.z += pq.z; s4.w += pq.w;
    }
    float inv = 1.0f / s4.x;
    float c0 = s4.y*inv, c1 = s4.z*inv, c2 = s4.w*inv;
    const int n = nt*64 + tid;
    const float* sp = src + (size_t)b*3*2048;
    float s0v = sp[n], s1v = sp[2048+n], s2v = sp[4096+n];
    float vals[15] = { c0, c1, c2, s0v, s1v, s2v,
                       s0v*c0, s0v*c1, s0v*c2,
                       s1v*c0, s1v*c1, s1v*c2,
                       s2v*c0, s2v*c1, s2v*c2 };
#pragma unroll
    for (int k = 0; k < 15; ++k) {
      float v = vals[k];
      v += __shfl_xor(v, 1);  v += __shfl_xor(v, 2);  v += __shfl_xor(v, 4);
      v += __shfl_xor(v, 8);  v += __shfl_xor(v, 16); v += __shfl_xor(v, 32);
      vals[k] = v;
    }
    if (tid == 0) {
#pragma unroll
      for (int k = 0; k < 15; ++k) ws[bid*16 + k] = vals[k];
    }
  }
}

// =============================================================================
// Kernel 2: ONE block, 16 waves; wave w = batch w; lane 0 runs the SVD.
// =============================================================================
__global__ __launch_bounds__(1024)
void finalize_kernel(const float* __restrict__ ws, float* __restrict__ out) {
  const int b = threadIdx.x >> 6;
  const int L = threadIdx.x & 63;

  float a = 0.0f;
  if (L < 15) {
#pragma unroll
    for (int ntile = 0; ntile < 32; ++ntile)
      a += ws[(ntile*16 + b)*16 + L];
  }
  float acc[15];
#pragma unroll
  for (int k = 0; k < 15; ++k) acc[k] = __shfl(a, k);

  if (L == 0) {
    const float invN = 1.0f/2048.0f;
    float Sc[3] = {acc[0], acc[1], acc[2]};
    float Ss[3] = {acc[3], acc[4], acc[5]};
    float cm[3] = {Sc[0]*invN, Sc[1]*invN, Sc[2]*invN};
    float sm[3] = {Ss[0]*invN, Ss[1]*invN, Ss[2]*invN};

    float A[3][3];
#pragma unroll
    for (int i = 0; i < 3; ++i)
#pragma unroll
      for (int j = 0; j < 3; ++j)
        A[i][j] = acc[6 + i*3 + j] - Ss[i]*cm[j];

    float u[3][3], vt[3][3];
    svd3_gesdd(A, u, vt);

    float R[3][3];
#pragma unroll
    for (int i = 0; i < 3; ++i)
#pragma unroll
      for (int k = 0; k < 3; ++k)
        R[i][k] = vt[i][0]*u[k][0] + vt[i][1]*u[k][1] + vt[i][2]*u[k][2];

    float det = R[0][0]*(R[1][1]*R[2][2] - R[1][2]*R[2][1])
              - R[0][1]*(R[1][0]*R[2][2] - R[1][2]*R[2][0])
              + R[0][2]*(R[1][0]*R[2][1] - R[1][1]*R[2][0]);

    if (det < 0.0f) {
#pragma unroll
      for (int i = 0; i < 3; ++i)
#pragma unroll
        for (int k = 0; k < 3; ++k)
          R[i][k] -= 2.0f*vt[i][2]*u[k][2];
    }

    float tv[3];
#pragma unroll
    for (int i = 0; i < 3; ++i)
      tv[i] = -(R[i][0]*sm[0] + R[i][1]*sm[1] + R[i][2]*sm[2]) + cm[i];

#pragma unroll
    for (int i = 0; i < 3; ++i)
#pragma unroll
      for (int j = 0; j < 3; ++j)
        out[b*9 + i*3 + j] = R[i][j];
#pragma unroll
    for (int i = 0; i < 3; ++i)
      out[144 + b*3 + i] = tv[i];
  }
}

extern "C" void kernel_launch(void* const* d_in, const int* in_sizes, int n_in,
                              void* d_out, int out_size, void* d_ws, size_t ws_size,
                              hipStream_t stream) {
  const float* srcE = (const float*)d_in[0];
  const float* tgtE = (const float*)d_in[1];
  const float* src  = (const float*)d_in[2];
  const float* tgt  = (const float*)d_in[3];
  float* out = (float*)d_out;

  // ws layout: [0,32KB) partials | Qp 2MB | Kp 2MB | Vt4 256KB
  float* part = (float*)d_ws;
  unsigned short* Qp  = (unsigned short*)((char*)d_ws + 32768);
  unsigned short* Kp  = (unsigned short*)((char*)d_ws + 32768 + (size_t)16*2048*32*2);
  unsigned short* Vt4 = (unsigned short*)((char*)d_ws + 32768 + (size_t)2*16*2048*32*2);

  hipLaunchKernelGGL(pack_kernel, dim3(256), dim3(128), 0, stream, srcE, tgtE, tgt, Qp, Kp, Vt4);
  hipLaunchKernelGGL(corr_kernel, dim3(512), dim3(512), 0, stream, Qp, Kp, Vt4, src, part);
  hipLaunchKernelGGL(finalize_kernel, dim3(1), dim3(1024), 0, stream, part, out);
}

// Round 10
// 50.768 us; speedup vs baseline: 1.7332x; 1.1068x over previous
//
#include <hip/hip_runtime.h>
#include <math.h>

// LAPACK >= 3.10 slartg convention (c >= 0). Flip to 0 to emulate <= 3.9.
#define NEW_SLARTG 1

typedef __attribute__((ext_vector_type(8))) short bf16x8;
typedef __attribute__((ext_vector_type(4))) float f32x4;

// =============================================================================
// LAPACK sgesdd emulation for 3x3 (f32), faithful sign conventions.
// FULLY SCALARIZED: no runtime-indexed arrays anywhere on the SVD path
// (rule: runtime-indexed small arrays -> scratch -> ~170cy/access serial chain;
// round-9 finalize was ~35us of pure scratch latency). All ops transcribed in
// exact LAPACK order from the loop version -> bit-identical results.
// =============================================================================

__device__ __forceinline__ void slartg_f(float f, float g, float& c, float& s, float& r) {
#if NEW_SLARTG
  if (g == 0.0f) { c = 1.0f; s = 0.0f; r = f; }
  else if (f == 0.0f) { c = 0.0f; s = copysignf(1.0f, g); r = fabsf(g); }
  else {
    float d = sqrtf(f*f + g*g);
    c = fabsf(f) / d;
    r = copysignf(d, f);
    s = g / r;
  }
#else
  if (g == 0.0f) { c = 1.0f; s = 0.0f; r = f; }
  else if (f == 0.0f) { c = 0.0f; s = 1.0f; r = g; }
  else {
    float d = sqrtf(f*f + g*g);
    c = f / d; s = g / d; r = d;
    if (fabsf(f) > fabsf(g) && c < 0.0f) { c = -c; s = -s; r = -r; }
  }
#endif
}

__device__ __forceinline__ void slas2_f(float f, float g, float h, float& ssmin, float& ssmax) {
  float fa = fabsf(f), ga = fabsf(g), ha = fabsf(h);
  float fhmn = fminf(fa, ha), fhmx = fmaxf(fa, ha);
  if (fhmn == 0.0f) {
    ssmin = 0.0f;
    if (fhmx == 0.0f) ssmax = ga;
    else {
      float mn = fminf(fhmx, ga), mx = fmaxf(fhmx, ga);
      float qq = mn / mx;
      ssmax = mx * sqrtf(1.0f + qq*qq);
    }
  } else {
    if (ga < fhmx) {
      float as_ = 1.0f + fhmn/fhmx;
      float at_ = (fhmx - fhmn)/fhmx;
      float au_ = ga/fhmx; au_ = au_*au_;
      float c = 2.0f/(sqrtf(as_*as_ + au_) + sqrtf(at_*at_ + au_));
      ssmin = fhmn*c;
      ssmax = fhmx/c;
    } else {
      float au_ = fhmx/ga;
      if (au_ == 0.0f) {
        ssmin = (fhmn*fhmx)/ga;
        ssmax = ga;
      } else {
        float as_ = 1.0f + fhmn/fhmx;
        float at_ = (fhmx - fhmn)/fhmx;
        float t1 = as_*au_, t2 = at_*au_;
        float c = 1.0f/(sqrtf(1.0f + t1*t1) + sqrtf(1.0f + t2*t2));
        ssmin = (fhmn*c)*au_;
        ssmin = ssmin + ssmin;
        ssmax = ga/(c + c);
      }
    }
  }
}

__device__ __forceinline__ void slasv2_f(float f, float g, float h,
                         float& ssmin, float& ssmax,
                         float& snr, float& csr, float& snl, float& csl) {
  const float eps = 5.9604645e-08f;
  float ft = f, fa = fabsf(f), ht = h, ha = fabsf(h);
  int pmax = 1;
  bool swap_ = (ha > fa);
  if (swap_) {
    pmax = 3;
    float tq = ft; ft = ht; ht = tq;
    tq = fa; fa = ha; ha = tq;
  }
  float gt = g, ga = fabsf(g);
  float clt = 0.f, crt = 0.f, slt = 0.f, srt = 0.f;
  if (ga == 0.0f) {
    ssmin = ha; ssmax = fa;
    clt = 1.0f; crt = 1.0f; slt = 0.0f; srt = 0.0f;
  } else {
    bool gasmal = true;
    if (ga > fa) {
      pmax = 2;
      if ((fa/ga) < eps) {
        gasmal = false;
        ssmax = ga;
        ssmin = (ha > 1.0f) ? (fa/(ga/ha)) : ((fa/ga)*ha);
        clt = 1.0f; slt = ht/gt; srt = 1.0f; crt = ft/gt;
      }
    }
    if (gasmal) {
      float dd = fa - ha;
      float l = (dd == fa) ? 1.0f : (dd/fa);
      float mr = gt/ft;
      float t = 2.0f - l;
      float mm2 = mr*mr, tt = t*t;
      float s_ = sqrtf(tt + mm2);
      float r_ = (l == 0.0f) ? fabsf(mr) : sqrtf(l*l + mm2);
      float a_ = 0.5f*(s_ + r_);
      ssmin = ha/a_;
      ssmax = fa*a_;
      if (mm2 == 0.0f) {
        if (l == 0.0f) t = copysignf(2.0f, ft)*copysignf(1.0f, gt);
        else t = gt/copysignf(dd, ft) + mr/t;
      } else {
        t = (mr/(s_ + t) + mr/(r_ + l))*(1.0f + a_);
      }
      float l2 = sqrtf(t*t + 4.0f);
      crt = 2.0f/l2;
      srt = t/l2;
      clt = (crt + srt*mr)/a_;
      slt = (ht/ft)*srt/a_;
    }
  }
  if (swap_) { csl = srt; snl = crt; csr = slt; snr = clt; }
  else       { csl = clt; snl = slt; csr = crt; snr = srt; }
  float tsign = 0.f;
  if (pmax == 1) tsign = copysignf(1.0f, csr)*copysignf(1.0f, csl)*copysignf(1.0f, f);
  if (pmax == 2) tsign = copysignf(1.0f, snr)*copysignf(1.0f, csl)*copysignf(1.0f, g);
  if (pmax == 3) tsign = copysignf(1.0f, snr)*copysignf(1.0f, snl)*copysignf(1.0f, h);
  ssmax = copysignf(ssmax, tsign);
  ssmin = copysignf(ssmin, tsign*copysignf(1.0f, f)*copysignf(1.0f, h));
}

// rotation / swap helpers with COMPILE-TIME indices (template params)
template<int R1, int R2>
__device__ __forceinline__ void rotr(float mt[3][3], float c, float s) {
#pragma unroll
  for (int k = 0; k < 3; ++k) {
    float x = mt[R1][k], y = mt[R2][k];
    mt[R1][k] = c*x + s*y;
    mt[R2][k] = c*y - s*x;
  }
}
template<int C1, int C2>
__device__ __forceinline__ void rotc(float mt[3][3], float c, float s) {
#pragma unroll
  for (int k = 0; k < 3; ++k) {
    float x = mt[k][C1], y = mt[k][C2];
    mt[k][C1] = c*x + s*y;
    mt[k][C2] = c*y - s*x;
  }
}
template<int R1, int R2>
__device__ __forceinline__ void swaprow(float mt[3][3]) {
#pragma unroll
  for (int k = 0; k < 3; ++k) { float t = mt[R1][k]; mt[R1][k] = mt[R2][k]; mt[R2][k] = t; }
}
template<int C1, int C2>
__device__ __forceinline__ void swapcol(float mt[3][3]) {
#pragma unroll
  for (int k = 0; k < 3; ++k) { float t = mt[k][C1]; mt[k][C1] = mt[k][C2]; mt[k][C2] = t; }
}

// SBDSQR specialized for n=3 upper bidiagonal, all-register state.
// For n=3 the only full QR sweep is (ll=1,m=3) with 2 rotations; m==2 blocks
// always resolve via slasv2. Ops transcribed in exact LAPACK order.
__device__ __forceinline__ void sbdsqr3_reg(float& d1, float& d2, float& d3,
                                            float& e1, float& e2,
                                            float u[3][3], float vt[3][3]) {
  const float eps  = 5.9604645e-08f;
  const float unfl = 1.17549435e-38f;
  const float tol  = 10.0f*eps;

  float sminoa = fabsf(d1);
  if (sminoa != 0.0f) {
    float mu = sminoa;
    mu = fabsf(d2)*(mu/(mu + fabsf(e1)));
    sminoa = fminf(sminoa, mu);
    if (sminoa != 0.0f) {
      mu = fabsf(d3)*(mu/(mu + fabsf(e2)));
      sminoa = fminf(sminoa, mu);
    }
  }
  sminoa = sminoa / sqrtf(3.0f);
  float thresh = fmaxf(tol*sminoa, 54.0f*unfl);

  int m = 3, oldll = -1, oldm = -1, idir = 0;
  int guard = 0;
  while (m > 1 && ++guard < 200) {
    if (m == 2) {
      // scan: only e1; negligible -> deflate, else 2x2 at rows (0,1)
      if (fabsf(e1) <= thresh) { e1 = 0.0f; m = 1; continue; }
      float sigmn, sigmx, sinr, cosr, sinl, cosl;
      slasv2_f(d1, e1, d2, sigmn, sigmx, sinr, cosr, sinl, cosl);
      d1 = sigmx; d2 = sigmn; e1 = 0.0f;
      rotr<0,1>(vt, cosr, sinr);
      rotc<0,1>(u,  cosl, sinl);
      m = 0; continue;
    }
    // ---- m == 3 ----
    float smax = fabsf(d3);
    // scan lll=1 (l2=2): e2
    if (fabsf(e2) <= thresh) { e2 = 0.0f; m = 2; continue; }   // ll=2==m-1
    smax = fmaxf(smax, fmaxf(fabsf(d2), fabsf(e2)));
    // scan lll=2 (l2=1): e1
    if (fabsf(e1) <= thresh) {
      e1 = 0.0f;   // ll=1 -> ll=2 -> 2x2 block rows (1,2)
      float sigmn, sigmx, sinr, cosr, sinl, cosl;
      slasv2_f(d2, e2, d3, sigmn, sigmx, sinr, cosr, sinl, cosl);
      d2 = sigmx; d3 = sigmn; e2 = 0.0f;
      rotr<1,2>(vt, cosr, sinr);
      rotc<1,2>(u,  cosl, sinl);
      m = 1; continue;
    }
    smax = fmaxf(smax, fmaxf(fabsf(d1), fabsf(e1)));

    // full 3x3 block, ll=1
    if (1 > oldm || 3 < oldll)
      idir = (fabsf(d1) >= fabsf(d3)) ? 1 : 2;

    float sminl = 0.0f;
    if (idir == 1) {
      if (fabsf(e2) <= tol*fabsf(d3)) { e2 = 0.0f; continue; }
      float mu = fabsf(d1); sminl = mu;
      if (fabsf(e1) <= tol*mu) { e1 = 0.0f; continue; }       // deflated
      mu = fabsf(d2)*(mu/(mu + fabsf(e1))); sminl = fminf(sminl, mu);
      if (fabsf(e2) <= tol*mu) { e2 = 0.0f; continue; }       // deflated
      mu = fabsf(d3)*(mu/(mu + fabsf(e2))); sminl = fminf(sminl, mu);
    } else {
      if (fabsf(e1) <= tol*fabsf(d1)) { e1 = 0.0f; continue; }
      float mu = fabsf(d3); sminl = mu;
      if (fabsf(e2) <= tol*mu) { e2 = 0.0f; continue; }       // deflated
      mu = fabsf(d2)*(mu/(mu + fabsf(e2))); sminl = fminf(sminl, mu);
      if (fabsf(e1) <= tol*mu) { e1 = 0.0f; continue; }       // deflated
      mu = fabsf(d1)*(mu/(mu + fabsf(e1))); sminl = fminf(sminl, mu);
    }
    oldll = 1; oldm = 3;

    float shift = 0.0f, rdum;
    if (!(3.0f*tol*(sminl/smax) <= fmaxf(eps, 0.01f*tol))) {
      float sll;
      if (idir == 1) { sll = fabsf(d1); slas2_f(d2, e2, d3, shift, rdum); }
      else           { sll = fabsf(d3); slas2_f(d1, e1, d2, shift, rdum); }
      if (sll > 0.0f) { float qq = shift/sll; if (qq*qq < eps) shift = 0.0f; }
    }

    if (shift == 0.0f) {
      if (idir == 1) {
        float cs = 1.0f, oldcs = 1.0f, sn = 0.0f, oldsn = 0.0f, r;
        float c10, s10, c20, s20, c11, s11, c21, s21;
        // i=1
        slartg_f(d1*cs, e1, cs, sn, r);
        slartg_f(oldcs*r, d2*sn, oldcs, oldsn, d1);
        c10 = cs; s10 = sn; c20 = oldcs; s20 = oldsn;
        // i=2
        slartg_f(d2*cs, e2, cs, sn, r);
        e1 = oldsn*r;
        slartg_f(oldcs*r, d3*sn, oldcs, oldsn, d2);
        c11 = cs; s11 = sn; c21 = oldcs; s21 = oldsn;
        float h = d3*cs;
        d3 = h*oldcs; e2 = h*oldsn;
        rotr<0,1>(vt, c10, s10); rotr<1,2>(vt, c11, s11);
        rotc<0,1>(u,  c20, s20); rotc<1,2>(u,  c21, s21);
        if (fabsf(e2) <= thresh) e2 = 0.0f;
      } else {
        float cs = 1.0f, oldcs = 1.0f, sn = 0.0f, oldsn = 0.0f, r;
        float c10, s10, c20, s20, c11, s11, c21, s21;
        // i=3
        slartg_f(d3*cs, e2, cs, sn, r);
        slartg_f(oldcs*r, d2*sn, oldcs, oldsn, d3);
        c11 = cs; s11 = -sn; c21 = oldcs; s21 = -oldsn;
        // i=2
        slartg_f(d2*cs, e1, cs, sn, r);
        e2 = oldsn*r;
        slartg_f(oldcs*r, d1*sn, oldcs, oldsn, d2);
        c10 = cs; s10 = -sn; c20 = oldcs; s20 = -oldsn;
        float h = d1*cs;
        d1 = h*oldcs; e1 = h*oldsn;
        rotr<1,2>(vt, c21, s21); rotr<0,1>(vt, c20, s20);
        rotc<1,2>(u,  c11, s11); rotc<0,1>(u,  c10, s10);
        if (fabsf(e1) <= thresh) e1 = 0.0f;
      }
    } else {
      if (idir == 1) {
        float f = (fabsf(d1) - shift)*(copysignf(1.0f, d1) + shift/d1);
        float g = e1, cr, sr, cl, sl, r;
        float c10, s10, c20, s20, c11, s11, c21, s21;
        // i=1
        slartg_f(f, g, cr, sr, r);
        f = cr*d1 + sr*e1;  e1 = cr*e1 - sr*d1;
        g = sr*d2;  d2 = cr*d2;
        slartg_f(f, g, cl, sl, r);
        d1 = r;  f = cl*e1 + sl*d2;  d2 = cl*d2 - sl*e1;
        g = sl*e2;  e2 = cl*e2;                 // i < m-1
        c10 = cr; s10 = sr; c20 = cl; s20 = sl;
        // i=2
        slartg_f(f, g, cr, sr, r);
        e1 = r;
        f = cr*d2 + sr*e2;  e2 = cr*e2 - sr*d2;
        g = sr*d3;  d3 = cr*d3;
        slartg_f(f, g, cl, sl, r);
        d2 = r;  f = cl*e2 + sl*d3;  d3 = cl*d3 - sl*e2;
        c11 = cr; s11 = sr; c21 = cl; s21 = sl;
        e2 = f;
        rotr<0,1>(vt, c10, s10); rotr<1,2>(vt, c11, s11);
        rotc<0,1>(u,  c20, s20); rotc<1,2>(u,  c21, s21);
        if (fabsf(e2) <= thresh) e2 = 0.0f;
      } else {
        float f = (fabsf(d3) - shift)*(copysignf(1.0f, d3) + shift/d3);
        float g = e2, cr, sr, cl, sl, r;
        float c10, s10, c20, s20, c11, s11, c21, s21;
        // i=3
        slartg_f(f, g, cr, sr, r);
        f = cr*d3 + sr*e2;  e2 = cr*e2 - sr*d3;
        g = sr*d2;  d2 = cr*d2;
        slartg_f(f, g, cl, sl, r);
        d3 = r;  f = cl*e2 + sl*d2;  d2 = cl*d2 - sl*e2;
        g = sl*e1;  e1 = cl*e1;                 // i > ll+1
        c11 = cr; s11 = -sr; c21 = cl; s21 = -sl;
        // i=2
        slartg_f(f, g, cr, sr, r);
        e2 = r;
        f = cr*d2 + sr*e1;  e1 = cr*e1 - sr*d2;
        g = sr*d1;  d1 = cr*d1;
        slartg_f(f, g, cl, sl, r);
        d2 = r;  f = cl*e1 + sl*d1;  d1 = cl*d1 - sl*e1;
        c10 = cr; s10 = -sr; c20 = cl; s20 = -sl;
        e1 = f;
        if (fabsf(e1) <= thresh) e1 = 0.0f;
        rotr<1,2>(vt, c21, s21); rotr<0,1>(vt, c20, s20);
        rotc<1,2>(u,  c11, s11); rotc<0,1>(u,  c10, s10);
      }
    }
  }

  // ---- make singular values positive (negate VT rows) ----
  if (d1 < 0.0f) { d1 = -d1; vt[0][0] = -vt[0][0]; vt[0][1] = -vt[0][1]; vt[0][2] = -vt[0][2]; }
  if (d2 < 0.0f) { d2 = -d2; vt[1][0] = -vt[1][0]; vt[1][1] = -vt[1][1]; vt[1][2] = -vt[1][2]; }
  if (d3 < 0.0f) { d3 = -d3; vt[2][0] = -vt[2][0]; vt[2][1] = -vt[2][1]; vt[2][2] = -vt[2][2]; }

  // ---- sort decreasing (LAPACK selection sort with <=, specialized) ----
  { // pass 1: min of (d1,d2,d3) -> slot 3
    int isub = 1; float smn = d1;
    if (d2 <= smn) { isub = 2; smn = d2; }
    if (d3 <= smn) { isub = 3; smn = d3; }
    if (isub == 1)      { d1 = d3; d3 = smn; swaprow<0,2>(vt); swapcol<0,2>(u); }
    else if (isub == 2) { d2 = d3; d3 = smn; swaprow<1,2>(vt); swapcol<1,2>(u); }
  }
  { // pass 2: min of (d1,d2) -> slot 2
    int isub = 1; float smn = d1;
    if (d2 <= smn) { isub = 2; smn = d2; }
    if (isub == 1) { d1 = d2; d2 = smn; swaprow<0,1>(vt); swapcol<0,1>(u); }
  }
}

__device__ __forceinline__ void svd3_gesdd(const float Ain[3][3], float u[3][3], float vt[3][3]) {
  float a[3][3];
#pragma unroll
  for (int i = 0; i < 3; ++i)
#pragma unroll
    for (int j = 0; j < 3; ++j) a[i][j] = Ain[i][j];

  float d1, d2, d3, e1, e2;
  float tq0 = 0.f, tq1 = 0.f, tp0 = 0.f;
  float v0a = 0.f, v0b = 0.f, v1a = 0.f, p0a = 0.f;

  { // i=0 left reflector (column 0)
    float alpha = a[0][0];
    float xn = sqrtf(a[1][0]*a[1][0] + a[2][0]*a[2][0]);
    if (xn == 0.0f) { tq0 = 0.0f; d1 = alpha; }
    else {
      float beta = -copysignf(sqrtf(alpha*alpha + xn*xn), alpha);
      tq0 = (beta - alpha)/beta;
      float sc = 1.0f/(alpha - beta);
      v0a = a[1][0]*sc; v0b = a[2][0]*sc;
      d1 = beta;
    }
#pragma unroll
    for (int j = 1; j < 3; ++j) {
      float w = (a[0][j] + v0a*a[1][j] + v0b*a[2][j])*tq0;
      a[0][j] -= w; a[1][j] -= w*v0a; a[2][j] -= w*v0b;
    }
  }
  { // i=0 right reflector (row 0, cols 1..2)
    float alpha = a[0][1];
    float xn = fabsf(a[0][2]);
    if (xn == 0.0f) { tp0 = 0.0f; e1 = alpha; }
    else {
      float beta = -copysignf(sqrtf(alpha*alpha + xn*xn), alpha);
      tp0 = (beta - alpha)/beta;
      p0a = a[0][2]/(alpha - beta);
      e1 = beta;
    }
#pragma unroll
    for (int i = 1; i < 3; ++i) {
      float w = (a[i][1] + p0a*a[i][2])*tp0;
      a[i][1] -= w; a[i][2] -= w*p0a;
    }
  }
  { // i=1 left reflector (column 1, rows 1..2)
    float alpha = a[1][1];
    float xn = fabsf(a[2][1]);
    if (xn == 0.0f) { tq1 = 0.0f; d2 = alpha; }
    else {
      float beta = -copysignf(sqrtf(alpha*alpha + xn*xn), alpha);
      tq1 = (beta - alpha)/beta;
      v1a = a[2][1]/(alpha - beta);
      d2 = beta;
    }
    float w = (a[1][2] + v1a*a[2][2])*tq1;
    a[1][2] -= w; a[2][2] -= w*v1a;
  }
  e2 = a[1][2];
  d3 = a[2][2];

  float ub[3][3] = {{1,0,0},{0,1,0},{0,0,1}};
  float vb[3][3] = {{1,0,0},{0,1,0},{0,0,1}};
  sbdsqr3_reg(d1, d2, d3, e1, e2, ub, vb);

#pragma unroll
  for (int j = 0; j < 3; ++j) {    // apply H1 (v = (0,1,v1a))
    float w = (ub[1][j] + v1a*ub[2][j])*tq1;
    ub[1][j] -= w; ub[2][j] -= w*v1a;
  }
#pragma unroll
  for (int j = 0; j < 3; ++j) {    // apply H0 (v = (1,v0a,v0b))
    float w = (ub[0][j] + v0a*ub[1][j] + v0b*ub[2][j])*tq0;
    ub[0][j] -= w; ub[1][j] -= w*v0a; ub[2][j] -= w*v0b;
  }
#pragma unroll
  for (int i = 0; i < 3; ++i) {    // VT = Vb * G0 (w = (0,1,p0a))
    float w = (vb[i][1] + p0a*vb[i][2])*tp0;
    vb[i][1] -= w; vb[i][2] -= w*p0a;
  }
#pragma unroll
  for (int i = 0; i < 3; ++i)
#pragma unroll
    for (int j = 0; j < 3; ++j) { u[i][j] = ub[i][j]; vt[i][j] = vb[i][j]; }
}

// =============================================================================
// bf16 helpers (RNE, manual — verified since round 1)
// =============================================================================
__device__ __forceinline__ unsigned int f2bf(float x) {
  unsigned int u = __float_as_uint(x);
  return (u + 0x7FFFu + ((u >> 16) & 1u)) >> 16;
}
__device__ __forceinline__ float bf2f(unsigned int h) {
  return __uint_as_float(h << 16);
}

// =============================================================================
// Kernel 0: pack. (unchanged from round 9)
// =============================================================================
__global__ __launch_bounds__(128)
void pack_kernel(const float* __restrict__ srcE, const float* __restrict__ tgtE,
                 const float* __restrict__ tgt,
                 unsigned short* __restrict__ Qp, unsigned short* __restrict__ Kp,
                 unsigned short* __restrict__ Vt4) {
  const int g = blockIdx.x*128 + threadIdx.x;   // 32768 = 16*2048
  const int b = g >> 11, n = g & 2047;
  const float* qs = srcE + (size_t)b*16*2048 + n;
  const float* ks = tgtE + (size_t)b*16*2048 + n;
  const float QSCALE = 0.25f * 1.44269504088896340736f;

  unsigned short qrow[32], krow[32];
#pragma unroll
  for (int dd = 0; dd < 16; ++dd) {
    float q = qs[dd*2048] * QSCALE;
    unsigned int qh = f2bf(q);
    qrow[dd] = (unsigned short)qh; qrow[16+dd] = (unsigned short)f2bf(q - bf2f(qh));
    float k = ks[dd*2048];
    unsigned int kh = f2bf(k);
    krow[dd] = (unsigned short)kh; krow[16+dd] = (unsigned short)f2bf(k - bf2f(kh));
  }
  uint4* qdst = (uint4*)(Qp + (size_t)g*32);
  uint4* kdst = (uint4*)(Kp + (size_t)g*32);
#pragma unroll
  for (int i = 0; i < 4; ++i) { qdst[i] = ((uint4*)qrow)[i]; kdst[i] = ((uint4*)krow)[i]; }

  const float* vp = tgt + (size_t)b*3*2048 + n;
  unsigned short* wb = Vt4 + (size_t)b*4*2048;
  wb[n]          = 0x3F80;             // ones column (j=0)
  wb[2048 + n]   = (unsigned short)f2bf(vp[0]);
  wb[2*2048 + n] = (unsigned short)f2bf(vp[2048]);
  wb[3*2048 + n] = (unsigned short)f2bf(vp[4096]);
}

// =============================================================================
// Kernel 1: MFMA flash attention; PV + softmax-sum ALSO via MFMA. (round 8,
// passed, corr ~15us) — unchanged.
// =============================================================================
__global__ __launch_bounds__(512, 4)
void corr_kernel(const unsigned short* __restrict__ Qp, const unsigned short* __restrict__ Kp,
                 const unsigned short* __restrict__ Vt4, const float* __restrict__ src,
                 float* __restrict__ ws) {
  const int bid = blockIdx.x;
  const int b   = bid & 15;
  const int nt  = bid >> 4;          // 0..31, 64 n each
  const int tid = threadIdx.x;
  const int w   = tid >> 6;
  const int L   = tid & 63;
  const int lg  = L >> 4;
  const int ll  = L & 15;

  __shared__ __align__(16) char  stage[8*1024];       // 8 KB: per-wave A' staging
  __shared__ __align__(16) float partial[8][64][4];   // 8 KB

  const unsigned short* Qb = Qp + (size_t)b*2048*32;
  const unsigned short* Kb = Kp + (size_t)b*2048*32;
  const unsigned short* Wb = Vt4 + (size_t)b*4*2048;

  const bf16x8 zero8 = {0,0,0,0,0,0,0,0};
  char* my = stage + w*1024;
  char* wr0 = my + ll*64 + lg*8;        // tile0 write slot
  char* wr1 = wr0 + 32;                 // tile1 write slot
  const char* rd = my + ll*64 + lg*16;  // A'-frag read slot

  // ---- Q-fragments for this block's 4 n-tiles ----
  bf16x8 bq1[4], bq2[4];
#pragma unroll
  for (int t2 = 0; t2 < 4; ++t2) {
    const unsigned short* qr = Qb + (size_t)(nt*64 + t2*16 + ll)*32;
    bq1[t2] = *(const bf16x8*)(qr + (lg & 1)*8);
    bf16x8 lo = *(const bf16x8*)(qr + 16 + (lg & 1)*8);
    bq2[t2] = (lg < 2) ? lo : zero8;
  }

  f32x4 accp[4];
#pragma unroll
  for (int t2 = 0; t2 < 4; ++t2) accp[t2] = (f32x4){0.f, 0.f, 0.f, 0.f};

  for (int p = w; p < 64; p += 8) {
    const unsigned short* ar = Kb + (size_t)(p*32 + ll)*32;
    bf16x8 a0 = *(const bf16x8*)(ar + lg*8);            // m-tile 2p
    bf16x8 a1 = *(const bf16x8*)(ar + 16*32 + lg*8);    // m-tile 2p+1
    bf16x8 wv = zero8;                                  // W B-frag (cols>=4 zero)
    if (ll < 4) wv = *(const bf16x8*)(Wb + (size_t)ll*2048 + p*32 + lg*8);

#pragma unroll
    for (int t2 = 0; t2 < 4; ++t2) {
      f32x4 c0 = (f32x4){0.f,0.f,0.f,0.f};
      f32x4 c1 = (f32x4){0.f,0.f,0.f,0.f};
      c0 = __builtin_amdgcn_mfma_f32_16x16x32_bf16(a0, bq1[t2], c0, 0, 0, 0);
      c0 = __builtin_amdgcn_mfma_f32_16x16x32_bf16(a0, bq2[t2], c0, 0, 0, 0);
      c1 = __builtin_amdgcn_mfma_f32_16x16x32_bf16(a1, bq1[t2], c1, 0, 0, 0);
      c1 = __builtin_amdgcn_mfma_f32_16x16x32_bf16(a1, bq2[t2], c1, 0, 0, 0);
      // P = exp2(scores); C-frag: row m_loc = lg*4+r, col n = ll
      float e0 = __builtin_amdgcn_exp2f(c0.x), e1 = __builtin_amdgcn_exp2f(c0.y);
      float e2 = __builtin_amdgcn_exp2f(c0.z), e3 = __builtin_amdgcn_exp2f(c0.w);
      float f0 = __builtin_amdgcn_exp2f(c1.x), f1 = __builtin_amdgcn_exp2f(c1.y);
      float f2 = __builtin_amdgcn_exp2f(c1.z), f3 = __builtin_amdgcn_exp2f(c1.w);
      // pack to bf16 pairs (lo = even r) and stage into A' layout
      *(uint2*)wr0 = make_uint2(f2bf(e0) | (f2bf(e1) << 16),
                                f2bf(e2) | (f2bf(e3) << 16));
      *(uint2*)wr1 = make_uint2(f2bf(f0) | (f2bf(f1) << 16),
                                f2bf(f2) | (f2bf(f3) << 16));
      bf16x8 pa = *(const bf16x8*)rd;   // A'[row=ll][k=lg*8..+7]
      // PV: X[n][j] += P^T x W   (j: 0=sumE, 1..3 = sum e*v)
      accp[t2] = __builtin_amdgcn_mfma_f32_16x16x32_bf16(pa, wv, accp[t2], 0, 0, 0);
    }
  }

  // ---- write per-wave partials: X[j=ll][n] for ll<4 ----
  if (ll < 4) {
#pragma unroll
    for (int t2 = 0; t2 < 4; ++t2) {
      int nb = t2*16 + lg*4;
      partial[w][nb+0][ll] = accp[t2].x;
      partial[w][nb+1][ll] = accp[t2].y;
      partial[w][nb+2][ll] = accp[t2].z;
      partial[w][nb+3][ll] = accp[t2].w;
    }
  }
  __syncthreads();

  // ---- per-n finish + 15-value single-wave reduction (wave 0 only) ----
  if (tid < 64) {
    float4 s4 = make_float4(0.f, 0.f, 0.f, 0.f);
#pragma unroll
    for (int w2 = 0; w2 < 8; ++w2) {
      float4 pq = *(const float4*)&partial[w2][tid][0];
      s4.x += pq.x; s4.y += pq.y; s4.z += pq.z; s4.w += pq.w;
    }
    float inv = 1.0f / s4.x;
    float c0 = s4.y*inv, c1 = s4.z*inv, c2 = s4.w*inv;
    const int n = nt*64 + tid;
    const float* sp = src + (size_t)b*3*2048;
    float s0v = sp[n], s1v = sp[2048+n], s2v = sp[4096+n];
    float vals[15] = { c0, c1, c2, s0v, s1v, s2v,
                       s0v*c0, s0v*c1, s0v*c2,
                       s1v*c0, s1v*c1, s1v*c2,
                       s2v*c0, s2v*c1, s2v*c2 };
#pragma unroll
    for (int k = 0; k < 15; ++k) {
      float v = vals[k];
      v += __shfl_xor(v, 1);  v += __shfl_xor(v, 2);  v += __shfl_xor(v, 4);
      v += __shfl_xor(v, 8);  v += __shfl_xor(v, 16); v += __shfl_xor(v, 32);
      vals[k] = v;
    }
    if (tid == 0) {
#pragma unroll
      for (int k = 0; k < 15; ++k) ws[bid*16 + k] = vals[k];
    }
  }
}

// =============================================================================
// Kernel 2: ONE block, 16 waves; wave w = batch w; lane 0 runs the SVD
// (now fully register-resident).
// =============================================================================
__global__ __launch_bounds__(1024)
void finalize_kernel(const float* __restrict__ ws, float* __restrict__ out) {
  const int b = threadIdx.x >> 6;
  const int L = threadIdx.x & 63;

  float a = 0.0f;
  if (L < 15) {
#pragma unroll
    for (int ntile = 0; ntile < 32; ++ntile)
      a += ws[(ntile*16 + b)*16 + L];
  }
  float acc[15];
#pragma unroll
  for (int k = 0; k < 15; ++k) acc[k] = __shfl(a, k);

  if (L == 0) {
    const float invN = 1.0f/2048.0f;
    float Sc[3] = {acc[0], acc[1], acc[2]};
    float Ss[3] = {acc[3], acc[4], acc[5]};
    float cm[3] = {Sc[0]*invN, Sc[1]*invN, Sc[2]*invN};
    float sm[3] = {Ss[0]*invN, Ss[1]*invN, Ss[2]*invN};

    float A[3][3];
#pragma unroll
    for (int i = 0; i < 3; ++i)
#pragma unroll
      for (int j = 0; j < 3; ++j)
        A[i][j] = acc[6 + i*3 + j] - Ss[i]*cm[j];

    float u[3][3], vt[3][3];
    svd3_gesdd(A, u, vt);

    float R[3][3];
#pragma unroll
    for (int i = 0; i < 3; ++i)
#pragma unroll
      for (int k = 0; k < 3; ++k)
        R[i][k] = vt[i][0]*u[k][0] + vt[i][1]*u[k][1] + vt[i][2]*u[k][2];

    float det = R[0][0]*(R[1][1]*R[2][2] - R[1][2]*R[2][1])
              - R[0][1]*(R[1][0]*R[2][2] - R[1][2]*R[2][0])
              + R[0][2]*(R[1][0]*R[2][1] - R[1][1]*R[2][0]);

    if (det < 0.0f) {
#pragma unroll
      for (int i = 0; i < 3; ++i)
#pragma unroll
        for (int k = 0; k < 3; ++k)
          R[i][k] -= 2.0f*vt[i][2]*u[k][2];
    }

    float tv[3];
#pragma unroll
    for (int i = 0; i < 3; ++i)
      tv[i] = -(R[i][0]*sm[0] + R[i][1]*sm[1] + R[i][2]*sm[2]) + cm[i];

#pragma unroll
    for (int i = 0; i < 3; ++i)
#pragma unroll
      for (int j = 0; j < 3; ++j)
        out[b*9 + i*3 + j] = R[i][j];
#pragma unroll
    for (int i = 0; i < 3; ++i)
      out[144 + b*3 + i] = tv[i];
  }
}

extern "C" void kernel_launch(void* const* d_in, const int* in_sizes, int n_in,
                              void* d_out, int out_size, void* d_ws, size_t ws_size,
                              hipStream_t stream) {
  const float* srcE = (const float*)d_in[0];
  const float* tgtE = (const float*)d_in[1];
  const float* src  = (const float*)d_in[2];
  const float* tgt  = (const float*)d_in[3];
  float* out = (float*)d_out;

  // ws layout: [0,32KB) partials | Qp 2MB | Kp 2MB | Vt4 256KB
  float* part = (float*)d_ws;
  unsigned short* Qp  = (unsigned short*)((char*)d_ws + 32768);
  unsigned short* Kp  = (unsigned short*)((char*)d_ws + 32768 + (size_t)16*2048*32*2);
  unsigned short* Vt4 = (unsigned short*)((char*)d_ws + 32768 + (size_t)2*16*2048*32*2);

  hipLaunchKernelGGL(pack_kernel, dim3(256), dim3(128), 0, stream, srcE, tgtE, tgt, Qp, Kp, Vt4);
  hipLaunchKernelGGL(corr_kernel, dim3(512), dim3(512), 0, stream, Qp, Kp, Vt4, src, part);
  hipLaunchKernelGGL(finalize_kernel, dim3(1), dim3(1024), 0, stream, part, out);
}

// Round 11
// 47.367 us; speedup vs baseline: 1.8576x; 1.0718x over previous
//
#include <hip/hip_runtime.h>
#include <math.h>

// LAPACK >= 3.10 slartg convention (c >= 0). Flip to 0 to emulate <= 3.9.
#define NEW_SLARTG 1

typedef __attribute__((ext_vector_type(8))) short bf16x8;
typedef __attribute__((ext_vector_type(4))) float f32x4;

// =============================================================================
// LAPACK sgesdd emulation for 3x3 (f32), faithful sign conventions.
// FULLY SCALARIZED (round 10: finalize scratch-latency fix, verified).
// =============================================================================

__device__ __forceinline__ void slartg_f(float f, float g, float& c, float& s, float& r) {
#if NEW_SLARTG
  if (g == 0.0f) { c = 1.0f; s = 0.0f; r = f; }
  else if (f == 0.0f) { c = 0.0f; s = copysignf(1.0f, g); r = fabsf(g); }
  else {
    float d = sqrtf(f*f + g*g);
    c = fabsf(f) / d;
    r = copysignf(d, f);
    s = g / r;
  }
#else
  if (g == 0.0f) { c = 1.0f; s = 0.0f; r = f; }
  else if (f == 0.0f) { c = 0.0f; s = 1.0f; r = g; }
  else {
    float d = sqrtf(f*f + g*g);
    c = f / d; s = g / d; r = d;
    if (fabsf(f) > fabsf(g) && c < 0.0f) { c = -c; s = -s; r = -r; }
  }
#endif
}

__device__ __forceinline__ void slas2_f(float f, float g, float h, float& ssmin, float& ssmax) {
  float fa = fabsf(f), ga = fabsf(g), ha = fabsf(h);
  float fhmn = fminf(fa, ha), fhmx = fmaxf(fa, ha);
  if (fhmn == 0.0f) {
    ssmin = 0.0f;
    if (fhmx == 0.0f) ssmax = ga;
    else {
      float mn = fminf(fhmx, ga), mx = fmaxf(fhmx, ga);
      float qq = mn / mx;
      ssmax = mx * sqrtf(1.0f + qq*qq);
    }
  } else {
    if (ga < fhmx) {
      float as_ = 1.0f + fhmn/fhmx;
      float at_ = (fhmx - fhmn)/fhmx;
      float au_ = ga/fhmx; au_ = au_*au_;
      float c = 2.0f/(sqrtf(as_*as_ + au_) + sqrtf(at_*at_ + au_));
      ssmin = fhmn*c;
      ssmax = fhmx/c;
    } else {
      float au_ = fhmx/ga;
      if (au_ == 0.0f) {
        ssmin = (fhmn*fhmx)/ga;
        ssmax = ga;
      } else {
        float as_ = 1.0f + fhmn/fhmx;
        float at_ = (fhmx - fhmn)/fhmx;
        float t1 = as_*au_, t2 = at_*au_;
        float c = 1.0f/(sqrtf(1.0f + t1*t1) + sqrtf(1.0f + t2*t2));
        ssmin = (fhmn*c)*au_;
        ssmin = ssmin + ssmin;
        ssmax = ga/(c + c);
      }
    }
  }
}

__device__ __forceinline__ void slasv2_f(float f, float g, float h,
                         float& ssmin, float& ssmax,
                         float& snr, float& csr, float& snl, float& csl) {
  const float eps = 5.9604645e-08f;
  float ft = f, fa = fabsf(f), ht = h, ha = fabsf(h);
  int pmax = 1;
  bool swap_ = (ha > fa);
  if (swap_) {
    pmax = 3;
    float tq = ft; ft = ht; ht = tq;
    tq = fa; fa = ha; ha = tq;
  }
  float gt = g, ga = fabsf(g);
  float clt = 0.f, crt = 0.f, slt = 0.f, srt = 0.f;
  if (ga == 0.0f) {
    ssmin = ha; ssmax = fa;
    clt = 1.0f; crt = 1.0f; slt = 0.0f; srt = 0.0f;
  } else {
    bool gasmal = true;
    if (ga > fa) {
      pmax = 2;
      if ((fa/ga) < eps) {
        gasmal = false;
        ssmax = ga;
        ssmin = (ha > 1.0f) ? (fa/(ga/ha)) : ((fa/ga)*ha);
        clt = 1.0f; slt = ht/gt; srt = 1.0f; crt = ft/gt;
      }
    }
    if (gasmal) {
      float dd = fa - ha;
      float l = (dd == fa) ? 1.0f : (dd/fa);
      float mr = gt/ft;
      float t = 2.0f - l;
      float mm2 = mr*mr, tt = t*t;
      float s_ = sqrtf(tt + mm2);
      float r_ = (l == 0.0f) ? fabsf(mr) : sqrtf(l*l + mm2);
      float a_ = 0.5f*(s_ + r_);
      ssmin = ha/a_;
      ssmax = fa*a_;
      if (mm2 == 0.0f) {
        if (l == 0.0f) t = copysignf(2.0f, ft)*copysignf(1.0f, gt);
        else t = gt/copysignf(dd, ft) + mr/t;
      } else {
        t = (mr/(s_ + t) + mr/(r_ + l))*(1.0f + a_);
      }
      float l2 = sqrtf(t*t + 4.0f);
      crt = 2.0f/l2;
      srt = t/l2;
      clt = (crt + srt*mr)/a_;
      slt = (ht/ft)*srt/a_;
    }
  }
  if (swap_) { csl = srt; snl = crt; csr = slt; snr = clt; }
  else       { csl = clt; snl = slt; csr = crt; snr = srt; }
  float tsign = 0.f;
  if (pmax == 1) tsign = copysignf(1.0f, csr)*copysignf(1.0f, csl)*copysignf(1.0f, f);
  if (pmax == 2) tsign = copysignf(1.0f, snr)*copysignf(1.0f, csl)*copysignf(1.0f, g);
  if (pmax == 3) tsign = copysignf(1.0f, snr)*copysignf(1.0f, snl)*copysignf(1.0f, h);
  ssmax = copysignf(ssmax, tsign);
  ssmin = copysignf(ssmin, tsign*copysignf(1.0f, f)*copysignf(1.0f, h));
}

// rotation / swap helpers with COMPILE-TIME indices (template params)
template<int R1, int R2>
__device__ __forceinline__ void rotr(float mt[3][3], float c, float s) {
#pragma unroll
  for (int k = 0; k < 3; ++k) {
    float x = mt[R1][k], y = mt[R2][k];
    mt[R1][k] = c*x + s*y;
    mt[R2][k] = c*y - s*x;
  }
}
template<int C1, int C2>
__device__ __forceinline__ void rotc(float mt[3][3], float c, float s) {
#pragma unroll
  for (int k = 0; k < 3; ++k) {
    float x = mt[k][C1], y = mt[k][C2];
    mt[k][C1] = c*x + s*y;
    mt[k][C2] = c*y - s*x;
  }
}
template<int R1, int R2>
__device__ __forceinline__ void swaprow(float mt[3][3]) {
#pragma unroll
  for (int k = 0; k < 3; ++k) { float t = mt[R1][k]; mt[R1][k] = mt[R2][k]; mt[R2][k] = t; }
}
template<int C1, int C2>
__device__ __forceinline__ void swapcol(float mt[3][3]) {
#pragma unroll
  for (int k = 0; k < 3; ++k) { float t = mt[k][C1]; mt[k][C1] = mt[k][C2]; mt[k][C2] = t; }
}

// SBDSQR specialized for n=3 upper bidiagonal, all-register state.
__device__ __forceinline__ void sbdsqr3_reg(float& d1, float& d2, float& d3,
                                            float& e1, float& e2,
                                            float u[3][3], float vt[3][3]) {
  const float eps  = 5.9604645e-08f;
  const float unfl = 1.17549435e-38f;
  const float tol  = 10.0f*eps;

  float sminoa = fabsf(d1);
  if (sminoa != 0.0f) {
    float mu = sminoa;
    mu = fabsf(d2)*(mu/(mu + fabsf(e1)));
    sminoa = fminf(sminoa, mu);
    if (sminoa != 0.0f) {
      mu = fabsf(d3)*(mu/(mu + fabsf(e2)));
      sminoa = fminf(sminoa, mu);
    }
  }
  sminoa = sminoa / sqrtf(3.0f);
  float thresh = fmaxf(tol*sminoa, 54.0f*unfl);

  int m = 3, oldll = -1, oldm = -1, idir = 0;
  int guard = 0;
  while (m > 1 && ++guard < 200) {
    if (m == 2) {
      if (fabsf(e1) <= thresh) { e1 = 0.0f; m = 1; continue; }
      float sigmn, sigmx, sinr, cosr, sinl, cosl;
      slasv2_f(d1, e1, d2, sigmn, sigmx, sinr, cosr, sinl, cosl);
      d1 = sigmx; d2 = sigmn; e1 = 0.0f;
      rotr<0,1>(vt, cosr, sinr);
      rotc<0,1>(u,  cosl, sinl);
      m = 0; continue;
    }
    // ---- m == 3 ----
    float smax = fabsf(d3);
    if (fabsf(e2) <= thresh) { e2 = 0.0f; m = 2; continue; }
    smax = fmaxf(smax, fmaxf(fabsf(d2), fabsf(e2)));
    if (fabsf(e1) <= thresh) {
      e1 = 0.0f;
      float sigmn, sigmx, sinr, cosr, sinl, cosl;
      slasv2_f(d2, e2, d3, sigmn, sigmx, sinr, cosr, sinl, cosl);
      d2 = sigmx; d3 = sigmn; e2 = 0.0f;
      rotr<1,2>(vt, cosr, sinr);
      rotc<1,2>(u,  cosl, sinl);
      m = 1; continue;
    }
    smax = fmaxf(smax, fmaxf(fabsf(d1), fabsf(e1)));

    if (1 > oldm || 3 < oldll)
      idir = (fabsf(d1) >= fabsf(d3)) ? 1 : 2;

    float sminl = 0.0f;
    if (idir == 1) {
      if (fabsf(e2) <= tol*fabsf(d3)) { e2 = 0.0f; continue; }
      float mu = fabsf(d1); sminl = mu;
      if (fabsf(e1) <= tol*mu) { e1 = 0.0f; continue; }
      mu = fabsf(d2)*(mu/(mu + fabsf(e1))); sminl = fminf(sminl, mu);
      if (fabsf(e2) <= tol*mu) { e2 = 0.0f; continue; }
      mu = fabsf(d3)*(mu/(mu + fabsf(e2))); sminl = fminf(sminl, mu);
    } else {
      if (fabsf(e1) <= tol*fabsf(d1)) { e1 = 0.0f; continue; }
      float mu = fabsf(d3); sminl = mu;
      if (fabsf(e2) <= tol*mu) { e2 = 0.0f; continue; }
      mu = fabsf(d2)*(mu/(mu + fabsf(e2))); sminl = fminf(sminl, mu);
      if (fabsf(e1) <= tol*mu) { e1 = 0.0f; continue; }
      mu = fabsf(d1)*(mu/(mu + fabsf(e1))); sminl = fminf(sminl, mu);
    }
    oldll = 1; oldm = 3;

    float shift = 0.0f, rdum;
    if (!(3.0f*tol*(sminl/smax) <= fmaxf(eps, 0.01f*tol))) {
      float sll;
      if (idir == 1) { sll = fabsf(d1); slas2_f(d2, e2, d3, shift, rdum); }
      else           { sll = fabsf(d3); slas2_f(d1, e1, d2, shift, rdum); }
      if (sll > 0.0f) { float qq = shift/sll; if (qq*qq < eps) shift = 0.0f; }
    }

    if (shift == 0.0f) {
      if (idir == 1) {
        float cs = 1.0f, oldcs = 1.0f, sn = 0.0f, oldsn = 0.0f, r;
        float c10, s10, c20, s20, c11, s11, c21, s21;
        slartg_f(d1*cs, e1, cs, sn, r);
        slartg_f(oldcs*r, d2*sn, oldcs, oldsn, d1);
        c10 = cs; s10 = sn; c20 = oldcs; s20 = oldsn;
        slartg_f(d2*cs, e2, cs, sn, r);
        e1 = oldsn*r;
        slartg_f(oldcs*r, d3*sn, oldcs, oldsn, d2);
        c11 = cs; s11 = sn; c21 = oldcs; s21 = oldsn;
        float h = d3*cs;
        d3 = h*oldcs; e2 = h*oldsn;
        rotr<0,1>(vt, c10, s10); rotr<1,2>(vt, c11, s11);
        rotc<0,1>(u,  c20, s20); rotc<1,2>(u,  c21, s21);
        if (fabsf(e2) <= thresh) e2 = 0.0f;
      } else {
        float cs = 1.0f, oldcs = 1.0f, sn = 0.0f, oldsn = 0.0f, r;
        float c10, s10, c20, s20, c11, s11, c21, s21;
        slartg_f(d3*cs, e2, cs, sn, r);
        slartg_f(oldcs*r, d2*sn, oldcs, oldsn, d3);
        c11 = cs; s11 = -sn; c21 = oldcs; s21 = -oldsn;
        slartg_f(d2*cs, e1, cs, sn, r);
        e2 = oldsn*r;
        slartg_f(oldcs*r, d1*sn, oldcs, oldsn, d2);
        c10 = cs; s10 = -sn; c20 = oldcs; s20 = -oldsn;
        float h = d1*cs;
        d1 = h*oldcs; e1 = h*oldsn;
        rotr<1,2>(vt, c21, s21); rotr<0,1>(vt, c20, s20);
        rotc<1,2>(u,  c11, s11); rotc<0,1>(u,  c10, s10);
        if (fabsf(e1) <= thresh) e1 = 0.0f;
      }
    } else {
      if (idir == 1) {
        float f = (fabsf(d1) - shift)*(copysignf(1.0f, d1) + shift/d1);
        float g = e1, cr, sr, cl, sl, r;
        float c10, s10, c20, s20, c11, s11, c21, s21;
        slartg_f(f, g, cr, sr, r);
        f = cr*d1 + sr*e1;  e1 = cr*e1 - sr*d1;
        g = sr*d2;  d2 = cr*d2;
        slartg_f(f, g, cl, sl, r);
        d1 = r;  f = cl*e1 + sl*d2;  d2 = cl*d2 - sl*e1;
        g = sl*e2;  e2 = cl*e2;
        c10 = cr; s10 = sr; c20 = cl; s20 = sl;
        slartg_f(f, g, cr, sr, r);
        e1 = r;
        f = cr*d2 + sr*e2;  e2 = cr*e2 - sr*d2;
        g = sr*d3;  d3 = cr*d3;
        slartg_f(f, g, cl, sl, r);
        d2 = r;  f = cl*e2 + sl*d3;  d3 = cl*d3 - sl*e2;
        c11 = cr; s11 = sr; c21 = cl; s21 = sl;
        e2 = f;
        rotr<0,1>(vt, c10, s10); rotr<1,2>(vt, c11, s11);
        rotc<0,1>(u,  c20, s20); rotc<1,2>(u,  c21, s21);
        if (fabsf(e2) <= thresh) e2 = 0.0f;
      } else {
        float f = (fabsf(d3) - shift)*(copysignf(1.0f, d3) + shift/d3);
        float g = e2, cr, sr, cl, sl, r;
        float c10, s10, c20, s20, c11, s11, c21, s21;
        slartg_f(f, g, cr, sr, r);
        f = cr*d3 + sr*e2;  e2 = cr*e2 - sr*d3;
        g = sr*d2;  d2 = cr*d2;
        slartg_f(f, g, cl, sl, r);
        d3 = r;  f = cl*e2 + sl*d2;  d2 = cl*d2 - sl*e2;
        g = sl*e1;  e1 = cl*e1;
        c11 = cr; s11 = -sr; c21 = cl; s21 = -sl;
        slartg_f(f, g, cr, sr, r);
        e2 = r;
        f = cr*d2 + sr*e1;  e1 = cr*e1 - sr*d2;
        g = sr*d1;  d1 = cr*d1;
        slartg_f(f, g, cl, sl, r);
        d2 = r;  f = cl*e1 + sl*d1;  d1 = cl*d1 - sl*e1;
        c10 = cr; s10 = -sr; c20 = cl; s20 = -sl;
        e1 = f;
        if (fabsf(e1) <= thresh) e1 = 0.0f;
        rotr<1,2>(vt, c21, s21); rotr<0,1>(vt, c20, s20);
        rotc<1,2>(u,  c11, s11); rotc<0,1>(u,  c10, s10);
      }
    }
  }

  if (d1 < 0.0f) { d1 = -d1; vt[0][0] = -vt[0][0]; vt[0][1] = -vt[0][1]; vt[0][2] = -vt[0][2]; }
  if (d2 < 0.0f) { d2 = -d2; vt[1][0] = -vt[1][0]; vt[1][1] = -vt[1][1]; vt[1][2] = -vt[1][2]; }
  if (d3 < 0.0f) { d3 = -d3; vt[2][0] = -vt[2][0]; vt[2][1] = -vt[2][1]; vt[2][2] = -vt[2][2]; }

  { // pass 1: min of (d1,d2,d3) -> slot 3
    int isub = 1; float smn = d1;
    if (d2 <= smn) { isub = 2; smn = d2; }
    if (d3 <= smn) { isub = 3; smn = d3; }
    if (isub == 1)      { d1 = d3; d3 = smn; swaprow<0,2>(vt); swapcol<0,2>(u); }
    else if (isub == 2) { d2 = d3; d3 = smn; swaprow<1,2>(vt); swapcol<1,2>(u); }
  }
  { // pass 2: min of (d1,d2) -> slot 2
    int isub = 1; float smn = d1;
    if (d2 <= smn) { isub = 2; smn = d2; }
    if (isub == 1) { d1 = d2; d2 = smn; swaprow<0,1>(vt); swapcol<0,1>(u); }
  }
}

__device__ __forceinline__ void svd3_gesdd(const float Ain[3][3], float u[3][3], float vt[3][3]) {
  float a[3][3];
#pragma unroll
  for (int i = 0; i < 3; ++i)
#pragma unroll
    for (int j = 0; j < 3; ++j) a[i][j] = Ain[i][j];

  float d1, d2, d3, e1, e2;
  float tq0 = 0.f, tq1 = 0.f, tp0 = 0.f;
  float v0a = 0.f, v0b = 0.f, v1a = 0.f, p0a = 0.f;

  {
    float alpha = a[0][0];
    float xn = sqrtf(a[1][0]*a[1][0] + a[2][0]*a[2][0]);
    if (xn == 0.0f) { tq0 = 0.0f; d1 = alpha; }
    else {
      float beta = -copysignf(sqrtf(alpha*alpha + xn*xn), alpha);
      tq0 = (beta - alpha)/beta;
      float sc = 1.0f/(alpha - beta);
      v0a = a[1][0]*sc; v0b = a[2][0]*sc;
      d1 = beta;
    }
#pragma unroll
    for (int j = 1; j < 3; ++j) {
      float w = (a[0][j] + v0a*a[1][j] + v0b*a[2][j])*tq0;
      a[0][j] -= w; a[1][j] -= w*v0a; a[2][j] -= w*v0b;
    }
  }
  {
    float alpha = a[0][1];
    float xn = fabsf(a[0][2]);
    if (xn == 0.0f) { tp0 = 0.0f; e1 = alpha; }
    else {
      float beta = -copysignf(sqrtf(alpha*alpha + xn*xn), alpha);
      tp0 = (beta - alpha)/beta;
      p0a = a[0][2]/(alpha - beta);
      e1 = beta;
    }
#pragma unroll
    for (int i = 1; i < 3; ++i) {
      float w = (a[i][1] + p0a*a[i][2])*tp0;
      a[i][1] -= w; a[i][2] -= w*p0a;
    }
  }
  {
    float alpha = a[1][1];
    float xn = fabsf(a[2][1]);
    if (xn == 0.0f) { tq1 = 0.0f; d2 = alpha; }
    else {
      float beta = -copysignf(sqrtf(alpha*alpha + xn*xn), alpha);
      tq1 = (beta - alpha)/beta;
      v1a = a[2][1]/(alpha - beta);
      d2 = beta;
    }
    float w = (a[1][2] + v1a*a[2][2])*tq1;
    a[1][2] -= w; a[2][2] -= w*v1a;
  }
  e2 = a[1][2];
  d3 = a[2][2];

  float ub[3][3] = {{1,0,0},{0,1,0},{0,0,1}};
  float vb[3][3] = {{1,0,0},{0,1,0},{0,0,1}};
  sbdsqr3_reg(d1, d2, d3, e1, e2, ub, vb);

#pragma unroll
  for (int j = 0; j < 3; ++j) {
    float w = (ub[1][j] + v1a*ub[2][j])*tq1;
    ub[1][j] -= w; ub[2][j] -= w*v1a;
  }
#pragma unroll
  for (int j = 0; j < 3; ++j) {
    float w = (ub[0][j] + v0a*ub[1][j] + v0b*ub[2][j])*tq0;
    ub[0][j] -= w; ub[1][j] -= w*v0a; ub[2][j] -= w*v0b;
  }
#pragma unroll
  for (int i = 0; i < 3; ++i) {
    float w = (vb[i][1] + p0a*vb[i][2])*tp0;
    vb[i][1] -= w; vb[i][2] -= w*p0a;
  }
#pragma unroll
  for (int i = 0; i < 3; ++i)
#pragma unroll
    for (int j = 0; j < 3; ++j) { u[i][j] = ub[i][j]; vt[i][j] = vb[i][j]; }
}

// =============================================================================
// bf16 helpers (RNE, manual — verified since round 1)
// =============================================================================
__device__ __forceinline__ unsigned int f2bf(float x) {
  unsigned int u = __float_as_uint(x);
  return (u + 0x7FFFu + ((u >> 16) & 1u)) >> 16;
}
__device__ __forceinline__ float bf2f(unsigned int h) {
  return __uint_as_float(h << 16);
}

// =============================================================================
// Kernel 0: pack. (unchanged)
// =============================================================================
__global__ __launch_bounds__(128)
void pack_kernel(const float* __restrict__ srcE, const float* __restrict__ tgtE,
                 const float* __restrict__ tgt,
                 unsigned short* __restrict__ Qp, unsigned short* __restrict__ Kp,
                 unsigned short* __restrict__ Vt4) {
  const int g = blockIdx.x*128 + threadIdx.x;   // 32768 = 16*2048
  const int b = g >> 11, n = g & 2047;
  const float* qs = srcE + (size_t)b*16*2048 + n;
  const float* ks = tgtE + (size_t)b*16*2048 + n;
  const float QSCALE = 0.25f * 1.44269504088896340736f;

  unsigned short qrow[32], krow[32];
#pragma unroll
  for (int dd = 0; dd < 16; ++dd) {
    float q = qs[dd*2048] * QSCALE;
    unsigned int qh = f2bf(q);
    qrow[dd] = (unsigned short)qh; qrow[16+dd] = (unsigned short)f2bf(q - bf2f(qh));
    float k = ks[dd*2048];
    unsigned int kh = f2bf(k);
    krow[dd] = (unsigned short)kh; krow[16+dd] = (unsigned short)f2bf(k - bf2f(kh));
  }
  uint4* qdst = (uint4*)(Qp + (size_t)g*32);
  uint4* kdst = (uint4*)(Kp + (size_t)g*32);
#pragma unroll
  for (int i = 0; i < 4; ++i) { qdst[i] = ((uint4*)qrow)[i]; kdst[i] = ((uint4*)krow)[i]; }

  const float* vp = tgt + (size_t)b*3*2048 + n;
  unsigned short* wb = Vt4 + (size_t)b*4*2048;
  wb[n]          = 0x3F80;             // ones column (j=0)
  wb[2048 + n]   = (unsigned short)f2bf(vp[0]);
  wb[2*2048 + n] = (unsigned short)f2bf(vp[2048]);
  wb[3*2048 + n] = (unsigned short)f2bf(vp[4096]);
}

// =============================================================================
// Kernel 1: MFMA flash attention; PV + softmax-sum via MFMA.
// ROUND 11 CHANGE: A'-staging row stride 64B -> 80B. Old stride folded all 64
// lanes onto 8 banks (8-way conflict, SQ_LDS_BANK_CONFLICT=7.86M). 80B = 20
// banks mod 32: write banks (ll*20+lg*2)%32 distinct except (ll,ll+8) pairs
// -> 2-way (free, m136); read spans likewise ~2-way. 16B alignment kept.
// =============================================================================
__global__ __launch_bounds__(512, 4)
void corr_kernel(const unsigned short* __restrict__ Qp, const unsigned short* __restrict__ Kp,
                 const unsigned short* __restrict__ Vt4, const float* __restrict__ src,
                 float* __restrict__ ws) {
  const int bid = blockIdx.x;
  const int b   = bid & 15;
  const int nt  = bid >> 4;          // 0..31, 64 n each
  const int tid = threadIdx.x;
  const int w   = tid >> 6;
  const int L   = tid & 63;
  const int lg  = L >> 4;
  const int ll  = L & 15;

  __shared__ __align__(16) char  stage[8*1280];       // 10 KB: per-wave A' staging (80B rows)
  __shared__ __align__(16) float partial[8][64][4];   // 8 KB

  const unsigned short* Qb = Qp + (size_t)b*2048*32;
  const unsigned short* Kb = Kp + (size_t)b*2048*32;
  const unsigned short* Wb = Vt4 + (size_t)b*4*2048;

  const bf16x8 zero8 = {0,0,0,0,0,0,0,0};
  char* my = stage + w*1280;
  char* wr0 = my + ll*80 + lg*8;        // tile0 write slot
  char* wr1 = wr0 + 32;                 // tile1 write slot
  const char* rd = my + ll*80 + lg*16;  // A'-frag read slot (16B aligned: 80=16*5)

  // ---- Q-fragments for this block's 4 n-tiles ----
  bf16x8 bq1[4], bq2[4];
#pragma unroll
  for (int t2 = 0; t2 < 4; ++t2) {
    const unsigned short* qr = Qb + (size_t)(nt*64 + t2*16 + ll)*32;
    bq1[t2] = *(const bf16x8*)(qr + (lg & 1)*8);
    bf16x8 lo = *(const bf16x8*)(qr + 16 + (lg & 1)*8);
    bq2[t2] = (lg < 2) ? lo : zero8;
  }

  f32x4 accp[4];
#pragma unroll
  for (int t2 = 0; t2 < 4; ++t2) accp[t2] = (f32x4){0.f, 0.f, 0.f, 0.f};

  for (int p = w; p < 64; p += 8) {
    const unsigned short* ar = Kb + (size_t)(p*32 + ll)*32;
    bf16x8 a0 = *(const bf16x8*)(ar + lg*8);            // m-tile 2p
    bf16x8 a1 = *(const bf16x8*)(ar + 16*32 + lg*8);    // m-tile 2p+1
    bf16x8 wv = zero8;                                  // W B-frag (cols>=4 zero)
    if (ll < 4) wv = *(const bf16x8*)(Wb + (size_t)ll*2048 + p*32 + lg*8);

#pragma unroll
    for (int t2 = 0; t2 < 4; ++t2) {
      f32x4 c0 = (f32x4){0.f,0.f,0.f,0.f};
      f32x4 c1 = (f32x4){0.f,0.f,0.f,0.f};
      c0 = __builtin_amdgcn_mfma_f32_16x16x32_bf16(a0, bq1[t2], c0, 0, 0, 0);
      c0 = __builtin_amdgcn_mfma_f32_16x16x32_bf16(a0, bq2[t2], c0, 0, 0, 0);
      c1 = __builtin_amdgcn_mfma_f32_16x16x32_bf16(a1, bq1[t2], c1, 0, 0, 0);
      c1 = __builtin_amdgcn_mfma_f32_16x16x32_bf16(a1, bq2[t2], c1, 0, 0, 0);
      // P = exp2(scores); C-frag: row m_loc = lg*4+r, col n = ll
      float e0 = __builtin_amdgcn_exp2f(c0.x), e1 = __builtin_amdgcn_exp2f(c0.y);
      float e2 = __builtin_amdgcn_exp2f(c0.z), e3 = __builtin_amdgcn_exp2f(c0.w);
      float f0 = __builtin_amdgcn_exp2f(c1.x), f1 = __builtin_amdgcn_exp2f(c1.y);
      float f2 = __builtin_amdgcn_exp2f(c1.z), f3 = __builtin_amdgcn_exp2f(c1.w);
      // pack to bf16 pairs (lo = even r) and stage into A' layout
      *(uint2*)wr0 = make_uint2(f2bf(e0) | (f2bf(e1) << 16),
                                f2bf(e2) | (f2bf(e3) << 16));
      *(uint2*)wr1 = make_uint2(f2bf(f0) | (f2bf(f1) << 16),
                                f2bf(f2) | (f2bf(f3) << 16));
      bf16x8 pa = *(const bf16x8*)rd;   // A'[row=ll][k=lg*8..+7]
      // PV: X[n][j] += P^T x W   (j: 0=sumE, 1..3 = sum e*v)
      accp[t2] = __builtin_amdgcn_mfma_f32_16x16x32_bf16(pa, wv, accp[t2], 0, 0, 0);
    }
  }

  // ---- write per-wave partials: X[j=ll][n] for ll<4 ----
  if (ll < 4) {
#pragma unroll
    for (int t2 = 0; t2 < 4; ++t2) {
      int nb = t2*16 + lg*4;
      partial[w][nb+0][ll] = accp[t2].x;
      partial[w][nb+1][ll] = accp[t2].y;
      partial[w][nb+2][ll] = accp[t2].z;
      partial[w][nb+3][ll] = accp[t2].w;
    }
  }
  __syncthreads();

  // ---- per-n finish + 15-value single-wave reduction (wave 0 only) ----
  if (tid < 64) {
    float4 s4 = make_float4(0.f, 0.f, 0.f, 0.f);
#pragma unroll
    for (int w2 = 0; w2 < 8; ++w2) {
      float4 pq = *(const float4*)&partial[w2][tid][0];
      s4.x += pq.x; s4.y += pq.y; s4.z += pq.z; s4.w += pq.w;
    }
    float inv = 1.0f / s4.x;
    float c0 = s4.y*inv, c1 = s4.z*inv, c2 = s4.w*inv;
    const int n = nt*64 + tid;
    const float* sp = src + (size_t)b*3*2048;
    float s0v = sp[n], s1v = sp[2048+n], s2v = sp[4096+n];
    float vals[15] = { c0, c1, c2, s0v, s1v, s2v,
                       s0v*c0, s0v*c1, s0v*c2,
                       s1v*c0, s1v*c1, s1v*c2,
                       s2v*c0, s2v*c1, s2v*c2 };
#pragma unroll
    for (int k = 0; k < 15; ++k) {
      float v = vals[k];
      v += __shfl_xor(v, 1);  v += __shfl_xor(v, 2);  v += __shfl_xor(v, 4);
      v += __shfl_xor(v, 8);  v += __shfl_xor(v, 16); v += __shfl_xor(v, 32);
      vals[k] = v;
    }
    if (tid == 0) {
#pragma unroll
      for (int k = 0; k < 15; ++k) ws[bid*16 + k] = vals[k];
    }
  }
}

// =============================================================================
// Kernel 2: ONE block, 16 waves; wave w = batch w; lane 0 runs the SVD
// (fully register-resident, round-10-verified).
// =============================================================================
__global__ __launch_bounds__(1024)
void finalize_kernel(const float* __restrict__ ws, float* __restrict__ out) {
  const int b = threadIdx.x >> 6;
  const int L = threadIdx.x & 63;

  float a = 0.0f;
  if (L < 15) {
#pragma unroll
    for (int ntile = 0; ntile < 32; ++ntile)
      a += ws[(ntile*16 + b)*16 + L];
  }
  float acc[15];
#pragma unroll
  for (int k = 0; k < 15; ++k) acc[k] = __shfl(a, k);

  if (L == 0) {
    const float invN = 1.0f/2048.0f;
    float Sc[3] = {acc[0], acc[1], acc[2]};
    float Ss[3] = {acc[3], acc[4], acc[5]};
    float cm[3] = {Sc[0]*invN, Sc[1]*invN, Sc[2]*invN};
    float sm[3] = {Ss[0]*invN, Ss[1]*invN, Ss[2]*invN};

    float A[3][3];
#pragma unroll
    for (int i = 0; i < 3; ++i)
#pragma unroll
      for (int j = 0; j < 3; ++j)
        A[i][j] = acc[6 + i*3 + j] - Ss[i]*cm[j];

    float u[3][3], vt[3][3];
    svd3_gesdd(A, u, vt);

    float R[3][3];
#pragma unroll
    for (int i = 0; i < 3; ++i)
#pragma unroll
      for (int k = 0; k < 3; ++k)
        R[i][k] = vt[i][0]*u[k][0] + vt[i][1]*u[k][1] + vt[i][2]*u[k][2];

    float det = R[0][0]*(R[1][1]*R[2][2] - R[1][2]*R[2][1])
              - R[0][1]*(R[1][0]*R[2][2] - R[1][2]*R[2][0])
              + R[0][2]*(R[1][0]*R[2][1] - R[1][1]*R[2][0]);

    if (det < 0.0f) {
#pragma unroll
      for (int i = 0; i < 3; ++i)
#pragma unroll
        for (int k = 0; k < 3; ++k)
          R[i][k] -= 2.0f*vt[i][2]*u[k][2];
    }

    float tv[3];
#pragma unroll
    for (int i = 0; i < 3; ++i)
      tv[i] = -(R[i][0]*sm[0] + R[i][1]*sm[1] + R[i][2]*sm[2]) + cm[i];

#pragma unroll
    for (int i = 0; i < 3; ++i)
#pragma unroll
      for (int j = 0; j < 3; ++j)
        out[b*9 + i*3 + j] = R[i][j];
#pragma unroll
    for (int i = 0; i < 3; ++i)
      out[144 + b*3 + i] = tv[i];
  }
}

extern "C" void kernel_launch(void* const* d_in, const int* in_sizes, int n_in,
                              void* d_out, int out_size, void* d_ws, size_t ws_size,
                              hipStream_t stream) {
  const float* srcE = (const float*)d_in[0];
  const float* tgtE = (const float*)d_in[1];
  const float* src  = (const float*)d_in[2];
  const float* tgt  = (const float*)d_in[3];
  float* out = (float*)d_out;

  // ws layout: [0,32KB) partials | Qp 2MB | Kp 2MB | Vt4 256KB
  float* part = (float*)d_ws;
  unsigned short* Qp  = (unsigned short*)((char*)d_ws + 32768);
  unsigned short* Kp  = (unsigned short*)((char*)d_ws + 32768 + (size_t)16*2048*32*2);
  unsigned short* Vt4 = (unsigned short*)((char*)d_ws + 32768 + (size_t)2*16*2048*32*2);

  hipLaunchKernelGGL(pack_kernel, dim3(256), dim3(128), 0, stream, srcE, tgtE, tgt, Qp, Kp, Vt4);
  hipLaunchKernelGGL(corr_kernel, dim3(512), dim3(512), 0, stream, Qp, Kp, Vt4, src, part);
  hipLaunchKernelGGL(finalize_kernel, dim3(1), dim3(1024), 0, stream, part, out);
}

// Round 12
// 39.022 us; speedup vs baseline: 2.2549x; 1.2139x over previous
//
#include <hip/hip_runtime.h>
#include <math.h>

// LAPACK >= 3.10 slartg convention (c >= 0). Flip to 0 to emulate <= 3.9.
#define NEW_SLARTG 1

typedef __attribute__((ext_vector_type(8))) short bf16x8;
typedef __attribute__((ext_vector_type(4))) float f32x4;

// =============================================================================
// LAPACK sgesdd emulation for 3x3 (f32), faithful sign conventions.
// FULLY SCALARIZED (round 10), run ONE SVD PER CU (round 12: the 1-block/16-
// wave layout thrashed one CU's L1-i with 16 divergent serial paths; round-2
// data shows 16-block layout is ~2x faster even with worse code).
// =============================================================================

__device__ __forceinline__ void slartg_f(float f, float g, float& c, float& s, float& r) {
#if NEW_SLARTG
  if (g == 0.0f) { c = 1.0f; s = 0.0f; r = f; }
  else if (f == 0.0f) { c = 0.0f; s = copysignf(1.0f, g); r = fabsf(g); }
  else {
    float d = sqrtf(f*f + g*g);
    c = fabsf(f) / d;
    r = copysignf(d, f);
    s = g / r;
  }
#else
  if (g == 0.0f) { c = 1.0f; s = 0.0f; r = f; }
  else if (f == 0.0f) { c = 0.0f; s = 1.0f; r = g; }
  else {
    float d = sqrtf(f*f + g*g);
    c = f / d; s = g / d; r = d;
    if (fabsf(f) > fabsf(g) && c < 0.0f) { c = -c; s = -s; r = -r; }
  }
#endif
}

__device__ __forceinline__ void slas2_f(float f, float g, float h, float& ssmin, float& ssmax) {
  float fa = fabsf(f), ga = fabsf(g), ha = fabsf(h);
  float fhmn = fminf(fa, ha), fhmx = fmaxf(fa, ha);
  if (fhmn == 0.0f) {
    ssmin = 0.0f;
    if (fhmx == 0.0f) ssmax = ga;
    else {
      float mn = fminf(fhmx, ga), mx = fmaxf(fhmx, ga);
      float qq = mn / mx;
      ssmax = mx * sqrtf(1.0f + qq*qq);
    }
  } else {
    if (ga < fhmx) {
      float as_ = 1.0f + fhmn/fhmx;
      float at_ = (fhmx - fhmn)/fhmx;
      float au_ = ga/fhmx; au_ = au_*au_;
      float c = 2.0f/(sqrtf(as_*as_ + au_) + sqrtf(at_*at_ + au_));
      ssmin = fhmn*c;
      ssmax = fhmx/c;
    } else {
      float au_ = fhmx/ga;
      if (au_ == 0.0f) {
        ssmin = (fhmn*fhmx)/ga;
        ssmax = ga;
      } else {
        float as_ = 1.0f + fhmn/fhmx;
        float at_ = (fhmx - fhmn)/fhmx;
        float t1 = as_*au_, t2 = at_*au_;
        float c = 1.0f/(sqrtf(1.0f + t1*t1) + sqrtf(1.0f + t2*t2));
        ssmin = (fhmn*c)*au_;
        ssmin = ssmin + ssmin;
        ssmax = ga/(c + c);
      }
    }
  }
}

__device__ __forceinline__ void slasv2_f(float f, float g, float h,
                         float& ssmin, float& ssmax,
                         float& snr, float& csr, float& snl, float& csl) {
  const float eps = 5.9604645e-08f;
  float ft = f, fa = fabsf(f), ht = h, ha = fabsf(h);
  int pmax = 1;
  bool swap_ = (ha > fa);
  if (swap_) {
    pmax = 3;
    float tq = ft; ft = ht; ht = tq;
    tq = fa; fa = ha; ha = tq;
  }
  float gt = g, ga = fabsf(g);
  float clt = 0.f, crt = 0.f, slt = 0.f, srt = 0.f;
  if (ga == 0.0f) {
    ssmin = ha; ssmax = fa;
    clt = 1.0f; crt = 1.0f; slt = 0.0f; srt = 0.0f;
  } else {
    bool gasmal = true;
    if (ga > fa) {
      pmax = 2;
      if ((fa/ga) < eps) {
        gasmal = false;
        ssmax = ga;
        ssmin = (ha > 1.0f) ? (fa/(ga/ha)) : ((fa/ga)*ha);
        clt = 1.0f; slt = ht/gt; srt = 1.0f; crt = ft/gt;
      }
    }
    if (gasmal) {
      float dd = fa - ha;
      float l = (dd == fa) ? 1.0f : (dd/fa);
      float mr = gt/ft;
      float t = 2.0f - l;
      float mm2 = mr*mr, tt = t*t;
      float s_ = sqrtf(tt + mm2);
      float r_ = (l == 0.0f) ? fabsf(mr) : sqrtf(l*l + mm2);
      float a_ = 0.5f*(s_ + r_);
      ssmin = ha/a_;
      ssmax = fa*a_;
      if (mm2 == 0.0f) {
        if (l == 0.0f) t = copysignf(2.0f, ft)*copysignf(1.0f, gt);
        else t = gt/copysignf(dd, ft) + mr/t;
      } else {
        t = (mr/(s_ + t) + mr/(r_ + l))*(1.0f + a_);
      }
      float l2 = sqrtf(t*t + 4.0f);
      crt = 2.0f/l2;
      srt = t/l2;
      clt = (crt + srt*mr)/a_;
      slt = (ht/ft)*srt/a_;
    }
  }
  if (swap_) { csl = srt; snl = crt; csr = slt; snr = clt; }
  else       { csl = clt; snl = slt; csr = crt; snr = srt; }
  float tsign = 0.f;
  if (pmax == 1) tsign = copysignf(1.0f, csr)*copysignf(1.0f, csl)*copysignf(1.0f, f);
  if (pmax == 2) tsign = copysignf(1.0f, snr)*copysignf(1.0f, csl)*copysignf(1.0f, g);
  if (pmax == 3) tsign = copysignf(1.0f, snr)*copysignf(1.0f, snl)*copysignf(1.0f, h);
  ssmax = copysignf(ssmax, tsign);
  ssmin = copysignf(ssmin, tsign*copysignf(1.0f, f)*copysignf(1.0f, h));
}

// rotation / swap helpers with COMPILE-TIME indices (template params)
template<int R1, int R2>
__device__ __forceinline__ void rotr(float mt[3][3], float c, float s) {
#pragma unroll
  for (int k = 0; k < 3; ++k) {
    float x = mt[R1][k], y = mt[R2][k];
    mt[R1][k] = c*x + s*y;
    mt[R2][k] = c*y - s*x;
  }
}
template<int C1, int C2>
__device__ __forceinline__ void rotc(float mt[3][3], float c, float s) {
#pragma unroll
  for (int k = 0; k < 3; ++k) {
    float x = mt[k][C1], y = mt[k][C2];
    mt[k][C1] = c*x + s*y;
    mt[k][C2] = c*y - s*x;
  }
}
template<int R1, int R2>
__device__ __forceinline__ void swaprow(float mt[3][3]) {
#pragma unroll
  for (int k = 0; k < 3; ++k) { float t = mt[R1][k]; mt[R1][k] = mt[R2][k]; mt[R2][k] = t; }
}
template<int C1, int C2>
__device__ __forceinline__ void swapcol(float mt[3][3]) {
#pragma unroll
  for (int k = 0; k < 3; ++k) { float t = mt[k][C1]; mt[k][C1] = mt[k][C2]; mt[k][C2] = t; }
}

// SBDSQR specialized for n=3 upper bidiagonal, all-register state.
__device__ __forceinline__ void sbdsqr3_reg(float& d1, float& d2, float& d3,
                                            float& e1, float& e2,
                                            float u[3][3], float vt[3][3]) {
  const float eps  = 5.9604645e-08f;
  const float unfl = 1.17549435e-38f;
  const float tol  = 10.0f*eps;

  float sminoa = fabsf(d1);
  if (sminoa != 0.0f) {
    float mu = sminoa;
    mu = fabsf(d2)*(mu/(mu + fabsf(e1)));
    sminoa = fminf(sminoa, mu);
    if (sminoa != 0.0f) {
      mu = fabsf(d3)*(mu/(mu + fabsf(e2)));
      sminoa = fminf(sminoa, mu);
    }
  }
  sminoa = sminoa / sqrtf(3.0f);
  float thresh = fmaxf(tol*sminoa, 54.0f*unfl);

  int m = 3, oldll = -1, oldm = -1, idir = 0;
  int guard = 0;
  while (m > 1 && ++guard < 200) {
    if (m == 2) {
      if (fabsf(e1) <= thresh) { e1 = 0.0f; m = 1; continue; }
      float sigmn, sigmx, sinr, cosr, sinl, cosl;
      slasv2_f(d1, e1, d2, sigmn, sigmx, sinr, cosr, sinl, cosl);
      d1 = sigmx; d2 = sigmn; e1 = 0.0f;
      rotr<0,1>(vt, cosr, sinr);
      rotc<0,1>(u,  cosl, sinl);
      m = 0; continue;
    }
    // ---- m == 3 ----
    float smax = fabsf(d3);
    if (fabsf(e2) <= thresh) { e2 = 0.0f; m = 2; continue; }
    smax = fmaxf(smax, fmaxf(fabsf(d2), fabsf(e2)));
    if (fabsf(e1) <= thresh) {
      e1 = 0.0f;
      float sigmn, sigmx, sinr, cosr, sinl, cosl;
      slasv2_f(d2, e2, d3, sigmn, sigmx, sinr, cosr, sinl, cosl);
      d2 = sigmx; d3 = sigmn; e2 = 0.0f;
      rotr<1,2>(vt, cosr, sinr);
      rotc<1,2>(u,  cosl, sinl);
      m = 1; continue;
    }
    smax = fmaxf(smax, fmaxf(fabsf(d1), fabsf(e1)));

    if (1 > oldm || 3 < oldll)
      idir = (fabsf(d1) >= fabsf(d3)) ? 1 : 2;

    float sminl = 0.0f;
    if (idir == 1) {
      if (fabsf(e2) <= tol*fabsf(d3)) { e2 = 0.0f; continue; }
      float mu = fabsf(d1); sminl = mu;
      if (fabsf(e1) <= tol*mu) { e1 = 0.0f; continue; }
      mu = fabsf(d2)*(mu/(mu + fabsf(e1))); sminl = fminf(sminl, mu);
      if (fabsf(e2) <= tol*mu) { e2 = 0.0f; continue; }
      mu = fabsf(d3)*(mu/(mu + fabsf(e2))); sminl = fminf(sminl, mu);
    } else {
      if (fabsf(e1) <= tol*fabsf(d1)) { e1 = 0.0f; continue; }
      float mu = fabsf(d3); sminl = mu;
      if (fabsf(e2) <= tol*mu) { e2 = 0.0f; continue; }
      mu = fabsf(d2)*(mu/(mu + fabsf(e2))); sminl = fminf(sminl, mu);
      if (fabsf(e1) <= tol*mu) { e1 = 0.0f; continue; }
      mu = fabsf(d1)*(mu/(mu + fabsf(e1))); sminl = fminf(sminl, mu);
    }
    oldll = 1; oldm = 3;

    float shift = 0.0f, rdum;
    if (!(3.0f*tol*(sminl/smax) <= fmaxf(eps, 0.01f*tol))) {
      float sll;
      if (idir == 1) { sll = fabsf(d1); slas2_f(d2, e2, d3, shift, rdum); }
      else           { sll = fabsf(d3); slas2_f(d1, e1, d2, shift, rdum); }
      if (sll > 0.0f) { float qq = shift/sll; if (qq*qq < eps) shift = 0.0f; }
    }

    if (shift == 0.0f) {
      if (idir == 1) {
        float cs = 1.0f, oldcs = 1.0f, sn = 0.0f, oldsn = 0.0f, r;
        float c10, s10, c20, s20, c11, s11, c21, s21;
        slartg_f(d1*cs, e1, cs, sn, r);
        slartg_f(oldcs*r, d2*sn, oldcs, oldsn, d1);
        c10 = cs; s10 = sn; c20 = oldcs; s20 = oldsn;
        slartg_f(d2*cs, e2, cs, sn, r);
        e1 = oldsn*r;
        slartg_f(oldcs*r, d3*sn, oldcs, oldsn, d2);
        c11 = cs; s11 = sn; c21 = oldcs; s21 = oldsn;
        float h = d3*cs;
        d3 = h*oldcs; e2 = h*oldsn;
        rotr<0,1>(vt, c10, s10); rotr<1,2>(vt, c11, s11);
        rotc<0,1>(u,  c20, s20); rotc<1,2>(u,  c21, s21);
        if (fabsf(e2) <= thresh) e2 = 0.0f;
      } else {
        float cs = 1.0f, oldcs = 1.0f, sn = 0.0f, oldsn = 0.0f, r;
        float c10, s10, c20, s20, c11, s11, c21, s21;
        slartg_f(d3*cs, e2, cs, sn, r);
        slartg_f(oldcs*r, d2*sn, oldcs, oldsn, d3);
        c11 = cs; s11 = -sn; c21 = oldcs; s21 = -oldsn;
        slartg_f(d2*cs, e1, cs, sn, r);
        e2 = oldsn*r;
        slartg_f(oldcs*r, d1*sn, oldcs, oldsn, d2);
        c10 = cs; s10 = -sn; c20 = oldcs; s20 = -oldsn;
        float h = d1*cs;
        d1 = h*oldcs; e1 = h*oldsn;
        rotr<1,2>(vt, c21, s21); rotr<0,1>(vt, c20, s20);
        rotc<1,2>(u,  c11, s11); rotc<0,1>(u,  c10, s10);
        if (fabsf(e1) <= thresh) e1 = 0.0f;
      }
    } else {
      if (idir == 1) {
        float f = (fabsf(d1) - shift)*(copysignf(1.0f, d1) + shift/d1);
        float g = e1, cr, sr, cl, sl, r;
        float c10, s10, c20, s20, c11, s11, c21, s21;
        slartg_f(f, g, cr, sr, r);
        f = cr*d1 + sr*e1;  e1 = cr*e1 - sr*d1;
        g = sr*d2;  d2 = cr*d2;
        slartg_f(f, g, cl, sl, r);
        d1 = r;  f = cl*e1 + sl*d2;  d2 = cl*d2 - sl*e1;
        g = sl*e2;  e2 = cl*e2;
        c10 = cr; s10 = sr; c20 = cl; s20 = sl;
        slartg_f(f, g, cr, sr, r);
        e1 = r;
        f = cr*d2 + sr*e2;  e2 = cr*e2 - sr*d2;
        g = sr*d3;  d3 = cr*d3;
        slartg_f(f, g, cl, sl, r);
        d2 = r;  f = cl*e2 + sl*d3;  d3 = cl*d3 - sl*e2;
        c11 = cr; s11 = sr; c21 = cl; s21 = sl;
        e2 = f;
        rotr<0,1>(vt, c10, s10); rotr<1,2>(vt, c11, s11);
        rotc<0,1>(u,  c20, s20); rotc<1,2>(u,  c21, s21);
        if (fabsf(e2) <= thresh) e2 = 0.0f;
      } else {
        float f = (fabsf(d3) - shift)*(copysignf(1.0f, d3) + shift/d3);
        float g = e2, cr, sr, cl, sl, r;
        float c10, s10, c20, s20, c11, s11, c21, s21;
        slartg_f(f, g, cr, sr, r);
        f = cr*d3 + sr*e2;  e2 = cr*e2 - sr*d3;
        g = sr*d2;  d2 = cr*d2;
        slartg_f(f, g, cl, sl, r);
        d3 = r;  f = cl*e2 + sl*d2;  d2 = cl*d2 - sl*e2;
        g = sl*e1;  e1 = cl*e1;
        c11 = cr; s11 = -sr; c21 = cl; s21 = -sl;
        slartg_f(f, g, cr, sr, r);
        e2 = r;
        f = cr*d2 + sr*e1;  e1 = cr*e1 - sr*d2;
        g = sr*d1;  d1 = cr*d1;
        slartg_f(f, g, cl, sl, r);
        d2 = r;  f = cl*e1 + sl*d1;  d1 = cl*d1 - sl*e1;
        c10 = cr; s10 = -sr; c20 = cl; s20 = -sl;
        e1 = f;
        if (fabsf(e1) <= thresh) e1 = 0.0f;
        rotr<1,2>(vt, c21, s21); rotr<0,1>(vt, c20, s20);
        rotc<1,2>(u,  c11, s11); rotc<0,1>(u,  c10, s10);
      }
    }
  }

  if (d1 < 0.0f) { d1 = -d1; vt[0][0] = -vt[0][0]; vt[0][1] = -vt[0][1]; vt[0][2] = -vt[0][2]; }
  if (d2 < 0.0f) { d2 = -d2; vt[1][0] = -vt[1][0]; vt[1][1] = -vt[1][1]; vt[1][2] = -vt[1][2]; }
  if (d3 < 0.0f) { d3 = -d3; vt[2][0] = -vt[2][0]; vt[2][1] = -vt[2][1]; vt[2][2] = -vt[2][2]; }

  { // pass 1: min of (d1,d2,d3) -> slot 3
    int isub = 1; float smn = d1;
    if (d2 <= smn) { isub = 2; smn = d2; }
    if (d3 <= smn) { isub = 3; smn = d3; }
    if (isub == 1)      { d1 = d3; d3 = smn; swaprow<0,2>(vt); swapcol<0,2>(u); }
    else if (isub == 2) { d2 = d3; d3 = smn; swaprow<1,2>(vt); swapcol<1,2>(u); }
  }
  { // pass 2: min of (d1,d2) -> slot 2
    int isub = 1; float smn = d1;
    if (d2 <= smn) { isub = 2; smn = d2; }
    if (isub == 1) { d1 = d2; d2 = smn; swaprow<0,1>(vt); swapcol<0,1>(u); }
  }
}

__device__ __forceinline__ void svd3_gesdd(const float Ain[3][3], float u[3][3], float vt[3][3]) {
  float a[3][3];
#pragma unroll
  for (int i = 0; i < 3; ++i)
#pragma unroll
    for (int j = 0; j < 3; ++j) a[i][j] = Ain[i][j];

  float d1, d2, d3, e1, e2;
  float tq0 = 0.f, tq1 = 0.f, tp0 = 0.f;
  float v0a = 0.f, v0b = 0.f, v1a = 0.f, p0a = 0.f;

  {
    float alpha = a[0][0];
    float xn = sqrtf(a[1][0]*a[1][0] + a[2][0]*a[2][0]);
    if (xn == 0.0f) { tq0 = 0.0f; d1 = alpha; }
    else {
      float beta = -copysignf(sqrtf(alpha*alpha + xn*xn), alpha);
      tq0 = (beta - alpha)/beta;
      float sc = 1.0f/(alpha - beta);
      v0a = a[1][0]*sc; v0b = a[2][0]*sc;
      d1 = beta;
    }
#pragma unroll
    for (int j = 1; j < 3; ++j) {
      float w = (a[0][j] + v0a*a[1][j] + v0b*a[2][j])*tq0;
      a[0][j] -= w; a[1][j] -= w*v0a; a[2][j] -= w*v0b;
    }
  }
  {
    float alpha = a[0][1];
    float xn = fabsf(a[0][2]);
    if (xn == 0.0f) { tp0 = 0.0f; e1 = alpha; }
    else {
      float beta = -copysignf(sqrtf(alpha*alpha + xn*xn), alpha);
      tp0 = (beta - alpha)/beta;
      p0a = a[0][2]/(alpha - beta);
      e1 = beta;
    }
#pragma unroll
    for (int i = 1; i < 3; ++i) {
      float w = (a[i][1] + p0a*a[i][2])*tp0;
      a[i][1] -= w; a[i][2] -= w*p0a;
    }
  }
  {
    float alpha = a[1][1];
    float xn = fabsf(a[2][1]);
    if (xn == 0.0f) { tq1 = 0.0f; d2 = alpha; }
    else {
      float beta = -copysignf(sqrtf(alpha*alpha + xn*xn), alpha);
      tq1 = (beta - alpha)/beta;
      v1a = a[2][1]/(alpha - beta);
      d2 = beta;
    }
    float w = (a[1][2] + v1a*a[2][2])*tq1;
    a[1][2] -= w; a[2][2] -= w*v1a;
  }
  e2 = a[1][2];
  d3 = a[2][2];

  float ub[3][3] = {{1,0,0},{0,1,0},{0,0,1}};
  float vb[3][3] = {{1,0,0},{0,1,0},{0,0,1}};
  sbdsqr3_reg(d1, d2, d3, e1, e2, ub, vb);

#pragma unroll
  for (int j = 0; j < 3; ++j) {
    float w = (ub[1][j] + v1a*ub[2][j])*tq1;
    ub[1][j] -= w; ub[2][j] -= w*v1a;
  }
#pragma unroll
  for (int j = 0; j < 3; ++j) {
    float w = (ub[0][j] + v0a*ub[1][j] + v0b*ub[2][j])*tq0;
    ub[0][j] -= w; ub[1][j] -= w*v0a; ub[2][j] -= w*v0b;
  }
#pragma unroll
  for (int i = 0; i < 3; ++i) {
    float w = (vb[i][1] + p0a*vb[i][2])*tp0;
    vb[i][1] -= w; vb[i][2] -= w*p0a;
  }
#pragma unroll
  for (int i = 0; i < 3; ++i)
#pragma unroll
    for (int j = 0; j < 3; ++j) { u[i][j] = ub[i][j]; vt[i][j] = vb[i][j]; }
}

// =============================================================================
// bf16 helpers (RNE, manual — verified since round 1)
// =============================================================================
__device__ __forceinline__ unsigned int f2bf(float x) {
  unsigned int u = __float_as_uint(x);
  return (u + 0x7FFFu + ((u >> 16) & 1u)) >> 16;
}
__device__ __forceinline__ float bf2f(unsigned int h) {
  return __uint_as_float(h << 16);
}

// =============================================================================
// Kernel 0: pack. (unchanged)
// =============================================================================
__global__ __launch_bounds__(128)
void pack_kernel(const float* __restrict__ srcE, const float* __restrict__ tgtE,
                 const float* __restrict__ tgt,
                 unsigned short* __restrict__ Qp, unsigned short* __restrict__ Kp,
                 unsigned short* __restrict__ Vt4) {
  const int g = blockIdx.x*128 + threadIdx.x;   // 32768 = 16*2048
  const int b = g >> 11, n = g & 2047;
  const float* qs = srcE + (size_t)b*16*2048 + n;
  const float* ks = tgtE + (size_t)b*16*2048 + n;
  const float QSCALE = 0.25f * 1.44269504088896340736f;

  unsigned short qrow[32], krow[32];
#pragma unroll
  for (int dd = 0; dd < 16; ++dd) {
    float q = qs[dd*2048] * QSCALE;
    unsigned int qh = f2bf(q);
    qrow[dd] = (unsigned short)qh; qrow[16+dd] = (unsigned short)f2bf(q - bf2f(qh));
    float k = ks[dd*2048];
    unsigned int kh = f2bf(k);
    krow[dd] = (unsigned short)kh; krow[16+dd] = (unsigned short)f2bf(k - bf2f(kh));
  }
  uint4* qdst = (uint4*)(Qp + (size_t)g*32);
  uint4* kdst = (uint4*)(Kp + (size_t)g*32);
#pragma unroll
  for (int i = 0; i < 4; ++i) { qdst[i] = ((uint4*)qrow)[i]; kdst[i] = ((uint4*)krow)[i]; }

  const float* vp = tgt + (size_t)b*3*2048 + n;
  unsigned short* wb = Vt4 + (size_t)b*4*2048;
  wb[n]          = 0x3F80;             // ones column (j=0)
  wb[2048 + n]   = (unsigned short)f2bf(vp[0]);
  wb[2*2048 + n] = (unsigned short)f2bf(vp[2048]);
  wb[3*2048 + n] = (unsigned short)f2bf(vp[4096]);
}

// =============================================================================
// Kernel 1: MFMA flash attention; PV + softmax-sum via MFMA.
// (round 11: 80B-stride staging, bank-conflict-free — unchanged)
// =============================================================================
__global__ __launch_bounds__(512, 4)
void corr_kernel(const unsigned short* __restrict__ Qp, const unsigned short* __restrict__ Kp,
                 const unsigned short* __restrict__ Vt4, const float* __restrict__ src,
                 float* __restrict__ ws) {
  const int bid = blockIdx.x;
  const int b   = bid & 15;
  const int nt  = bid >> 4;          // 0..31, 64 n each
  const int tid = threadIdx.x;
  const int w   = tid >> 6;
  const int L   = tid & 63;
  const int lg  = L >> 4;
  const int ll  = L & 15;

  __shared__ __align__(16) char  stage[8*1280];       // 10 KB: per-wave A' staging (80B rows)
  __shared__ __align__(16) float partial[8][64][4];   // 8 KB

  const unsigned short* Qb = Qp + (size_t)b*2048*32;
  const unsigned short* Kb = Kp + (size_t)b*2048*32;
  const unsigned short* Wb = Vt4 + (size_t)b*4*2048;

  const bf16x8 zero8 = {0,0,0,0,0,0,0,0};
  char* my = stage + w*1280;
  char* wr0 = my + ll*80 + lg*8;        // tile0 write slot
  char* wr1 = wr0 + 32;                 // tile1 write slot
  const char* rd = my + ll*80 + lg*16;  // A'-frag read slot (16B aligned: 80=16*5)

  // ---- Q-fragments for this block's 4 n-tiles ----
  bf16x8 bq1[4], bq2[4];
#pragma unroll
  for (int t2 = 0; t2 < 4; ++t2) {
    const unsigned short* qr = Qb + (size_t)(nt*64 + t2*16 + ll)*32;
    bq1[t2] = *(const bf16x8*)(qr + (lg & 1)*8);
    bf16x8 lo = *(const bf16x8*)(qr + 16 + (lg & 1)*8);
    bq2[t2] = (lg < 2) ? lo : zero8;
  }

  f32x4 accp[4];
#pragma unroll
  for (int t2 = 0; t2 < 4; ++t2) accp[t2] = (f32x4){0.f, 0.f, 0.f, 0.f};

  for (int p = w; p < 64; p += 8) {
    const unsigned short* ar = Kb + (size_t)(p*32 + ll)*32;
    bf16x8 a0 = *(const bf16x8*)(ar + lg*8);            // m-tile 2p
    bf16x8 a1 = *(const bf16x8*)(ar + 16*32 + lg*8);    // m-tile 2p+1
    bf16x8 wv = zero8;                                  // W B-frag (cols>=4 zero)
    if (ll < 4) wv = *(const bf16x8*)(Wb + (size_t)ll*2048 + p*32 + lg*8);

#pragma unroll
    for (int t2 = 0; t2 < 4; ++t2) {
      f32x4 c0 = (f32x4){0.f,0.f,0.f,0.f};
      f32x4 c1 = (f32x4){0.f,0.f,0.f,0.f};
      c0 = __builtin_amdgcn_mfma_f32_16x16x32_bf16(a0, bq1[t2], c0, 0, 0, 0);
      c0 = __builtin_amdgcn_mfma_f32_16x16x32_bf16(a0, bq2[t2], c0, 0, 0, 0);
      c1 = __builtin_amdgcn_mfma_f32_16x16x32_bf16(a1, bq1[t2], c1, 0, 0, 0);
      c1 = __builtin_amdgcn_mfma_f32_16x16x32_bf16(a1, bq2[t2], c1, 0, 0, 0);
      // P = exp2(scores); C-frag: row m_loc = lg*4+r, col n = ll
      float e0 = __builtin_amdgcn_exp2f(c0.x), e1 = __builtin_amdgcn_exp2f(c0.y);
      float e2 = __builtin_amdgcn_exp2f(c0.z), e3 = __builtin_amdgcn_exp2f(c0.w);
      float f0 = __builtin_amdgcn_exp2f(c1.x), f1 = __builtin_amdgcn_exp2f(c1.y);
      float f2 = __builtin_amdgcn_exp2f(c1.z), f3 = __builtin_amdgcn_exp2f(c1.w);
      // pack to bf16 pairs (lo = even r) and stage into A' layout
      *(uint2*)wr0 = make_uint2(f2bf(e0) | (f2bf(e1) << 16),
                                f2bf(e2) | (f2bf(e3) << 16));
      *(uint2*)wr1 = make_uint2(f2bf(f0) | (f2bf(f1) << 16),
                                f2bf(f2) | (f2bf(f3) << 16));
      bf16x8 pa = *(const bf16x8*)rd;   // A'[row=ll][k=lg*8..+7]
      // PV: X[n][j] += P^T x W   (j: 0=sumE, 1..3 = sum e*v)
      accp[t2] = __builtin_amdgcn_mfma_f32_16x16x32_bf16(pa, wv, accp[t2], 0, 0, 0);
    }
  }

  // ---- write per-wave partials: X[j=ll][n] for ll<4 ----
  if (ll < 4) {
#pragma unroll
    for (int t2 = 0; t2 < 4; ++t2) {
      int nb = t2*16 + lg*4;
      partial[w][nb+0][ll] = accp[t2].x;
      partial[w][nb+1][ll] = accp[t2].y;
      partial[w][nb+2][ll] = accp[t2].z;
      partial[w][nb+3][ll] = accp[t2].w;
    }
  }
  __syncthreads();

  // ---- per-n finish + 15-value single-wave reduction (wave 0 only) ----
  if (tid < 64) {
    float4 s4 = make_float4(0.f, 0.f, 0.f, 0.f);
#pragma unroll
    for (int w2 = 0; w2 < 8; ++w2) {
      float4 pq = *(const float4*)&partial[w2][tid][0];
      s4.x += pq.x; s4.y += pq.y; s4.z += pq.z; s4.w += pq.w;
    }
    float inv = 1.0f / s4.x;
    float c0 = s4.y*inv, c1 = s4.z*inv, c2 = s4.w*inv;
    const int n = nt*64 + tid;
    const float* sp = src + (size_t)b*3*2048;
    float s0v = sp[n], s1v = sp[2048+n], s2v = sp[4096+n];
    float vals[15] = { c0, c1, c2, s0v, s1v, s2v,
                       s0v*c0, s0v*c1, s0v*c2,
                       s1v*c0, s1v*c1, s1v*c2,
                       s2v*c0, s2v*c1, s2v*c2 };
#pragma unroll
    for (int k = 0; k < 15; ++k) {
      float v = vals[k];
      v += __shfl_xor(v, 1);  v += __shfl_xor(v, 2);  v += __shfl_xor(v, 4);
      v += __shfl_xor(v, 8);  v += __shfl_xor(v, 16); v += __shfl_xor(v, 32);
      vals[k] = v;
    }
    if (tid == 0) {
#pragma unroll
      for (int k = 0; k < 15; ++k) ws[bid*16 + k] = vals[k];
    }
  }
}

// =============================================================================
// Kernel 2: 16 BLOCKS x 64 threads — one batch per block, one CU each.
// Round 12: the 1-block/16-wave layout made 16 divergent serial SVD paths
// share one CU's L1-i and sequencer (~30us); one-per-CU fetches in parallel.
// =============================================================================
__global__ __launch_bounds__(64)
void finalize_kernel(const float* __restrict__ ws, float* __restrict__ out) {
  const int b = blockIdx.x;
  const int L = threadIdx.x;

  float a = 0.0f;
  if (L < 15) {
#pragma unroll
    for (int ntile = 0; ntile < 32; ++ntile)
      a += ws[(ntile*16 + b)*16 + L];
  }
  float acc[15];
#pragma unroll
  for (int k = 0; k < 15; ++k) acc[k] = __shfl(a, k);

  if (L == 0) {
    const float invN = 1.0f/2048.0f;
    float Sc[3] = {acc[0], acc[1], acc[2]};
    float Ss[3] = {acc[3], acc[4], acc[5]};
    float cm[3] = {Sc[0]*invN, Sc[1]*invN, Sc[2]*invN};
    float sm[3] = {Ss[0]*invN, Ss[1]*invN, Ss[2]*invN};

    float A[3][3];
#pragma unroll
    for (int i = 0; i < 3; ++i)
#pragma unroll
      for (int j = 0; j < 3; ++j)
        A[i][j] = acc[6 + i*3 + j] - Ss[i]*cm[j];

    float u[3][3], vt[3][3];
    svd3_gesdd(A, u, vt);

    float R[3][3];
#pragma unroll
    for (int i = 0; i < 3; ++i)
#pragma unroll
      for (int k = 0; k < 3; ++k)
        R[i][k] = vt[i][0]*u[k][0] + vt[i][1]*u[k][1] + vt[i][2]*u[k][2];

    float det = R[0][0]*(R[1][1]*R[2][2] - R[1][2]*R[2][1])
              - R[0][1]*(R[1][0]*R[2][2] - R[1][2]*R[2][0])
              + R[0][2]*(R[1][0]*R[2][1] - R[1][1]*R[2][0]);

    if (det < 0.0f) {
#pragma unroll
      for (int i = 0; i < 3; ++i)
#pragma unroll
        for (int k = 0; k < 3; ++k)
          R[i][k] -= 2.0f*vt[i][2]*u[k][2];
    }

    float tv[3];
#pragma unroll
    for (int i = 0; i < 3; ++i)
      tv[i] = -(R[i][0]*sm[0] + R[i][1]*sm[1] + R[i][2]*sm[2]) + cm[i];

#pragma unroll
    for (int i = 0; i < 3; ++i)
#pragma unroll
      for (int j = 0; j < 3; ++j)
        out[b*9 + i*3 + j] = R[i][j];
#pragma unroll
    for (int i = 0; i < 3; ++i)
      out[144 + b*3 + i] = tv[i];
  }
}

extern "C" void kernel_launch(void* const* d_in, const int* in_sizes, int n_in,
                              void* d_out, int out_size, void* d_ws, size_t ws_size,
                              hipStream_t stream) {
  const float* srcE = (const float*)d_in[0];
  const float* tgtE = (const float*)d_in[1];
  const float* src  = (const float*)d_in[2];
  const float* tgt  = (const float*)d_in[3];
  float* out = (float*)d_out;

  // ws layout: [0,32KB) partials | Qp 2MB | Kp 2MB | Vt4 256KB
  float* part = (float*)d_ws;
  unsigned short* Qp  = (unsigned short*)((char*)d_ws + 32768);
  unsigned short* Kp  = (unsigned short*)((char*)d_ws + 32768 + (size_t)16*2048*32*2);
  unsigned short* Vt4 = (unsigned short*)((char*)d_ws + 32768 + (size_t)2*16*2048*32*2);

  hipLaunchKernelGGL(pack_kernel, dim3(256), dim3(128), 0, stream, srcE, tgtE, tgt, Qp, Kp, Vt4);
  hipLaunchKernelGGL(corr_kernel, dim3(512), dim3(512), 0, stream, Qp, Kp, Vt4, src, part);
  hipLaunchKernelGGL(finalize_kernel, dim3(16), dim3(64), 0, stream, part, out);
}